// Round 2
// baseline (4267.379 us; speedup 1.0000x reference)
//
#include <hip/hip_runtime.h>
#include <hip/hip_bf16.h>

#define NLOC_   4096
#define NALL_   6144
#define NEDGE_  262144
#define NANGLE_ 409600

__device__ __forceinline__ float silu_(float x){ return x / (1.0f + __expf(-x)); }

// ---------------------------------------------------------------------------
// K1: scatter outer products h2 (x) (sw*edge_ebd) and h2 (x) (sw*nei_node)
// into per-node h2g2 accumulators. One wave (64 lanes) per edge.
// ---------------------------------------------------------------------------
__global__ void k_scatter_sym(const float* __restrict__ node_ext,
                              const float* __restrict__ edge_ebd,
                              const float* __restrict__ h2,
                              const float* __restrict__ sw,
                              const int*  __restrict__ n2e,
                              const int*  __restrict__ n_ext2e,
                              float* __restrict__ h2g2_e,
                              float* __restrict__ h2g2_n)
{
    int e = blockIdx.x * 4 + (threadIdx.x >> 6);
    int l = threadIdx.x & 63;
    int n = n2e[e];
    int g = n_ext2e[e];
    float swe = sw[e];
    float h0  = h2[e*3 + 0];
    float h1  = h2[e*3 + 1];
    float h2v = h2[e*3 + 2];

    // edge part (d = 64): lane owns column l
    float we = edge_ebd[(size_t)e*64 + l] * swe;
    float* pe = h2g2_e + (size_t)n * 192;
    atomicAdd(pe +   0 + l, h0 * we);
    atomicAdd(pe +  64 + l, h1 * we);
    atomicAdd(pe + 128 + l, h2v * we);

    // node part (d = 128): lane owns columns l and l+64
    float v0 = node_ext[(size_t)g*128 + l]      * swe;
    float v1 = node_ext[(size_t)g*128 + 64 + l] * swe;
    float* pn = h2g2_n + (size_t)n * 384;
    atomicAdd(pn +   0 + l, h0 * v0);
    atomicAdd(pn +  64 + l, h0 * v1);
    atomicAdd(pn + 128 + l, h1 * v0);
    atomicAdd(pn + 192 + l, h1 * v1);
    atomicAdd(pn + 256 + l, h2v * v0);
    atomicAdd(pn + 320 + l, h2v * v1);
}

// ---------------------------------------------------------------------------
// K3: per-edge GEMV: edge_info(320) -> node_edge_update(128) + edge_self(64).
// One wave per edge; edge_info held in registers (5 vals/lane), broadcast
// via __shfl; W read row-major (coalesced across lanes, L2 resident).
// ---------------------------------------------------------------------------
__global__ void k_edge_gemm(const float* __restrict__ node_ext,
                            const float* __restrict__ edge_ebd,
                            const float* __restrict__ sw,
                            const int*  __restrict__ n2e,
                            const int*  __restrict__ n_ext2e,
                            const float* __restrict__ Wne, const float* __restrict__ bne,
                            const float* __restrict__ Wes, const float* __restrict__ bes,
                            const float* __restrict__ e_res0,
                            float* __restrict__ msg,
                            float* __restrict__ e_out)
{
    int e = blockIdx.x * 4 + (threadIdx.x >> 6);
    int l = threadIdx.x & 63;
    int n = n2e[e];
    int g = n_ext2e[e];

    // edge_info = [node_i(128) | nei_node(128) | edge_ebd(64)], lane holds k=p*64+l
    float ei[5];
    ei[0] = node_ext[(size_t)n*128 + l];
    ei[1] = node_ext[(size_t)n*128 + 64 + l];
    ei[2] = node_ext[(size_t)g*128 + l];
    ei[3] = node_ext[(size_t)g*128 + 64 + l];
    ei[4] = edge_ebd[(size_t)e*64 + l];

    float acc0 = 0.f, acc1 = 0.f, acc2 = 0.f;
    #pragma unroll
    for (int p = 0; p < 5; ++p) {
        float src = ei[p];
        #pragma unroll 16
        for (int j = 0; j < 64; ++j) {
            float v = __shfl(src, j);
            int k = p*64 + j;
            acc0 = fmaf(v, Wne[k*128 + l],      acc0);
            acc1 = fmaf(v, Wne[k*128 + 64 + l], acc1);
            acc2 = fmaf(v, Wes[k*64 + l],       acc2);
        }
    }

    float swe = sw[e];
    float u0 = silu_(acc0 + bne[l])      * swe;
    float u1 = silu_(acc1 + bne[64 + l]) * swe;
    atomicAdd(msg + (size_t)n*128 + l,      u0);
    atomicAdd(msg + (size_t)n*128 + 64 + l, u1);

    float es = silu_(acc2 + bes[l]);
    e_out[(size_t)e*64 + l] = edge_ebd[(size_t)e*64 + l] + e_res0[l] * es;
}

// ---------------------------------------------------------------------------
// K4: per-angle GEMV: angle_info(288) -> edge_angle(64) + angle_self(32).
// edge_angle * a_sw scattered into reduced[eij2a]; a_updated written.
// ---------------------------------------------------------------------------
__global__ void k_angle_gemm(const float* __restrict__ node_ext,
                             const float* __restrict__ edge_ebd,
                             const float* __restrict__ angle_ebd,
                             const float* __restrict__ a_sw,
                             const int*  __restrict__ n2a,
                             const int*  __restrict__ eij2a,
                             const int*  __restrict__ eik2a,
                             const float* __restrict__ W1, const float* __restrict__ b1,
                             const float* __restrict__ WA, const float* __restrict__ bA,
                             const float* __restrict__ a_res0,
                             float* __restrict__ reduced,
                             float* __restrict__ a_out)
{
    int a = blockIdx.x * 4 + (threadIdx.x >> 6);
    int l = threadIdx.x & 63;
    int n   = n2a[a];
    int eij = eij2a[a];
    int eik = eik2a[a];

    // angle_info = [angle_ebd(32) | node(128) | edge_ik(64) | edge_ij(64)]
    // lane holds k = p*64 + l   (p=4 valid only for l<32)
    float ai[5];
    ai[0] = (l < 32) ? angle_ebd[(size_t)a*32 + l]
                     : node_ext[(size_t)n*128 + (l - 32)];
    ai[1] = node_ext[(size_t)n*128 + (l + 32)];
    ai[2] = (l < 32) ? node_ext[(size_t)n*128 + (l + 96)]
                     : edge_ebd[(size_t)eik*64 + (l - 32)];
    ai[3] = (l < 32) ? edge_ebd[(size_t)eik*64 + (l + 32)]
                     : edge_ebd[(size_t)eij*64 + (l - 32)];
    ai[4] = (l < 32) ? edge_ebd[(size_t)eij*64 + (l + 32)] : 0.f;

    float acce = 0.f, acca = 0.f;
    int la = l & 31;
    #pragma unroll
    for (int p = 0; p < 5; ++p) {
        float src = ai[p];
        const int jmax = (p == 4) ? 32 : 64;
        #pragma unroll 16
        for (int j = 0; j < jmax; ++j) {
            float v = __shfl(src, j);
            int k = p*64 + j;
            acce = fmaf(v, W1[k*64 + l],  acce);
            acca = fmaf(v, WA[k*32 + la], acca);
        }
    }

    float ea = silu_(acce + b1[l]) * a_sw[a];
    atomicAdd(reduced + (size_t)eij*64 + l, ea);

    if (l < 32) {
        float as = silu_(acca + bA[la]);
        a_out[(size_t)a*32 + l] = angle_ebd[(size_t)a*32 + l] + a_res0[la] * as;
    }
}

// ---------------------------------------------------------------------------
// K5: edge_angle_msg = silu(reduced @ W2 + b2); e_out += e_res1 * msg
// ---------------------------------------------------------------------------
__global__ void k_edge_final(const float* __restrict__ reduced,
                             const float* __restrict__ W2, const float* __restrict__ b2_,
                             const float* __restrict__ e_res1,
                             float* __restrict__ e_out)
{
    int e = blockIdx.x * 4 + (threadIdx.x >> 6);
    int l = threadIdx.x & 63;
    float r = reduced[(size_t)e*64 + l];
    float acc = 0.f;
    #pragma unroll 16
    for (int k = 0; k < 64; ++k) {
        float v = __shfl(r, k);
        acc = fmaf(v, W2[k*64 + l], acc);
    }
    float m = silu_(acc + b2_[l]);
    size_t idx = (size_t)e*64 + l;
    e_out[idx] = e_out[idx] + e_res1[l] * m;
}

// ---------------------------------------------------------------------------
// K2: per-node finalize: node_self + node_sym (from h2g2) + node_edge_msg.
// One 128-thread block per node; thread = output channel.
// ---------------------------------------------------------------------------
__global__ void k_node_final(const float* __restrict__ node_ext,
                             const float* __restrict__ h2g2_e,
                             const float* __restrict__ h2g2_n,
                             const float* __restrict__ msg,
                             const float* __restrict__ Wns,  const float* __restrict__ bns,
                             const float* __restrict__ Wsym, const float* __restrict__ bsym,
                             const float* __restrict__ nr0, const float* __restrict__ nr1,
                             const float* __restrict__ nr2,
                             float* __restrict__ n_out)
{
    __shared__ float x[128];
    __shared__ float he[192];
    __shared__ float hn[384];
    __shared__ float symc[768];

    int n = blockIdx.x;
    int c = threadIdx.x;   // 128 threads

    x[c] = node_ext[(size_t)n*128 + c];
    for (int i = c; i < 192; i += 128) he[i] = h2g2_e[(size_t)n*192 + i];
    for (int i = c; i < 384; i += 128) hn[i] = h2g2_n[(size_t)n*384 + i];
    __syncthreads();

    // sym_cat = [g_edge (4x64) | g_node (4x128)],
    // g[a][j] = (1/(6.4*3)) * sum_x h_raw[x][a] * h_raw[x][j]
    const float SCALE = 1.0f / (6.4f * 3.0f);
    for (int i = c; i < 768; i += 128) {
        float s;
        if (i < 256) {
            int a = i >> 6, j = i & 63;
            s = he[a]*he[j] + he[64 + a]*he[64 + j] + he[128 + a]*he[128 + j];
        } else {
            int i2 = i - 256;
            int a = i2 >> 7, j = i2 & 127;
            s = hn[a]*hn[j] + hn[128 + a]*hn[128 + j] + hn[256 + a]*hn[256 + j];
        }
        symc[i] = s * SCALE;
    }
    __syncthreads();

    // node_self = silu(x @ Wns + bns)
    float accs = 0.f;
    #pragma unroll 8
    for (int k = 0; k < 128; ++k) accs = fmaf(x[k], Wns[k*128 + c], accs);
    float self_ = silu_(accs + bns[c]);

    // node_sym = silu(sym_cat @ Wsym + bsym)
    float accy = 0.f;
    #pragma unroll 8
    for (int k = 0; k < 768; ++k) accy = fmaf(symc[k], Wsym[k*128 + c], accy);
    float sym_ = silu_(accy + bsym[c]);

    float m = msg[(size_t)n*128 + c] * (1.0f / 6.4f);
    n_out[(size_t)n*128 + c] =
        x[c] + nr0[c]*self_ + nr1[c]*sym_ + nr2[c]*m;
}

// ---------------------------------------------------------------------------
extern "C" void kernel_launch(void* const* d_in, const int* in_sizes, int n_in,
                              void* d_out, int out_size, void* d_ws, size_t ws_size,
                              hipStream_t stream)
{
    const float* node_ext  = (const float*)d_in[0];
    const float* edge_ebd  = (const float*)d_in[1];
    const float* h2        = (const float*)d_in[2];
    const float* angle_ebd = (const float*)d_in[3];
    // d_in[4] nlist, d_in[5] nlist_mask : unused (shapes only)
    const float* sw        = (const float*)d_in[6];
    // d_in[7] a_nlist, d_in[8] a_nlist_mask : unused
    const float* a_sw      = (const float*)d_in[9];
    const int*  edge_index  = (const int*)d_in[10];
    const int*  angle_index = (const int*)d_in[11];
    const int* n2e     = edge_index;
    const int* n_ext2e = edge_index + NEDGE_;
    const int* n2a     = angle_index;
    const int* eij2a   = angle_index + NANGLE_;
    const int* eik2a   = angle_index + 2*NANGLE_;

    const float* Wns  = (const float*)d_in[12];
    const float* bns  = (const float*)d_in[13];
    const float* Wsym = (const float*)d_in[14];
    const float* bsym = (const float*)d_in[15];
    const float* Wne  = (const float*)d_in[16];
    const float* bne  = (const float*)d_in[17];
    const float* Wes  = (const float*)d_in[18];
    const float* bes  = (const float*)d_in[19];
    const float* W1   = (const float*)d_in[20];
    const float* b1   = (const float*)d_in[21];
    const float* W2   = (const float*)d_in[22];
    const float* b2_  = (const float*)d_in[23];
    const float* WA   = (const float*)d_in[24];
    const float* bA   = (const float*)d_in[25];
    const float* nr0  = (const float*)d_in[26];
    const float* nr1  = (const float*)d_in[27];
    const float* nr2  = (const float*)d_in[28];
    const float* er0  = (const float*)d_in[29];
    const float* er1  = (const float*)d_in[30];
    const float* ar0  = (const float*)d_in[31];

    // f32 accumulator workspace layout
    float* h2g2_e  = (float*)d_ws;                          // 4096*192
    float* h2g2_n  = h2g2_e + (size_t)NLOC_*192;            // 4096*384
    float* msg     = h2g2_n + (size_t)NLOC_*384;            // 4096*128
    float* reduced = msg    + (size_t)NLOC_*128;            // 262144*64
    size_t acc_floats = (size_t)NLOC_*192 + (size_t)NLOC_*384
                      + (size_t)NLOC_*128 + (size_t)NEDGE_*64;
    hipMemsetAsync(d_ws, 0, acc_floats * sizeof(float), stream);

    float* n_out = (float*)d_out;
    float* e_out = n_out + (size_t)NLOC_*128;
    float* a_out = e_out + (size_t)NEDGE_*64;

    k_scatter_sym<<<NEDGE_/4,  256, 0, stream>>>(node_ext, edge_ebd, h2, sw,
                                                 n2e, n_ext2e, h2g2_e, h2g2_n);
    k_edge_gemm  <<<NEDGE_/4,  256, 0, stream>>>(node_ext, edge_ebd, sw, n2e, n_ext2e,
                                                 Wne, bne, Wes, bes, er0, msg, e_out);
    k_angle_gemm <<<NANGLE_/4, 256, 0, stream>>>(node_ext, edge_ebd, angle_ebd, a_sw,
                                                 n2a, eij2a, eik2a,
                                                 W1, b1, WA, bA, ar0, reduced, a_out);
    k_edge_final <<<NEDGE_/4,  256, 0, stream>>>(reduced, W2, b2_, er1, e_out);
    k_node_final <<<NLOC_,     128, 0, stream>>>(node_ext, h2g2_e, h2g2_n, msg,
                                                 Wns, bns, Wsym, bsym,
                                                 nr0, nr1, nr2, n_out);
}

// Round 3
// 1012.112 us; speedup vs baseline: 4.2163x; 4.2163x over previous
//
#include <hip/hip_runtime.h>
#include <hip/hip_bf16.h>

#define NLOC_   4096
#define NALL_   6144
#define NEDGE_  262144
#define NANGLE_ 409600

typedef __bf16 bf16x8 __attribute__((ext_vector_type(8)));
typedef float  f32x4  __attribute__((ext_vector_type(4)));
typedef unsigned short u16;

__device__ __forceinline__ float silu_(float x){ return x / (1.0f + __expf(-x)); }

// f32 -> bf16 (RNE) bit pattern
__device__ __forceinline__ u16 f2bu(float f){
    union { float f; unsigned u; } v; v.f = f;
    unsigned r = v.u + 0x7fffu + ((v.u >> 16) & 1u);
    return (u16)(r >> 16);
}
__device__ __forceinline__ void st_bf16x4(u16* dst, float4 v){
    unsigned lo = (unsigned)f2bu(v.x) | ((unsigned)f2bu(v.y) << 16);
    unsigned hi = (unsigned)f2bu(v.z) | ((unsigned)f2bu(v.w) << 16);
    *reinterpret_cast<uint2*>(dst) = make_uint2(lo, hi);
}

// ---------------------------------------------------------------------------
// Prep: bf16-transposed weights.  WTe[192][320] (cols 0-127=Wne, 128-191=Wes)
// WTa[96][288] (0-63=W1, 64-95=WA), WT2[64][64] (W2).
// ---------------------------------------------------------------------------
__global__ void k_prep(const float* __restrict__ Wne, const float* __restrict__ Wes,
                       const float* __restrict__ W1,  const float* __restrict__ WA,
                       const float* __restrict__ W2,
                       u16* __restrict__ WTe, u16* __restrict__ WTa, u16* __restrict__ WT2)
{
    int b = blockIdx.x, t = threadIdx.x;
    if (b < 192) {
        if (t < 320) WTe[b*320 + t] = f2bu(b < 128 ? Wne[t*128 + b] : Wes[t*64 + (b-128)]);
    } else if (b < 288) {
        int n = b - 192;
        if (t < 288) WTa[n*288 + t] = f2bu(n < 64 ? W1[t*64 + n] : WA[t*32 + (n-64)]);
    } else {
        int n = b - 288;
        if (t < 64)  WT2[n*64 + t] = f2bu(W2[t*64 + n]);
    }
}

// ---------------------------------------------------------------------------
// K1: scatter outer products into per-node h2g2 accumulators (f32, unchanged).
// ---------------------------------------------------------------------------
__global__ void k_scatter_sym(const float* __restrict__ node_ext,
                              const float* __restrict__ edge_ebd,
                              const float* __restrict__ h2,
                              const float* __restrict__ sw,
                              const int*  __restrict__ n2e,
                              const int*  __restrict__ n_ext2e,
                              float* __restrict__ h2g2_e,
                              float* __restrict__ h2g2_n)
{
    int e = blockIdx.x * 4 + (threadIdx.x >> 6);
    int l = threadIdx.x & 63;
    int n = n2e[e];
    int g = n_ext2e[e];
    float swe = sw[e];
    float h0  = h2[e*3 + 0];
    float h1  = h2[e*3 + 1];
    float h2v = h2[e*3 + 2];

    float we = edge_ebd[(size_t)e*64 + l] * swe;
    float* pe = h2g2_e + (size_t)n * 192;
    atomicAdd(pe +   0 + l, h0 * we);
    atomicAdd(pe +  64 + l, h1 * we);
    atomicAdd(pe + 128 + l, h2v * we);

    float v0 = node_ext[(size_t)g*128 + l]      * swe;
    float v1 = node_ext[(size_t)g*128 + 64 + l] * swe;
    float* pn = h2g2_n + (size_t)n * 384;
    atomicAdd(pn +   0 + l, h0 * v0);
    atomicAdd(pn +  64 + l, h0 * v1);
    atomicAdd(pn + 128 + l, h1 * v0);
    atomicAdd(pn + 192 + l, h1 * v1);
    atomicAdd(pn + 256 + l, h2v * v0);
    atomicAdd(pn + 320 + l, h2v * v1);
}

// ---------------------------------------------------------------------------
// K3': edge GEMM via MFMA. M-tile=64 edges, K=320, N=192.
// LDS A [64][328] bf16; 4 waves: wave w owns N cols 48w..48w+47 (3 frags),
// all 64 rows (4 M-frags).
// ---------------------------------------------------------------------------
__global__ __launch_bounds__(256) void k_edge_mfma(
    const float* __restrict__ node_ext, const float* __restrict__ edge_ebd,
    const float* __restrict__ sw,
    const int* __restrict__ n2e, const int* __restrict__ n_ext2e,
    const u16* __restrict__ WTe,
    const float* __restrict__ bne, const float* __restrict__ bes,
    const float* __restrict__ e_res0,
    float* __restrict__ msg, float* __restrict__ e_out)
{
    __shared__ u16 sA[64][328];
    __shared__ int s_n[64], s_g[64];
    const int tid = threadIdx.x;
    const int e0 = blockIdx.x * 64;

    if (tid < 64) s_n[tid] = n2e[e0 + tid];
    else if (tid < 128) s_g[tid - 64] = n_ext2e[e0 + tid - 64];
    __syncthreads();

    const float4* node4 = (const float4*)node_ext;
    const float4* edge4 = (const float4*)edge_ebd;
    #pragma unroll
    for (int f = tid; f < 2048; f += 256) {          // node_i: 64 x 32 float4
        int e = f >> 5, c = f & 31;
        st_bf16x4(&sA[e][4*c], node4[(size_t)s_n[e]*32 + c]);
    }
    #pragma unroll
    for (int f = tid; f < 2048; f += 256) {          // nei node
        int e = f >> 5, c = f & 31;
        st_bf16x4(&sA[e][128 + 4*c], node4[(size_t)s_g[e]*32 + c]);
    }
    #pragma unroll
    for (int f = tid; f < 1024; f += 256) {          // edge_ebd: 64 x 16 float4
        int e = f >> 4, c = f & 15;
        st_bf16x4(&sA[e][256 + 4*c], edge4[(size_t)(e0 + e)*16 + c]);
    }
    __syncthreads();

    const int w = tid >> 6, l = tid & 63;
    const int lr = l & 15, lk = (l >> 4) * 8;

    f32x4 acc[4][3] = {};
    #pragma unroll
    for (int kk = 0; kk < 10; ++kk) {
        bf16x8 a[4], b[3];
        #pragma unroll
        for (int m = 0; m < 4; ++m)
            a[m] = *(const bf16x8*)&sA[16*m + lr][kk*32 + lk];
        #pragma unroll
        for (int n = 0; n < 3; ++n)
            b[n] = *(const bf16x8*)&WTe[(size_t)(48*w + 16*n + lr)*320 + kk*32 + lk];
        #pragma unroll
        for (int m = 0; m < 4; ++m)
            #pragma unroll
            for (int n = 0; n < 3; ++n)
                acc[m][n] = __builtin_amdgcn_mfma_f32_16x16x32_bf16(a[m], b[n], acc[m][n], 0, 0, 0);
    }

    #pragma unroll
    for (int n = 0; n < 3; ++n) {
        int c = 48*w + 16*n + lr;
        if (c < 128) {                                // node_edge_update path
            float bn = bne[c];
            #pragma unroll
            for (int m = 0; m < 4; ++m) {
                #pragma unroll
                for (int j = 0; j < 4; ++j) {
                    int r = 16*m + ((l >> 4) << 2) + j;
                    float u = silu_(acc[m][n][j] + bn) * sw[e0 + r];
                    atomicAdd(&msg[(size_t)s_n[r]*128 + c], u);
                }
            }
        } else {                                      // edge_self path
            int c2 = c - 128;
            float bs = bes[c2], rr = e_res0[c2];
            #pragma unroll
            for (int m = 0; m < 4; ++m) {
                #pragma unroll
                for (int j = 0; j < 4; ++j) {
                    int r = 16*m + ((l >> 4) << 2) + j;
                    size_t idx = (size_t)(e0 + r)*64 + c2;
                    e_out[idx] = edge_ebd[idx] + rr * silu_(acc[m][n][j] + bs);
                }
            }
        }
    }
}

// ---------------------------------------------------------------------------
// K4': angle GEMM via MFMA. M-tile=64 angles, K=288, N=96.
// LDS A [64][296]; 4 waves: wave w owns rows 16w..16w+15 (1 M-frag), all 96 cols.
// ---------------------------------------------------------------------------
__global__ __launch_bounds__(256) void k_angle_mfma(
    const float* __restrict__ node_ext, const float* __restrict__ edge_ebd,
    const float* __restrict__ angle_ebd, const float* __restrict__ a_sw,
    const int* __restrict__ n2a, const int* __restrict__ eij2a, const int* __restrict__ eik2a,
    const u16* __restrict__ WTa,
    const float* __restrict__ b1, const float* __restrict__ bA,
    const float* __restrict__ a_res0,
    float* __restrict__ reduced, float* __restrict__ a_out)
{
    __shared__ u16 sA[64][296];
    __shared__ int s_na[64], s_ij[64], s_ik[64];
    const int tid = threadIdx.x;
    const int a0 = blockIdx.x * 64;

    if (tid < 64) {
        s_na[tid] = n2a[a0 + tid];
        s_ij[tid] = eij2a[a0 + tid];
        s_ik[tid] = eik2a[a0 + tid];
    }
    __syncthreads();

    const float4* ang4  = (const float4*)angle_ebd;
    const float4* node4 = (const float4*)node_ext;
    const float4* edge4 = (const float4*)edge_ebd;
    #pragma unroll
    for (int f = tid; f < 512; f += 256) {            // angle_ebd: 64 x 8 float4
        int a = f >> 3, c = f & 7;
        st_bf16x4(&sA[a][4*c], ang4[(size_t)(a0 + a)*8 + c]);
    }
    #pragma unroll
    for (int f = tid; f < 2048; f += 256) {           // node: 64 x 32 float4
        int a = f >> 5, c = f & 31;
        st_bf16x4(&sA[a][32 + 4*c], node4[(size_t)s_na[a]*32 + c]);
    }
    #pragma unroll
    for (int f = tid; f < 1024; f += 256) {           // edge_ik
        int a = f >> 4, c = f & 15;
        st_bf16x4(&sA[a][160 + 4*c], edge4[(size_t)s_ik[a]*16 + c]);
    }
    #pragma unroll
    for (int f = tid; f < 1024; f += 256) {           // edge_ij
        int a = f >> 4, c = f & 15;
        st_bf16x4(&sA[a][224 + 4*c], edge4[(size_t)s_ij[a]*16 + c]);
    }
    __syncthreads();

    const int w = tid >> 6, l = tid & 63;
    const int lr = l & 15, lk = (l >> 4) * 8;

    f32x4 acc[6] = {};
    #pragma unroll
    for (int kk = 0; kk < 9; ++kk) {
        bf16x8 a = *(const bf16x8*)&sA[16*w + lr][kk*32 + lk];
        #pragma unroll
        for (int n = 0; n < 6; ++n) {
            bf16x8 b = *(const bf16x8*)&WTa[(size_t)(16*n + lr)*288 + kk*32 + lk];
            acc[n] = __builtin_amdgcn_mfma_f32_16x16x32_bf16(a, b, acc[n], 0, 0, 0);
        }
    }

    #pragma unroll
    for (int n = 0; n < 6; ++n) {
        int c = 16*n + lr;
        if (n < 4) {                                   // edge_angle -> reduced
            float bb = b1[c];
            #pragma unroll
            for (int j = 0; j < 4; ++j) {
                int r = 16*w + ((l >> 4) << 2) + j;
                float ea = silu_(acc[n][j] + bb) * a_sw[a0 + r];
                atomicAdd(&reduced[(size_t)s_ij[r]*64 + c], ea);
            }
        } else {                                       // angle_self -> a_out
            int c2 = c - 64;
            float bb = bA[c2], rr = a_res0[c2];
            #pragma unroll
            for (int j = 0; j < 4; ++j) {
                int r = 16*w + ((l >> 4) << 2) + j;
                size_t idx = (size_t)(a0 + r)*32 + c2;
                a_out[idx] = angle_ebd[idx] + rr * silu_(acc[n][j] + bb);
            }
        }
    }
}

// ---------------------------------------------------------------------------
// K5': edge_angle_msg = silu(reduced @ W2 + b2); e_out += e_res1 * msg (MFMA)
// ---------------------------------------------------------------------------
__global__ __launch_bounds__(256) void k_edgefin_mfma(
    const float* __restrict__ reduced, const u16* __restrict__ WT2,
    const float* __restrict__ b2_, const float* __restrict__ e_res1,
    float* __restrict__ e_out)
{
    __shared__ u16 sR[64][72];
    const int tid = threadIdx.x;
    const int e0 = blockIdx.x * 64;
    const float4* red4 = (const float4*)reduced;
    #pragma unroll
    for (int f = tid; f < 1024; f += 256) {
        int e = f >> 4, c = f & 15;
        st_bf16x4(&sR[e][4*c], red4[(size_t)(e0 + e)*16 + c]);
    }
    __syncthreads();

    const int w = tid >> 6, l = tid & 63;
    const int lr = l & 15, lk = (l >> 4) * 8;

    f32x4 acc[4] = {};
    #pragma unroll
    for (int kk = 0; kk < 2; ++kk) {
        bf16x8 b = *(const bf16x8*)&WT2[(size_t)(16*w + lr)*64 + kk*32 + lk];
        #pragma unroll
        for (int m = 0; m < 4; ++m) {
            bf16x8 a = *(const bf16x8*)&sR[16*m + lr][kk*32 + lk];
            acc[m] = __builtin_amdgcn_mfma_f32_16x16x32_bf16(a, b, acc[m], 0, 0, 0);
        }
    }
    int c = 16*w + lr;
    float bb = b2_[c], rr = e_res1[c];
    #pragma unroll
    for (int m = 0; m < 4; ++m)
        #pragma unroll
        for (int j = 0; j < 4; ++j) {
            size_t idx = (size_t)(e0 + 16*m + ((l >> 4) << 2) + j)*64 + c;
            e_out[idx] += rr * silu_(acc[m][j] + bb);
        }
}

// ---------------------------------------------------------------------------
// K2: per-node finalize (f32, unchanged).
// ---------------------------------------------------------------------------
__global__ void k_node_final(const float* __restrict__ node_ext,
                             const float* __restrict__ h2g2_e,
                             const float* __restrict__ h2g2_n,
                             const float* __restrict__ msg,
                             const float* __restrict__ Wns,  const float* __restrict__ bns,
                             const float* __restrict__ Wsym, const float* __restrict__ bsym,
                             const float* __restrict__ nr0, const float* __restrict__ nr1,
                             const float* __restrict__ nr2,
                             float* __restrict__ n_out)
{
    __shared__ float x[128];
    __shared__ float he[192];
    __shared__ float hn[384];
    __shared__ float symc[768];

    int n = blockIdx.x;
    int c = threadIdx.x;

    x[c] = node_ext[(size_t)n*128 + c];
    for (int i = c; i < 192; i += 128) he[i] = h2g2_e[(size_t)n*192 + i];
    for (int i = c; i < 384; i += 128) hn[i] = h2g2_n[(size_t)n*384 + i];
    __syncthreads();

    const float SCALE = 1.0f / (6.4f * 3.0f);
    for (int i = c; i < 768; i += 128) {
        float s;
        if (i < 256) {
            int a = i >> 6, j = i & 63;
            s = he[a]*he[j] + he[64 + a]*he[64 + j] + he[128 + a]*he[128 + j];
        } else {
            int i2 = i - 256;
            int a = i2 >> 7, j = i2 & 127;
            s = hn[a]*hn[j] + hn[128 + a]*hn[128 + j] + hn[256 + a]*hn[256 + j];
        }
        symc[i] = s * SCALE;
    }
    __syncthreads();

    float accs = 0.f;
    #pragma unroll 8
    for (int k = 0; k < 128; ++k) accs = fmaf(x[k], Wns[k*128 + c], accs);
    float self_ = silu_(accs + bns[c]);

    float accy = 0.f;
    #pragma unroll 8
    for (int k = 0; k < 768; ++k) accy = fmaf(symc[k], Wsym[k*128 + c], accy);
    float sym_ = silu_(accy + bsym[c]);

    float m = msg[(size_t)n*128 + c] * (1.0f / 6.4f);
    n_out[(size_t)n*128 + c] = x[c] + nr0[c]*self_ + nr1[c]*sym_ + nr2[c]*m;
}

// ---------------------------------------------------------------------------
extern "C" void kernel_launch(void* const* d_in, const int* in_sizes, int n_in,
                              void* d_out, int out_size, void* d_ws, size_t ws_size,
                              hipStream_t stream)
{
    const float* node_ext  = (const float*)d_in[0];
    const float* edge_ebd  = (const float*)d_in[1];
    const float* h2        = (const float*)d_in[2];
    const float* angle_ebd = (const float*)d_in[3];
    const float* sw        = (const float*)d_in[6];
    const float* a_sw      = (const float*)d_in[9];
    const int*  edge_index  = (const int*)d_in[10];
    const int*  angle_index = (const int*)d_in[11];
    const int* n2e     = edge_index;
    const int* n_ext2e = edge_index + NEDGE_;
    const int* n2a     = angle_index;
    const int* eij2a   = angle_index + NANGLE_;
    const int* eik2a   = angle_index + 2*NANGLE_;

    const float* Wns  = (const float*)d_in[12];
    const float* bns  = (const float*)d_in[13];
    const float* Wsym = (const float*)d_in[14];
    const float* bsym = (const float*)d_in[15];
    const float* Wne  = (const float*)d_in[16];
    const float* bne  = (const float*)d_in[17];
    const float* Wes  = (const float*)d_in[18];
    const float* bes  = (const float*)d_in[19];
    const float* W1   = (const float*)d_in[20];
    const float* b1   = (const float*)d_in[21];
    const float* W2   = (const float*)d_in[22];
    const float* b2_  = (const float*)d_in[23];
    const float* WA   = (const float*)d_in[24];
    const float* bA   = (const float*)d_in[25];
    const float* nr0  = (const float*)d_in[26];
    const float* nr1  = (const float*)d_in[27];
    const float* nr2  = (const float*)d_in[28];
    const float* er0  = (const float*)d_in[29];
    const float* er1  = (const float*)d_in[30];
    const float* ar0  = (const float*)d_in[31];

    // workspace layout: f32 accumulators, then bf16 transposed weights
    float* h2g2_e  = (float*)d_ws;                          // 4096*192
    float* h2g2_n  = h2g2_e + (size_t)NLOC_*192;            // 4096*384
    float* msg     = h2g2_n + (size_t)NLOC_*384;            // 4096*128
    float* reduced = msg    + (size_t)NLOC_*128;            // 262144*64
    size_t acc_floats = (size_t)NLOC_*192 + (size_t)NLOC_*384
                      + (size_t)NLOC_*128 + (size_t)NEDGE_*64;
    u16* WTe = (u16*)(reduced + (size_t)NEDGE_*64);         // 192*320
    u16* WTa = WTe + 192*320;                               // 96*288
    u16* WT2 = WTa + 96*288;                                // 64*64

    hipMemsetAsync(d_ws, 0, acc_floats * sizeof(float), stream);

    float* n_out = (float*)d_out;
    float* e_out = n_out + (size_t)NLOC_*128;
    float* a_out = e_out + (size_t)NEDGE_*64;

    k_prep        <<<352, 320, 0, stream>>>(Wne, Wes, W1, WA, W2, WTe, WTa, WT2);
    k_scatter_sym <<<NEDGE_/4, 256, 0, stream>>>(node_ext, edge_ebd, h2, sw,
                                                 n2e, n_ext2e, h2g2_e, h2g2_n);
    k_edge_mfma   <<<NEDGE_/64, 256, 0, stream>>>(node_ext, edge_ebd, sw, n2e, n_ext2e,
                                                  WTe, bne, bes, er0, msg, e_out);
    k_angle_mfma  <<<NANGLE_/64, 256, 0, stream>>>(node_ext, edge_ebd, angle_ebd, a_sw,
                                                   n2a, eij2a, eik2a,
                                                   WTa, b1, bA, ar0, reduced, a_out);
    k_edgefin_mfma<<<NEDGE_/64, 256, 0, stream>>>(reduced, WT2, b2_, er1, e_out);
    k_node_final  <<<NLOC_, 128, 0, stream>>>(node_ext, h2g2_e, h2g2_n, msg,
                                              Wns, bns, Wsym, bsym,
                                              nr0, nr1, nr2, n_out);
}

// Round 4
// 923.675 us; speedup vs baseline: 4.6200x; 1.0957x over previous
//
#include <hip/hip_runtime.h>
#include <hip/hip_bf16.h>

#define NLOC_   4096
#define NALL_   6144
#define NEDGE_  262144
#define NANGLE_ 409600

typedef __bf16 bf16x8 __attribute__((ext_vector_type(8)));
typedef float  f32x4  __attribute__((ext_vector_type(4)));
typedef unsigned short u16;

__device__ __forceinline__ float silu_(float x){ return x / (1.0f + __expf(-x)); }

// f32 -> bf16 (RNE) bit pattern
__device__ __forceinline__ u16 f2bu(float f){
    union { float f; unsigned u; } v; v.f = f;
    unsigned r = v.u + 0x7fffu + ((v.u >> 16) & 1u);
    return (u16)(r >> 16);
}
__device__ __forceinline__ float bu2f(u16 b){
    union { unsigned u; float f; } v; v.u = ((unsigned)b) << 16; return v.f;
}
__device__ __forceinline__ void st_bf16x4(u16* dst, float4 v){
    unsigned lo = (unsigned)f2bu(v.x) | ((unsigned)f2bu(v.y) << 16);
    unsigned hi = (unsigned)f2bu(v.z) | ((unsigned)f2bu(v.w) << 16);
    *reinterpret_cast<uint2*>(dst) = make_uint2(lo, hi);
}

// ---------------------------------------------------------------------------
// Prep: bf16-transposed weights.  WTe[192][320] (cols 0-127=Wne, 128-191=Wes)
// WTa[96][288] (0-63=W1, 64-95=WA), WT2[64][64] (W2).
// ---------------------------------------------------------------------------
__global__ void k_prep(const float* __restrict__ Wne, const float* __restrict__ Wes,
                       const float* __restrict__ W1,  const float* __restrict__ WA,
                       const float* __restrict__ W2,
                       u16* __restrict__ WTe, u16* __restrict__ WTa, u16* __restrict__ WT2)
{
    int b = blockIdx.x, t = threadIdx.x;
    if (b < 192) {
        if (t < 320) WTe[b*320 + t] = f2bu(b < 128 ? Wne[t*128 + b] : Wes[t*64 + (b-128)]);
    } else if (b < 288) {
        int n = b - 192;
        if (t < 288) WTa[n*288 + t] = f2bu(n < 64 ? W1[t*64 + n] : WA[t*32 + (n-64)]);
    } else {
        int n = b - 288;
        if (t < 64)  WT2[n*64 + t] = f2bu(W2[t*64 + n]);
    }
}

// ---------------------------------------------------------------------------
// CSR build: count -> scan -> fill.  Rebuilt every launch (graph-safe).
// ---------------------------------------------------------------------------
__global__ void k_count(const int* __restrict__ n2e, int* __restrict__ cnt)
{
    int e = blockIdx.x * 256 + threadIdx.x;
    atomicAdd(&cnt[n2e[e]], 1);
}

__global__ void k_scan(const int* __restrict__ cnt, int* __restrict__ off,
                       int* __restrict__ cursor)
{
    __shared__ int wa[1024];
    int t = threadIdx.x;
    int a0 = cnt[4*t], a1 = cnt[4*t+1], a2 = cnt[4*t+2], a3 = cnt[4*t+3];
    int s1 = a0 + a1, s2 = s1 + a2, s3 = s2 + a3;
    wa[t] = s3;
    __syncthreads();
    for (int d = 1; d < 1024; d <<= 1) {
        int x = wa[t];
        int y = (t >= d) ? wa[t-d] : 0;
        __syncthreads();
        wa[t] = x + y;
        __syncthreads();
    }
    int excl = (t == 0) ? 0 : wa[t-1];
    off[4*t]   = excl;        cursor[4*t]   = excl;
    off[4*t+1] = excl + a0;   cursor[4*t+1] = excl + a0;
    off[4*t+2] = excl + s1;   cursor[4*t+2] = excl + s1;
    off[4*t+3] = excl + s2;   cursor[4*t+3] = excl + s2;
    if (t == 1023) off[4096] = excl + s3;
}

__global__ void k_fill(const int* __restrict__ n2e, int* __restrict__ cursor,
                       int* __restrict__ csr)
{
    int e = blockIdx.x * 256 + threadIdx.x;
    int pos = atomicAdd(&cursor[n2e[e]], 1);
    csr[pos] = e;
}

// ---------------------------------------------------------------------------
// Fused per-node kernel: edge GEMM (Wne+Wes) + msg accumulation + h2g2
// accumulation + symc + node_self/node_sym GEMMs + n_out + e_out partials.
// One 256-thread block per node; edges gathered via CSR; ZERO global atomics.
// ---------------------------------------------------------------------------
__global__ __launch_bounds__(256) void k_fused_node(
    const float* __restrict__ node_ext, const float* __restrict__ edge_ebd,
    const float* __restrict__ h2,       const float* __restrict__ sw,
    const int* __restrict__ n_ext2e,
    const int* __restrict__ csr,        const int* __restrict__ off,
    const u16* __restrict__ WTe,
    const float* __restrict__ bne, const float* __restrict__ bes,
    const float* __restrict__ e_res0,
    const float* __restrict__ Wns,  const float* __restrict__ bns,
    const float* __restrict__ Wsym, const float* __restrict__ bsym,
    const float* __restrict__ nr0, const float* __restrict__ nr1,
    const float* __restrict__ nr2,
    float* __restrict__ e_out, float* __restrict__ n_out)
{
    __shared__ u16   sA[64][328];
    __shared__ int   s_eid[64];
    __shared__ int   s_g[64];
    __shared__ float s_sw[64];
    __shared__ float s_h2[64][3];
    __shared__ float sred[4][576];   // per-wave h2g2 copies: he[192] | hn[384]
    __shared__ float smsg[128];
    __shared__ float ssym[768];
    __shared__ float sx[128];
    __shared__ float spart[128];

    const int tid = threadIdx.x;
    const int w  = tid >> 6, l = tid & 63;
    const int lr = l & 15, hq = l >> 4, lk = hq * 8;
    const int n = blockIdx.x;
    const int beg = off[n];
    const int cnt0 = off[n+1] - beg;

    if (tid < 128) { sx[tid] = node_ext[(size_t)n*128 + tid]; smsg[tid] = 0.f; }
    __syncthreads();

    // node n's own row -> sA cols 0-127 of ALL 64 rows (constant across tiles)
    #pragma unroll
    for (int f = tid; f < 2048; f += 256) {
        int r = f >> 5, c = f & 31;
        float4 v = make_float4(sx[4*c], sx[4*c+1], sx[4*c+2], sx[4*c+3]);
        st_bf16x4(&sA[r][4*c], v);
    }

    // hoist per-lane output-column constants
    float bias[3], rres[3];
    int   cful[3];
    #pragma unroll
    for (int nf = 0; nf < 3; ++nf) {
        int c = 48*w + 16*nf + lr;
        cful[nf] = c;
        bias[nf] = (c < 128) ? bne[c] : bes[c-128];
        rres[nf] = (c < 128) ? 0.f    : e_res0[c-128];
    }

    float msum[3] = {0.f, 0.f, 0.f};
    float hacc[9] = {0.f,0.f,0.f,0.f,0.f,0.f,0.f,0.f,0.f};

    const float4* node4 = (const float4*)node_ext;
    const float4* edge4 = (const float4*)edge_ebd;

    for (int t0 = 0; t0 < cnt0; t0 += 64) {
        const int rows = min(64, cnt0 - t0);
        __syncthreads();                       // previous tile fully consumed
        if (tid < 64) {
            int r = tid;
            if (r < rows) {
                int e = csr[beg + t0 + r];
                s_eid[r] = e;
                s_g[r]   = n_ext2e[e];
                s_sw[r]  = sw[e];
                s_h2[r][0] = h2[e*3];
                s_h2[r][1] = h2[e*3+1];
                s_h2[r][2] = h2[e*3+2];
            } else {
                s_eid[r] = -1; s_g[r] = 0; s_sw[r] = 0.f;
                s_h2[r][0] = s_h2[r][1] = s_h2[r][2] = 0.f;
            }
        }
        __syncthreads();

        // stage nei-node (cols 128-255) and edge_ebd (cols 256-319)
        #pragma unroll
        for (int f = tid; f < 2048; f += 256) {
            int r = f >> 5, c = f & 31;
            if (r < rows)
                st_bf16x4(&sA[r][128 + 4*c], node4[(size_t)s_g[r]*32 + c]);
            else
                *reinterpret_cast<uint2*>(&sA[r][128 + 4*c]) = make_uint2(0,0);
        }
        #pragma unroll
        for (int f = tid; f < 1024; f += 256) {
            int r = f >> 4, c = f & 15;
            if (r < rows)
                st_bf16x4(&sA[r][256 + 4*c], edge4[(size_t)s_eid[r]*16 + c]);
            else
                *reinterpret_cast<uint2*>(&sA[r][256 + 4*c]) = make_uint2(0,0);
        }
        __syncthreads();

        // ---- MFMA: [64 rows] x [K=320] x [192 cols] ----
        f32x4 acc[4][3] = {};
        #pragma unroll
        for (int kk = 0; kk < 10; ++kk) {
            bf16x8 a[4], b[3];
            #pragma unroll
            for (int m = 0; m < 4; ++m)
                a[m] = *(const bf16x8*)&sA[16*m + lr][kk*32 + lk];
            #pragma unroll
            for (int nf = 0; nf < 3; ++nf)
                b[nf] = *(const bf16x8*)&WTe[(size_t)cful[nf]*320 + kk*32 + lk];
            #pragma unroll
            for (int m = 0; m < 4; ++m)
                #pragma unroll
                for (int nf = 0; nf < 3; ++nf)
                    acc[m][nf] = __builtin_amdgcn_mfma_f32_16x16x32_bf16(a[m], b[nf], acc[m][nf], 0, 0, 0);
        }

        // ---- epilogue: msg partials (c<128) / e_out writes (c>=128) ----
        #pragma unroll
        for (int nf = 0; nf < 3; ++nf) {
            if (cful[nf] < 128) {
                float s = 0.f;
                #pragma unroll
                for (int m = 0; m < 4; ++m)
                    #pragma unroll
                    for (int j = 0; j < 4; ++j) {
                        int r = 16*m + 4*hq + j;
                        s += silu_(acc[m][nf][j] + bias[nf]) * s_sw[r];
                    }
                msum[nf] += s;
            } else {
                int c2 = cful[nf] - 128;
                #pragma unroll
                for (int m = 0; m < 4; ++m)
                    #pragma unroll
                    for (int j = 0; j < 4; ++j) {
                        int r = 16*m + 4*hq + j;
                        int eid = s_eid[r];
                        if (eid >= 0) {
                            float base = bu2f(sA[r][256 + c2]);
                            e_out[(size_t)eid*64 + c2] =
                                base + rres[nf] * silu_(acc[m][nf][j] + bias[nf]);
                        }
                    }
            }
        }

        // ---- h2g2 accumulation: wave w handles rows 16w..16w+15 ----
        #pragma unroll
        for (int i = 0; i < 16; ++i) {
            int r = 16*w + i;
            float swv = s_sw[r];
            float s0 = s_h2[r][0] * swv;
            float s1 = s_h2[r][1] * swv;
            float s2 = s_h2[r][2] * swv;
            float eb = bu2f(sA[r][256 + l]);
            float n0 = bu2f(sA[r][128 + l]);
            float n1 = bu2f(sA[r][192 + l]);
            hacc[0] = fmaf(s0, eb, hacc[0]);
            hacc[1] = fmaf(s1, eb, hacc[1]);
            hacc[2] = fmaf(s2, eb, hacc[2]);
            hacc[3] = fmaf(s0, n0, hacc[3]);
            hacc[4] = fmaf(s0, n1, hacc[4]);
            hacc[5] = fmaf(s1, n0, hacc[5]);
            hacc[6] = fmaf(s1, n1, hacc[6]);
            hacc[7] = fmaf(s2, n0, hacc[7]);
            hacc[8] = fmaf(s2, n1, hacc[8]);
        }
    }

    // ---- msg reduce (4 row-groups per col) via shfl butterfly ----
    #pragma unroll
    for (int nf = 0; nf < 3; ++nf) {
        float v = msum[nf];
        v += __shfl_xor(v, 16);
        v += __shfl_xor(v, 32);
        if (cful[nf] < 128 && hq == 0) smsg[cful[nf]] = v;
    }

    // ---- h2g2 wave copies -> LDS ----
    sred[w][      l]       = hacc[0];
    sred[w][ 64 + l]       = hacc[1];
    sred[w][128 + l]       = hacc[2];
    sred[w][192 +       l] = hacc[3];
    sred[w][192 +  64 + l] = hacc[4];
    sred[w][192 + 128 + l] = hacc[5];
    sred[w][192 + 192 + l] = hacc[6];
    sred[w][192 + 256 + l] = hacc[7];
    sred[w][192 + 320 + l] = hacc[8];
    __syncthreads();

    for (int i = tid; i < 576; i += 256)
        sred[0][i] = sred[0][i] + sred[1][i] + sred[2][i] + sred[3][i];
    __syncthreads();

    // ---- symc from h2g2 ----
    const float SCALE = 1.0f / (6.4f * 3.0f);
    const float* he = &sred[0][0];
    const float* hn = &sred[0][192];
    for (int i = tid; i < 768; i += 256) {
        float s;
        if (i < 256) {
            int a = i >> 6, j = i & 63;
            s = he[a]*he[j] + he[64+a]*he[64+j] + he[128+a]*he[128+j];
        } else {
            int i2 = i - 256;
            int a = i2 >> 7, j = i2 & 127;
            s = hn[a]*hn[j] + hn[128+a]*hn[128+j] + hn[256+a]*hn[256+j];
        }
        ssym[i] = s * SCALE;
    }
    __syncthreads();

    // ---- node_sym GEMM split over two half-K groups + node_self + output ----
    {
        int c = tid & 127, half = tid >> 7;
        float acc2 = 0.f;
        int k0 = half * 384;
        #pragma unroll 8
        for (int k = k0; k < k0 + 384; ++k)
            acc2 = fmaf(ssym[k], Wsym[(size_t)k*128 + c], acc2);
        if (half) spart[c] = acc2;
        __syncthreads();
        if (!half) {
            float accy = acc2 + spart[c];
            float sym_ = silu_(accy + bsym[c]);
            float accs = 0.f;
            #pragma unroll 8
            for (int k = 0; k < 128; ++k)
                accs = fmaf(sx[k], Wns[(size_t)k*128 + c], accs);
            float self_ = silu_(accs + bns[c]);
            float m = smsg[c] * (1.0f / 6.4f);
            n_out[(size_t)n*128 + c] = sx[c] + nr0[c]*self_ + nr1[c]*sym_ + nr2[c]*m;
        }
    }
}

// ---------------------------------------------------------------------------
// K4': angle GEMM via MFMA (unchanged). M-tile=64 angles, K=288, N=96.
// ---------------------------------------------------------------------------
__global__ __launch_bounds__(256) void k_angle_mfma(
    const float* __restrict__ node_ext, const float* __restrict__ edge_ebd,
    const float* __restrict__ angle_ebd, const float* __restrict__ a_sw,
    const int* __restrict__ n2a, const int* __restrict__ eij2a, const int* __restrict__ eik2a,
    const u16* __restrict__ WTa,
    const float* __restrict__ b1, const float* __restrict__ bA,
    const float* __restrict__ a_res0,
    float* __restrict__ reduced, float* __restrict__ a_out)
{
    __shared__ u16 sA[64][296];
    __shared__ int s_na[64], s_ij[64], s_ik[64];
    const int tid = threadIdx.x;
    const int a0 = blockIdx.x * 64;

    if (tid < 64) {
        s_na[tid] = n2a[a0 + tid];
        s_ij[tid] = eij2a[a0 + tid];
        s_ik[tid] = eik2a[a0 + tid];
    }
    __syncthreads();

    const float4* ang4  = (const float4*)angle_ebd;
    const float4* node4 = (const float4*)node_ext;
    const float4* edge4 = (const float4*)edge_ebd;
    #pragma unroll
    for (int f = tid; f < 512; f += 256) {
        int a = f >> 3, c = f & 7;
        st_bf16x4(&sA[a][4*c], ang4[(size_t)(a0 + a)*8 + c]);
    }
    #pragma unroll
    for (int f = tid; f < 2048; f += 256) {
        int a = f >> 5, c = f & 31;
        st_bf16x4(&sA[a][32 + 4*c], node4[(size_t)s_na[a]*32 + c]);
    }
    #pragma unroll
    for (int f = tid; f < 1024; f += 256) {
        int a = f >> 4, c = f & 15;
        st_bf16x4(&sA[a][160 + 4*c], edge4[(size_t)s_ik[a]*16 + c]);
    }
    #pragma unroll
    for (int f = tid; f < 1024; f += 256) {
        int a = f >> 4, c = f & 15;
        st_bf16x4(&sA[a][224 + 4*c], edge4[(size_t)s_ij[a]*16 + c]);
    }
    __syncthreads();

    const int w = tid >> 6, l = tid & 63;
    const int lr = l & 15, lk = (l >> 4) * 8;

    f32x4 acc[6] = {};
    #pragma unroll
    for (int kk = 0; kk < 9; ++kk) {
        bf16x8 a = *(const bf16x8*)&sA[16*w + lr][kk*32 + lk];
        #pragma unroll
        for (int n = 0; n < 6; ++n) {
            bf16x8 b = *(const bf16x8*)&WTa[(size_t)(16*n + lr)*288 + kk*32 + lk];
            acc[n] = __builtin_amdgcn_mfma_f32_16x16x32_bf16(a, b, acc[n], 0, 0, 0);
        }
    }

    #pragma unroll
    for (int n = 0; n < 6; ++n) {
        int c = 16*n + lr;
        if (n < 4) {
            float bb = b1[c];
            #pragma unroll
            for (int j = 0; j < 4; ++j) {
                int r = 16*w + ((l >> 4) << 2) + j;
                float ea = silu_(acc[n][j] + bb) * a_sw[a0 + r];
                atomicAdd(&reduced[(size_t)s_ij[r]*64 + c], ea);
            }
        } else {
            int c2 = c - 64;
            float bb = bA[c2], rr = a_res0[c2];
            #pragma unroll
            for (int j = 0; j < 4; ++j) {
                int r = 16*w + ((l >> 4) << 2) + j;
                size_t idx = (size_t)(a0 + r)*32 + c2;
                a_out[idx] = angle_ebd[idx] + rr * silu_(acc[n][j] + bb);
            }
        }
    }
}

// ---------------------------------------------------------------------------
// K5': edge_angle_msg = silu(reduced @ W2 + b2); e_out += e_res1 * msg
// ---------------------------------------------------------------------------
__global__ __launch_bounds__(256) void k_edgefin_mfma(
    const float* __restrict__ reduced, const u16* __restrict__ WT2,
    const float* __restrict__ b2_, const float* __restrict__ e_res1,
    float* __restrict__ e_out)
{
    __shared__ u16 sR[64][72];
    const int tid = threadIdx.x;
    const int e0 = blockIdx.x * 64;
    const float4* red4 = (const float4*)reduced;
    #pragma unroll
    for (int f = tid; f < 1024; f += 256) {
        int e = f >> 4, c = f & 15;
        st_bf16x4(&sR[e][4*c], red4[(size_t)(e0 + e)*16 + c]);
    }
    __syncthreads();

    const int w = tid >> 6, l = tid & 63;
    const int lr = l & 15, lk = (l >> 4) * 8;

    f32x4 acc[4] = {};
    #pragma unroll
    for (int kk = 0; kk < 2; ++kk) {
        bf16x8 b = *(const bf16x8*)&WT2[(size_t)(16*w + lr)*64 + kk*32 + lk];
        #pragma unroll
        for (int m = 0; m < 4; ++m) {
            bf16x8 a = *(const bf16x8*)&sR[16*m + lr][kk*32 + lk];
            acc[m] = __builtin_amdgcn_mfma_f32_16x16x32_bf16(a, b, acc[m], 0, 0, 0);
        }
    }
    int c = 16*w + lr;
    float bb = b2_[c], rr = e_res1[c];
    #pragma unroll
    for (int m = 0; m < 4; ++m)
        #pragma unroll
        for (int j = 0; j < 4; ++j) {
            size_t idx = (size_t)(e0 + 16*m + ((l >> 4) << 2) + j)*64 + c;
            e_out[idx] += rr * silu_(acc[m][j] + bb);
        }
}

// ---------------------------------------------------------------------------
extern "C" void kernel_launch(void* const* d_in, const int* in_sizes, int n_in,
                              void* d_out, int out_size, void* d_ws, size_t ws_size,
                              hipStream_t stream)
{
    const float* node_ext  = (const float*)d_in[0];
    const float* edge_ebd  = (const float*)d_in[1];
    const float* h2        = (const float*)d_in[2];
    const float* angle_ebd = (const float*)d_in[3];
    const float* sw        = (const float*)d_in[6];
    const float* a_sw      = (const float*)d_in[9];
    const int*  edge_index  = (const int*)d_in[10];
    const int*  angle_index = (const int*)d_in[11];
    const int* n2e     = edge_index;
    const int* n_ext2e = edge_index + NEDGE_;
    const int* n2a     = angle_index;
    const int* eij2a   = angle_index + NANGLE_;
    const int* eik2a   = angle_index + 2*NANGLE_;

    const float* Wns  = (const float*)d_in[12];
    const float* bns  = (const float*)d_in[13];
    const float* Wsym = (const float*)d_in[14];
    const float* bsym = (const float*)d_in[15];
    const float* Wne  = (const float*)d_in[16];
    const float* bne  = (const float*)d_in[17];
    const float* Wes  = (const float*)d_in[18];
    const float* bes  = (const float*)d_in[19];
    const float* W1   = (const float*)d_in[20];
    const float* b1   = (const float*)d_in[21];
    const float* W2   = (const float*)d_in[22];
    const float* b2_  = (const float*)d_in[23];
    const float* WA   = (const float*)d_in[24];
    const float* bA   = (const float*)d_in[25];
    const float* nr0  = (const float*)d_in[26];
    const float* nr1  = (const float*)d_in[27];
    const float* nr2  = (const float*)d_in[28];
    const float* er0  = (const float*)d_in[29];
    const float* er1  = (const float*)d_in[30];
    const float* ar0  = (const float*)d_in[31];

    // workspace layout
    char* wsp = (char*)d_ws;
    float* reduced = (float*)wsp;  wsp += (size_t)NEDGE_ * 64 * 4;
    int*   cnt     = (int*)wsp;    wsp += 4096 * 4;
    int*   off     = (int*)wsp;    wsp += 4104 * 4;   // 4097 (+pad)
    int*   cursor  = (int*)wsp;    wsp += 4096 * 4;
    int*   csr     = (int*)wsp;    wsp += (size_t)NEDGE_ * 4;
    wsp = (char*)(((uintptr_t)wsp + 63) & ~(uintptr_t)63);
    u16*   WTe     = (u16*)wsp;    wsp += 192 * 320 * 2;
    u16*   WTa     = (u16*)wsp;    wsp += 96 * 288 * 2;
    u16*   WT2     = (u16*)wsp;    wsp += 64 * 64 * 2;

    // zero reduced + cnt in one call (contiguous)
    hipMemsetAsync(reduced, 0, (size_t)NEDGE_ * 64 * 4 + 4096 * 4, stream);

    float* n_out = (float*)d_out;
    float* e_out = n_out + (size_t)NLOC_ * 128;
    float* a_out = e_out + (size_t)NEDGE_ * 64;

    k_prep  <<<352, 320, 0, stream>>>(Wne, Wes, W1, WA, W2, WTe, WTa, WT2);
    k_count <<<NEDGE_/256, 256, 0, stream>>>(n2e, cnt);
    k_scan  <<<1, 1024, 0, stream>>>(cnt, off, cursor);
    k_fill  <<<NEDGE_/256, 256, 0, stream>>>(n2e, cursor, csr);

    k_fused_node <<<NLOC_, 256, 0, stream>>>(node_ext, edge_ebd, h2, sw,
                                             n_ext2e, csr, off,
                                             WTe, bne, bes, er0,
                                             Wns, bns, Wsym, bsym,
                                             nr0, nr1, nr2,
                                             e_out, n_out);
    k_angle_mfma <<<NANGLE_/64, 256, 0, stream>>>(node_ext, edge_ebd, angle_ebd, a_sw,
                                                  n2a, eij2a, eik2a,
                                                  WTa, b1, bA, ar0, reduced, a_out);
    k_edgefin_mfma <<<NEDGE_/64, 256, 0, stream>>>(reduced, WT2, b2_, er1, e_out);
}

// Round 5
// 752.379 us; speedup vs baseline: 5.6718x; 1.2277x over previous
//
#include <hip/hip_runtime.h>
#include <hip/hip_bf16.h>

#define NLOC_   4096
#define NALL_   6144
#define NEDGE_  262144
#define NANGLE_ 409600

typedef __bf16 bf16x8 __attribute__((ext_vector_type(8)));
typedef float  f32x4  __attribute__((ext_vector_type(4)));
typedef unsigned short u16;

__device__ __forceinline__ float silu_(float x){ return x / (1.0f + __expf(-x)); }

__device__ __forceinline__ u16 f2bu(float f){
    union { float f; unsigned u; } v; v.f = f;
    unsigned r = v.u + 0x7fffu + ((v.u >> 16) & 1u);
    return (u16)(r >> 16);
}
__device__ __forceinline__ float bu2f(u16 b){
    union { unsigned u; float f; } v; v.u = ((unsigned)b) << 16; return v.f;
}
__device__ __forceinline__ void st_bf16x4(u16* dst, float4 v){
    unsigned lo = (unsigned)f2bu(v.x) | ((unsigned)f2bu(v.y) << 16);
    unsigned hi = (unsigned)f2bu(v.z) | ((unsigned)f2bu(v.w) << 16);
    *reinterpret_cast<uint2*>(dst) = make_uint2(lo, hi);
}

// ---------------------------------------------------------------------------
// Prep: bf16-transposed weights.  WTe[192][320] (cols 0-127=Wne, 128-191=Wes)
// WTa[96][288] (0-63=W1, 64-95=WA), WT2[64][64] (W2).
// ---------------------------------------------------------------------------
__global__ void k_prep(const float* __restrict__ Wne, const float* __restrict__ Wes,
                       const float* __restrict__ W1,  const float* __restrict__ WA,
                       const float* __restrict__ W2,
                       u16* __restrict__ WTe, u16* __restrict__ WTa, u16* __restrict__ WT2)
{
    int b = blockIdx.x, t = threadIdx.x;
    if (b < 192) {
        if (t < 320) WTe[b*320 + t] = f2bu(b < 128 ? Wne[t*128 + b] : Wes[t*64 + (b-128)]);
    } else if (b < 288) {
        int n = b - 192;
        if (t < 288) WTa[n*288 + t] = f2bu(n < 64 ? W1[t*64 + n] : WA[t*32 + (n-64)]);
    } else {
        int n = b - 288;
        if (t < 64)  WT2[n*64 + t] = f2bu(W2[t*64 + n]);
    }
}

// ---------------------------------------------------------------------------
// nconst[n][c] = node_ebd[n] @ W[0:128][c]  for all 192 output cols (MFMA).
// 64-node tiles, K=128.
// ---------------------------------------------------------------------------
__global__ __launch_bounds__(256) void k_nconst(
    const float* __restrict__ node_ext, const u16* __restrict__ WTe,
    float* __restrict__ nconst)
{
    __shared__ u16 sN[64][136];
    const int tid = threadIdx.x;
    const int e0 = blockIdx.x * 64;
    const float4* node4 = (const float4*)node_ext;
    #pragma unroll
    for (int f = tid; f < 2048; f += 256) {
        int r = f >> 5, c = f & 31;
        st_bf16x4(&sN[r][4*c], node4[(size_t)(e0 + r)*32 + c]);
    }
    __syncthreads();

    const int w = tid >> 6, l = tid & 63;
    const int lr = l & 15, hq = l >> 4, lk = hq * 8;

    f32x4 acc[4][3] = {};
    #pragma unroll
    for (int kk = 0; kk < 4; ++kk) {
        bf16x8 a[4], b[3];
        #pragma unroll
        for (int m = 0; m < 4; ++m)
            a[m] = *(const bf16x8*)&sN[16*m + lr][kk*32 + lk];
        #pragma unroll
        for (int nf = 0; nf < 3; ++nf)
            b[nf] = *(const bf16x8*)&WTe[(size_t)(48*w + 16*nf + lr)*320 + kk*32 + lk];
        #pragma unroll
        for (int m = 0; m < 4; ++m)
            #pragma unroll
            for (int nf = 0; nf < 3; ++nf)
                acc[m][nf] = __builtin_amdgcn_mfma_f32_16x16x32_bf16(a[m], b[nf], acc[m][nf], 0, 0, 0);
    }
    #pragma unroll
    for (int nf = 0; nf < 3; ++nf) {
        int c = 48*w + 16*nf + lr;
        #pragma unroll
        for (int m = 0; m < 4; ++m)
            #pragma unroll
            for (int j = 0; j < 4; ++j) {
                int r = 16*m + 4*hq + j;
                nconst[(size_t)(e0 + r)*192 + c] = acc[m][nf][j];
            }
    }
}

// ---------------------------------------------------------------------------
// CSR build: count -> scan -> fill.
// ---------------------------------------------------------------------------
__global__ void k_count(const int* __restrict__ n2e, int* __restrict__ cnt)
{
    int e = blockIdx.x * 256 + threadIdx.x;
    atomicAdd(&cnt[n2e[e]], 1);
}

__global__ void k_scan(const int* __restrict__ cnt, int* __restrict__ off,
                       int* __restrict__ cursor)
{
    __shared__ int wa[1024];
    int t = threadIdx.x;
    int a0 = cnt[4*t], a1 = cnt[4*t+1], a2 = cnt[4*t+2], a3 = cnt[4*t+3];
    int s1 = a0 + a1, s2 = s1 + a2, s3 = s2 + a3;
    wa[t] = s3;
    __syncthreads();
    for (int d = 1; d < 1024; d <<= 1) {
        int x = wa[t];
        int y = (t >= d) ? wa[t-d] : 0;
        __syncthreads();
        wa[t] = x + y;
        __syncthreads();
    }
    int excl = (t == 0) ? 0 : wa[t-1];
    off[4*t]   = excl;        cursor[4*t]   = excl;
    off[4*t+1] = excl + a0;   cursor[4*t+1] = excl + a0;
    off[4*t+2] = excl + s1;   cursor[4*t+2] = excl + s1;
    off[4*t+3] = excl + s2;   cursor[4*t+3] = excl + s2;
    if (t == 1023) off[4096] = excl + s3;
}

__global__ void k_fill(const int* __restrict__ n2e, int* __restrict__ cursor,
                       int* __restrict__ csr)
{
    int e = blockIdx.x * 256 + threadIdx.x;
    int pos = atomicAdd(&cursor[n2e[e]], 1);
    csr[pos] = e;
}

// ---------------------------------------------------------------------------
// Fused per-node edge kernel: edge GEMM (K=192, node-self part hoisted into
// nconst) + msg accumulation + h2g2 accumulation + e_out partials.
// One 256-thread block per node; zero global atomics; ~27 KB LDS.
// ---------------------------------------------------------------------------
__global__ __launch_bounds__(256) void k_fused_node(
    const float* __restrict__ node_ext, const float* __restrict__ edge_ebd,
    const float* __restrict__ h2,       const float* __restrict__ sw,
    const int* __restrict__ n_ext2e,
    const int* __restrict__ csr,        const int* __restrict__ off,
    const u16* __restrict__ WTe,        const float* __restrict__ nconst,
    const float* __restrict__ bne, const float* __restrict__ bes,
    const float* __restrict__ e_res0,
    float* __restrict__ msg, float* __restrict__ h2g2_e, float* __restrict__ h2g2_n,
    float* __restrict__ e_out)
{
    __shared__ __align__(16) u16 sA[64][200];   // cols 0-127 nei node, 128-191 edge
    __shared__ int   s_eid[64];
    __shared__ int   s_g[64];
    __shared__ float s_sw[64];
    __shared__ float s_h2[64][3];

    const int tid = threadIdx.x;
    const int w  = tid >> 6, l = tid & 63;
    const int lr = l & 15, hq = l >> 4, lk = hq * 8;
    const int n = blockIdx.x;
    const int beg = off[n];
    const int cnt0 = off[n+1] - beg;

    // per-lane output-column constants
    float bias[3], rres[3], ncv[3];
    int   cful[3];
    #pragma unroll
    for (int nf = 0; nf < 3; ++nf) {
        int c = 48*w + 16*nf + lr;
        cful[nf] = c;
        ncv[nf]  = nconst[(size_t)n*192 + c];
        bias[nf] = (c < 128) ? bne[c] : bes[c-128];
        rres[nf] = (c < 128) ? 0.f    : e_res0[c-128];
    }

    float msum[3] = {0.f, 0.f, 0.f};
    float hacc[9] = {0.f,0.f,0.f,0.f,0.f,0.f,0.f,0.f,0.f};

    const float4* node4 = (const float4*)node_ext;
    const float4* edge4 = (const float4*)edge_ebd;

    for (int t0 = 0; t0 < cnt0; t0 += 64) {
        const int rows = min(64, cnt0 - t0);
        __syncthreads();
        if (tid < 64) {
            int r = tid;
            if (r < rows) {
                int e = csr[beg + t0 + r];
                s_eid[r] = e;
                s_g[r]   = n_ext2e[e];
                s_sw[r]  = sw[e];
                s_h2[r][0] = h2[e*3];
                s_h2[r][1] = h2[e*3+1];
                s_h2[r][2] = h2[e*3+2];
            } else {
                s_eid[r] = -1; s_g[r] = 0; s_sw[r] = 0.f;
                s_h2[r][0] = s_h2[r][1] = s_h2[r][2] = 0.f;
            }
        }
        __syncthreads();

        #pragma unroll
        for (int f = tid; f < 2048; f += 256) {       // nei node -> cols 0-127
            int r = f >> 5, c = f & 31;
            if (r < rows)
                st_bf16x4(&sA[r][4*c], node4[(size_t)s_g[r]*32 + c]);
            else
                *reinterpret_cast<uint2*>(&sA[r][4*c]) = make_uint2(0,0);
        }
        #pragma unroll
        for (int f = tid; f < 1024; f += 256) {       // edge -> cols 128-191
            int r = f >> 4, c = f & 15;
            if (r < rows)
                st_bf16x4(&sA[r][128 + 4*c], edge4[(size_t)s_eid[r]*16 + c]);
            else
                *reinterpret_cast<uint2*>(&sA[r][128 + 4*c]) = make_uint2(0,0);
        }
        __syncthreads();

        // ---- MFMA: [64 rows] x [K=192] x [192 cols] ----
        f32x4 acc[4][3] = {};
        #pragma unroll
        for (int kk = 0; kk < 6; ++kk) {
            bf16x8 a[4], b[3];
            #pragma unroll
            for (int m = 0; m < 4; ++m)
                a[m] = *(const bf16x8*)&sA[16*m + lr][kk*32 + lk];
            #pragma unroll
            for (int nf = 0; nf < 3; ++nf)
                b[nf] = *(const bf16x8*)&WTe[(size_t)cful[nf]*320 + 128 + kk*32 + lk];
            #pragma unroll
            for (int m = 0; m < 4; ++m)
                #pragma unroll
                for (int nf = 0; nf < 3; ++nf)
                    acc[m][nf] = __builtin_amdgcn_mfma_f32_16x16x32_bf16(a[m], b[nf], acc[m][nf], 0, 0, 0);
        }

        // ---- epilogue ----
        #pragma unroll
        for (int nf = 0; nf < 3; ++nf) {
            if (cful[nf] < 128) {
                float s = 0.f;
                #pragma unroll
                for (int m = 0; m < 4; ++m)
                    #pragma unroll
                    for (int j = 0; j < 4; ++j) {
                        int r = 16*m + 4*hq + j;
                        s += silu_(acc[m][nf][j] + ncv[nf] + bias[nf]) * s_sw[r];
                    }
                msum[nf] += s;
            } else {
                int c2 = cful[nf] - 128;
                #pragma unroll
                for (int m = 0; m < 4; ++m)
                    #pragma unroll
                    for (int j = 0; j < 4; ++j) {
                        int r = 16*m + 4*hq + j;
                        int eid = s_eid[r];
                        if (eid >= 0) {
                            float base = bu2f(sA[r][128 + c2]);
                            e_out[(size_t)eid*64 + c2] =
                                base + rres[nf] * silu_(acc[m][nf][j] + ncv[nf] + bias[nf]);
                        }
                    }
            }
        }

        // ---- h2g2 accumulation: wave w handles rows 16w..16w+15 ----
        #pragma unroll
        for (int i = 0; i < 16; ++i) {
            int r = 16*w + i;
            float swv = s_sw[r];
            float s0 = s_h2[r][0] * swv;
            float s1 = s_h2[r][1] * swv;
            float s2 = s_h2[r][2] * swv;
            float eb = bu2f(sA[r][128 + l]);
            float n0 = bu2f(sA[r][l]);
            float n1 = bu2f(sA[r][64 + l]);
            hacc[0] = fmaf(s0, eb, hacc[0]);
            hacc[1] = fmaf(s1, eb, hacc[1]);
            hacc[2] = fmaf(s2, eb, hacc[2]);
            hacc[3] = fmaf(s0, n0, hacc[3]);
            hacc[4] = fmaf(s0, n1, hacc[4]);
            hacc[5] = fmaf(s1, n0, hacc[5]);
            hacc[6] = fmaf(s1, n1, hacc[6]);
            hacc[7] = fmaf(s2, n0, hacc[7]);
            hacc[8] = fmaf(s2, n1, hacc[8]);
        }
    }

    // ---- msg reduce across hq groups, write to ws ----
    #pragma unroll
    for (int nf = 0; nf < 3; ++nf) {
        float v = msum[nf];
        v += __shfl_xor(v, 16);
        v += __shfl_xor(v, 32);
        if (cful[nf] < 128 && hq == 0) msg[(size_t)n*128 + cful[nf]] = v;
    }

    // ---- h2g2: per-wave partials into LDS (aliasing sA), reduce, write ----
    __syncthreads();
    float* sred = (float*)&sA[0][0];   // 4 x 576 f32 = 9216 B  (sA is dead)
    sred[w*576 +       l] = hacc[0];
    sred[w*576 +  64 + l] = hacc[1];
    sred[w*576 + 128 + l] = hacc[2];
    sred[w*576 + 192 +       l] = hacc[3];
    sred[w*576 + 192 +  64 + l] = hacc[4];
    sred[w*576 + 192 + 128 + l] = hacc[5];
    sred[w*576 + 192 + 192 + l] = hacc[6];
    sred[w*576 + 192 + 256 + l] = hacc[7];
    sred[w*576 + 192 + 320 + l] = hacc[8];
    __syncthreads();
    for (int i = tid; i < 576; i += 256) {
        float v = sred[i] + sred[576 + i] + sred[1152 + i] + sred[1728 + i];
        if (i < 192) h2g2_e[(size_t)n*192 + i] = v;
        else         h2g2_n[(size_t)n*384 + (i - 192)] = v;
    }
}

// ---------------------------------------------------------------------------
// K4': angle GEMM via MFMA (unchanged).
// ---------------------------------------------------------------------------
__global__ __launch_bounds__(256) void k_angle_mfma(
    const float* __restrict__ node_ext, const float* __restrict__ edge_ebd,
    const float* __restrict__ angle_ebd, const float* __restrict__ a_sw,
    const int* __restrict__ n2a, const int* __restrict__ eij2a, const int* __restrict__ eik2a,
    const u16* __restrict__ WTa,
    const float* __restrict__ b1, const float* __restrict__ bA,
    const float* __restrict__ a_res0,
    float* __restrict__ reduced, float* __restrict__ a_out)
{
    __shared__ u16 sA[64][296];
    __shared__ int s_na[64], s_ij[64], s_ik[64];
    const int tid = threadIdx.x;
    const int a0 = blockIdx.x * 64;

    if (tid < 64) {
        s_na[tid] = n2a[a0 + tid];
        s_ij[tid] = eij2a[a0 + tid];
        s_ik[tid] = eik2a[a0 + tid];
    }
    __syncthreads();

    const float4* ang4  = (const float4*)angle_ebd;
    const float4* node4 = (const float4*)node_ext;
    const float4* edge4 = (const float4*)edge_ebd;
    #pragma unroll
    for (int f = tid; f < 512; f += 256) {
        int a = f >> 3, c = f & 7;
        st_bf16x4(&sA[a][4*c], ang4[(size_t)(a0 + a)*8 + c]);
    }
    #pragma unroll
    for (int f = tid; f < 2048; f += 256) {
        int a = f >> 5, c = f & 31;
        st_bf16x4(&sA[a][32 + 4*c], node4[(size_t)s_na[a]*32 + c]);
    }
    #pragma unroll
    for (int f = tid; f < 1024; f += 256) {
        int a = f >> 4, c = f & 15;
        st_bf16x4(&sA[a][160 + 4*c], edge4[(size_t)s_ik[a]*16 + c]);
    }
    #pragma unroll
    for (int f = tid; f < 1024; f += 256) {
        int a = f >> 4, c = f & 15;
        st_bf16x4(&sA[a][224 + 4*c], edge4[(size_t)s_ij[a]*16 + c]);
    }
    __syncthreads();

    const int w = tid >> 6, l = tid & 63;
    const int lr = l & 15, lk = (l >> 4) * 8;

    f32x4 acc[6] = {};
    #pragma unroll
    for (int kk = 0; kk < 9; ++kk) {
        bf16x8 a = *(const bf16x8*)&sA[16*w + lr][kk*32 + lk];
        #pragma unroll
        for (int n = 0; n < 6; ++n) {
            bf16x8 b = *(const bf16x8*)&WTa[(size_t)(16*n + lr)*288 + kk*32 + lk];
            acc[n] = __builtin_amdgcn_mfma_f32_16x16x32_bf16(a, b, acc[n], 0, 0, 0);
        }
    }

    #pragma unroll
    for (int n = 0; n < 6; ++n) {
        int c = 16*n + lr;
        if (n < 4) {
            float bb = b1[c];
            #pragma unroll
            for (int j = 0; j < 4; ++j) {
                int r = 16*w + ((l >> 4) << 2) + j;
                float ea = silu_(acc[n][j] + bb) * a_sw[a0 + r];
                atomicAdd(&reduced[(size_t)s_ij[r]*64 + c], ea);
            }
        } else {
            int c2 = c - 64;
            float bb = bA[c2], rr = a_res0[c2];
            #pragma unroll
            for (int j = 0; j < 4; ++j) {
                int r = 16*w + ((l >> 4) << 2) + j;
                size_t idx = (size_t)(a0 + r)*32 + c2;
                a_out[idx] = angle_ebd[idx] + rr * silu_(acc[n][j] + bb);
            }
        }
    }
}

// ---------------------------------------------------------------------------
// K5': edge_angle_msg = silu(reduced @ W2 + b2); e_out += e_res1 * msg
// ---------------------------------------------------------------------------
__global__ __launch_bounds__(256) void k_edgefin_mfma(
    const float* __restrict__ reduced, const u16* __restrict__ WT2,
    const float* __restrict__ b2_, const float* __restrict__ e_res1,
    float* __restrict__ e_out)
{
    __shared__ u16 sR[64][72];
    const int tid = threadIdx.x;
    const int e0 = blockIdx.x * 64;
    const float4* red4 = (const float4*)reduced;
    #pragma unroll
    for (int f = tid; f < 1024; f += 256) {
        int e = f >> 4, c = f & 15;
        st_bf16x4(&sR[e][4*c], red4[(size_t)(e0 + e)*16 + c]);
    }
    __syncthreads();

    const int w = tid >> 6, l = tid & 63;
    const int lr = l & 15, lk = (l >> 4) * 8;

    f32x4 acc[4] = {};
    #pragma unroll
    for (int kk = 0; kk < 2; ++kk) {
        bf16x8 b = *(const bf16x8*)&WT2[(size_t)(16*w + lr)*64 + kk*32 + lk];
        #pragma unroll
        for (int m = 0; m < 4; ++m) {
            bf16x8 a = *(const bf16x8*)&sR[16*m + lr][kk*32 + lk];
            acc[m] = __builtin_amdgcn_mfma_f32_16x16x32_bf16(a, b, acc[m], 0, 0, 0);
        }
    }
    int c = 16*w + lr;
    float bb = b2_[c], rr = e_res1[c];
    #pragma unroll
    for (int m = 0; m < 4; ++m)
        #pragma unroll
        for (int j = 0; j < 4; ++j) {
            size_t idx = (size_t)(e0 + 16*m + ((l >> 4) << 2) + j)*64 + c;
            e_out[idx] += rr * silu_(acc[m][j] + bb);
        }
}

// ---------------------------------------------------------------------------
// K2: per-node finalize (round-3 version, reads ws msg/h2g2).
// ---------------------------------------------------------------------------
__global__ void k_node_final(const float* __restrict__ node_ext,
                             const float* __restrict__ h2g2_e,
                             const float* __restrict__ h2g2_n,
                             const float* __restrict__ msg,
                             const float* __restrict__ Wns,  const float* __restrict__ bns,
                             const float* __restrict__ Wsym, const float* __restrict__ bsym,
                             const float* __restrict__ nr0, const float* __restrict__ nr1,
                             const float* __restrict__ nr2,
                             float* __restrict__ n_out)
{
    __shared__ float x[128];
    __shared__ float he[192];
    __shared__ float hn[384];
    __shared__ float symc[768];

    int n = blockIdx.x;
    int c = threadIdx.x;

    x[c] = node_ext[(size_t)n*128 + c];
    for (int i = c; i < 192; i += 128) he[i] = h2g2_e[(size_t)n*192 + i];
    for (int i = c; i < 384; i += 128) hn[i] = h2g2_n[(size_t)n*384 + i];
    __syncthreads();

    const float SCALE = 1.0f / (6.4f * 3.0f);
    for (int i = c; i < 768; i += 128) {
        float s;
        if (i < 256) {
            int a = i >> 6, j = i & 63;
            s = he[a]*he[j] + he[64+a]*he[64+j] + he[128+a]*he[128+j];
        } else {
            int i2 = i - 256;
            int a = i2 >> 7, j = i2 & 127;
            s = hn[a]*hn[j] + hn[128+a]*hn[128+j] + hn[256+a]*hn[256+j];
        }
        symc[i] = s * SCALE;
    }
    __syncthreads();

    float accs = 0.f;
    #pragma unroll 8
    for (int k = 0; k < 128; ++k) accs = fmaf(x[k], Wns[k*128 + c], accs);
    float self_ = silu_(accs + bns[c]);

    float accy = 0.f;
    #pragma unroll 8
    for (int k = 0; k < 768; ++k) accy = fmaf(symc[k], Wsym[k*128 + c], accy);
    float sym_ = silu_(accy + bsym[c]);

    float m = msg[(size_t)n*128 + c] * (1.0f / 6.4f);
    n_out[(size_t)n*128 + c] = x[c] + nr0[c]*self_ + nr1[c]*sym_ + nr2[c]*m;
}

// ---------------------------------------------------------------------------
extern "C" void kernel_launch(void* const* d_in, const int* in_sizes, int n_in,
                              void* d_out, int out_size, void* d_ws, size_t ws_size,
                              hipStream_t stream)
{
    const float* node_ext  = (const float*)d_in[0];
    const float* edge_ebd  = (const float*)d_in[1];
    const float* h2        = (const float*)d_in[2];
    const float* angle_ebd = (const float*)d_in[3];
    const float* sw        = (const float*)d_in[6];
    const float* a_sw      = (const float*)d_in[9];
    const int*  edge_index  = (const int*)d_in[10];
    const int*  angle_index = (const int*)d_in[11];
    const int* n2e     = edge_index;
    const int* n_ext2e = edge_index + NEDGE_;
    const int* n2a     = angle_index;
    const int* eij2a   = angle_index + NANGLE_;
    const int* eik2a   = angle_index + 2*NANGLE_;

    const float* Wns  = (const float*)d_in[12];
    const float* bns  = (const float*)d_in[13];
    const float* Wsym = (const float*)d_in[14];
    const float* bsym = (const float*)d_in[15];
    const float* Wne  = (const float*)d_in[16];
    const float* bne  = (const float*)d_in[17];
    const float* Wes  = (const float*)d_in[18];
    const float* bes  = (const float*)d_in[19];
    const float* W1   = (const float*)d_in[20];
    const float* b1   = (const float*)d_in[21];
    const float* W2   = (const float*)d_in[22];
    const float* b2_  = (const float*)d_in[23];
    const float* WA   = (const float*)d_in[24];
    const float* bA   = (const float*)d_in[25];
    const float* nr0  = (const float*)d_in[26];
    const float* nr1  = (const float*)d_in[27];
    const float* nr2  = (const float*)d_in[28];
    const float* er0  = (const float*)d_in[29];
    const float* er1  = (const float*)d_in[30];
    const float* ar0  = (const float*)d_in[31];

    // workspace layout
    char* wsp = (char*)d_ws;
    float* reduced = (float*)wsp;  wsp += (size_t)NEDGE_ * 64 * 4;
    int*   cnt     = (int*)wsp;    wsp += 4096 * 4;
    int*   off     = (int*)wsp;    wsp += 4104 * 4;
    int*   cursor  = (int*)wsp;    wsp += 4096 * 4;
    int*   csr     = (int*)wsp;    wsp += (size_t)NEDGE_ * 4;
    float* h2g2_e  = (float*)wsp;  wsp += (size_t)NLOC_ * 192 * 4;
    float* h2g2_n  = (float*)wsp;  wsp += (size_t)NLOC_ * 384 * 4;
    float* msg     = (float*)wsp;  wsp += (size_t)NLOC_ * 128 * 4;
    float* nconst  = (float*)wsp;  wsp += (size_t)NLOC_ * 192 * 4;
    wsp = (char*)(((uintptr_t)wsp + 63) & ~(uintptr_t)63);
    u16*   WTe     = (u16*)wsp;    wsp += 192 * 320 * 2;
    u16*   WTa     = (u16*)wsp;    wsp += 96 * 288 * 2;
    u16*   WT2     = (u16*)wsp;    wsp += 64 * 64 * 2;

    // zero reduced + cnt (contiguous)
    hipMemsetAsync(reduced, 0, (size_t)NEDGE_ * 64 * 4 + 4096 * 4, stream);

    float* n_out = (float*)d_out;
    float* e_out = n_out + (size_t)NLOC_ * 128;
    float* a_out = e_out + (size_t)NEDGE_ * 64;

    k_prep   <<<352, 320, 0, stream>>>(Wne, Wes, W1, WA, W2, WTe, WTa, WT2);
    k_nconst <<<NLOC_/64, 256, 0, stream>>>(node_ext, WTe, nconst);
    k_count  <<<NEDGE_/256, 256, 0, stream>>>(n2e, cnt);
    k_scan   <<<1, 1024, 0, stream>>>(cnt, off, cursor);
    k_fill   <<<NEDGE_/256, 256, 0, stream>>>(n2e, cursor, csr);

    k_fused_node <<<NLOC_, 256, 0, stream>>>(node_ext, edge_ebd, h2, sw,
                                             n_ext2e, csr, off,
                                             WTe, nconst, bne, bes, er0,
                                             msg, h2g2_e, h2g2_n, e_out);
    k_angle_mfma <<<NANGLE_/64, 256, 0, stream>>>(node_ext, edge_ebd, angle_ebd, a_sw,
                                                  n2a, eij2a, eik2a,
                                                  WTa, b1, bA, ar0, reduced, a_out);
    k_edgefin_mfma <<<NEDGE_/64, 256, 0, stream>>>(reduced, WT2, b2_, er1, e_out);
    k_node_final <<<NLOC_, 128, 0, stream>>>(node_ext, h2g2_e, h2g2_n, msg,
                                             Wns, bns, Wsym, bsym,
                                             nr0, nr1, nr2, n_out);
}

// Round 6
// 573.412 us; speedup vs baseline: 7.4421x; 1.3121x over previous
//
#include <hip/hip_runtime.h>
#include <hip/hip_bf16.h>

#define NLOC_   4096
#define NALL_   6144
#define NEDGE_  262144
#define NANGLE_ 409600

typedef __bf16 bf16x8 __attribute__((ext_vector_type(8)));
typedef float  f32x4  __attribute__((ext_vector_type(4)));
typedef unsigned short u16;

__device__ __forceinline__ float silu_(float x){ return x / (1.0f + __expf(-x)); }

__device__ __forceinline__ u16 f2bu(float f){
    union { float f; unsigned u; } v; v.f = f;
    unsigned r = v.u + 0x7fffu + ((v.u >> 16) & 1u);
    return (u16)(r >> 16);
}
__device__ __forceinline__ float bu2f(u16 b){
    union { unsigned u; float f; } v; v.u = ((unsigned)b) << 16; return v.f;
}
__device__ __forceinline__ void st_bf16x4(u16* dst, float4 v){
    unsigned lo = (unsigned)f2bu(v.x) | ((unsigned)f2bu(v.y) << 16);
    unsigned hi = (unsigned)f2bu(v.z) | ((unsigned)f2bu(v.w) << 16);
    *reinterpret_cast<uint2*>(dst) = make_uint2(lo, hi);
}

// ---------------------------------------------------------------------------
// Prep: bf16-transposed weights.
// ---------------------------------------------------------------------------
__global__ void k_prep(const float* __restrict__ Wne, const float* __restrict__ Wes,
                       const float* __restrict__ W1,  const float* __restrict__ WA,
                       const float* __restrict__ W2,
                       u16* __restrict__ WTe, u16* __restrict__ WTa, u16* __restrict__ WT2)
{
    int b = blockIdx.x, t = threadIdx.x;
    if (b < 192) {
        if (t < 320) WTe[b*320 + t] = f2bu(b < 128 ? Wne[t*128 + b] : Wes[t*64 + (b-128)]);
    } else if (b < 288) {
        int n = b - 192;
        if (t < 288) WTa[n*288 + t] = f2bu(n < 64 ? W1[t*64 + n] : WA[t*32 + (n-64)]);
    } else {
        int n = b - 288;
        if (t < 64)  WT2[n*64 + t] = f2bu(W2[t*64 + n]);
    }
}

// ---------------------------------------------------------------------------
// nconst[n][c] = node_ebd[n] @ W[0:128][c]  for all 192 output cols (MFMA).
// ---------------------------------------------------------------------------
__global__ __launch_bounds__(256) void k_nconst(
    const float* __restrict__ node_ext, const u16* __restrict__ WTe,
    float* __restrict__ nconst)
{
    __shared__ u16 sN[64][136];
    const int tid = threadIdx.x;
    const int e0 = blockIdx.x * 64;
    const float4* node4 = (const float4*)node_ext;
    #pragma unroll
    for (int f = tid; f < 2048; f += 256) {
        int r = f >> 5, c = f & 31;
        st_bf16x4(&sN[r][4*c], node4[(size_t)(e0 + r)*32 + c]);
    }
    __syncthreads();

    const int w = tid >> 6, l = tid & 63;
    const int lr = l & 15, hq = l >> 4, lk = hq * 8;

    f32x4 acc[4][3] = {};
    #pragma unroll
    for (int kk = 0; kk < 4; ++kk) {
        bf16x8 a[4], b[3];
        #pragma unroll
        for (int m = 0; m < 4; ++m)
            a[m] = *(const bf16x8*)&sN[16*m + lr][kk*32 + lk];
        #pragma unroll
        for (int nf = 0; nf < 3; ++nf)
            b[nf] = *(const bf16x8*)&WTe[(size_t)(48*w + 16*nf + lr)*320 + kk*32 + lk];
        #pragma unroll
        for (int m = 0; m < 4; ++m)
            #pragma unroll
            for (int nf = 0; nf < 3; ++nf)
                acc[m][nf] = __builtin_amdgcn_mfma_f32_16x16x32_bf16(a[m], b[nf], acc[m][nf], 0, 0, 0);
    }
    #pragma unroll
    for (int nf = 0; nf < 3; ++nf) {
        int c = 48*w + 16*nf + lr;
        #pragma unroll
        for (int m = 0; m < 4; ++m)
            #pragma unroll
            for (int j = 0; j < 4; ++j) {
                int r = 16*m + 4*hq + j;
                nconst[(size_t)(e0 + r)*192 + c] = acc[m][nf][j];
            }
    }
}

// ---------------------------------------------------------------------------
// CSR build: count -> scan -> fill.
// ---------------------------------------------------------------------------
__global__ void k_count(const int* __restrict__ n2e, int* __restrict__ cnt)
{
    int e = blockIdx.x * 256 + threadIdx.x;
    atomicAdd(&cnt[n2e[e]], 1);
}

__global__ void k_scan(const int* __restrict__ cnt, int* __restrict__ off,
                       int* __restrict__ cursor)
{
    __shared__ int wa[1024];
    int t = threadIdx.x;
    int a0 = cnt[4*t], a1 = cnt[4*t+1], a2 = cnt[4*t+2], a3 = cnt[4*t+3];
    int s1 = a0 + a1, s2 = s1 + a2, s3 = s2 + a3;
    wa[t] = s3;
    __syncthreads();
    for (int d = 1; d < 1024; d <<= 1) {
        int x = wa[t];
        int y = (t >= d) ? wa[t-d] : 0;
        __syncthreads();
        wa[t] = x + y;
        __syncthreads();
    }
    int excl = (t == 0) ? 0 : wa[t-1];
    off[4*t]   = excl;        cursor[4*t]   = excl;
    off[4*t+1] = excl + a0;   cursor[4*t+1] = excl + a0;
    off[4*t+2] = excl + s1;   cursor[4*t+2] = excl + s1;
    off[4*t+3] = excl + s2;   cursor[4*t+3] = excl + s2;
    if (t == 1023) off[4096] = excl + s3;
}

__global__ void k_fill(const int* __restrict__ n2e, int* __restrict__ cursor,
                       int* __restrict__ csr)
{
    int e = blockIdx.x * 256 + threadIdx.x;
    int pos = atomicAdd(&cursor[n2e[e]], 1);
    csr[pos] = e;
}

// ---------------------------------------------------------------------------
// Flat edge GEMM over CSR-ordered tiles: 4096 uniform 64-edge tiles, zero
// padding. K=192 (node-self hoisted into nconst). Segmented msg reduction
// (ballot over node-change flags) -> ~1M low-contention atomics.
// ---------------------------------------------------------------------------
__global__ __launch_bounds__(256, 4) void k_edge_flat(
    const float* __restrict__ node_ext, const float* __restrict__ edge_ebd,
    const float* __restrict__ sw,
    const int* __restrict__ n2e, const int* __restrict__ n_ext2e,
    const int* __restrict__ csr,
    const u16* __restrict__ WTe, const float* __restrict__ nconst,
    const float* __restrict__ bne, const float* __restrict__ bes,
    const float* __restrict__ e_res0,
    float* __restrict__ msg, float* __restrict__ e_out)
{
    __shared__ __align__(16) u16 sA[64][200];   // cols 0-127 nei node, 128-191 edge
    __shared__ int   s_eid[64];
    __shared__ int   s_node[64];
    __shared__ int   s_g[64];
    __shared__ float s_sw[64];
    __shared__ int   s_segstart[65];
    __shared__ int   s_nseg;

    const int tid = threadIdx.x;
    const int w  = tid >> 6, l = tid & 63;
    const int lr = l & 15, hq = l >> 4, lk = hq * 8;
    const int base = blockIdx.x * 64;

    if (tid < 64) {
        int e = csr[base + tid];
        s_eid[tid]  = e;
        s_node[tid] = n2e[e];
        s_g[tid]    = n_ext2e[e];
        s_sw[tid]   = sw[e];
    }
    __syncthreads();

    // segment boundaries (wave 0)
    if (tid < 64) {
        bool flag = (tid == 0) || (s_node[tid] != s_node[tid-1]);
        unsigned long long mask = __ballot(flag);
        if (flag) {
            int sid = __popcll(mask & ((1ull << tid) - 1ull));
            s_segstart[sid] = tid;
        }
        if (tid == 0) {
            int ns = __popcll(mask);
            s_nseg = ns;
            s_segstart[ns] = 64;
        }
    }

    const float4* node4 = (const float4*)node_ext;
    const float4* edge4 = (const float4*)edge_ebd;
    #pragma unroll
    for (int f = tid; f < 2048; f += 256) {       // nei node -> cols 0-127
        int r = f >> 5, c = f & 31;
        st_bf16x4(&sA[r][4*c], node4[(size_t)s_g[r]*32 + c]);
    }
    #pragma unroll
    for (int f = tid; f < 1024; f += 256) {       // edge -> cols 128-191
        int r = f >> 4, c = f & 15;
        st_bf16x4(&sA[r][128 + 4*c], edge4[(size_t)s_eid[r]*16 + c]);
    }
    __syncthreads();

    // per-lane output-column constants
    float bias[3], rres[3];
    int   cful[3];
    #pragma unroll
    for (int nf = 0; nf < 3; ++nf) {
        int c = 48*w + 16*nf + lr;
        cful[nf] = c;
        bias[nf] = (c < 128) ? bne[c] : bes[c-128];
        rres[nf] = (c < 128) ? 0.f    : e_res0[c-128];
    }

    // ---- MFMA: [64 rows] x [K=192] x [192 cols] ----
    f32x4 acc[4][3] = {};
    #pragma unroll
    for (int kk = 0; kk < 6; ++kk) {
        bf16x8 a[4], b[3];
        #pragma unroll
        for (int m = 0; m < 4; ++m)
            a[m] = *(const bf16x8*)&sA[16*m + lr][kk*32 + lk];
        #pragma unroll
        for (int nf = 0; nf < 3; ++nf)
            b[nf] = *(const bf16x8*)&WTe[(size_t)cful[nf]*320 + 128 + kk*32 + lk];
        #pragma unroll
        for (int m = 0; m < 4; ++m)
            #pragma unroll
            for (int nf = 0; nf < 3; ++nf)
                acc[m][nf] = __builtin_amdgcn_mfma_f32_16x16x32_bf16(a[m], b[nf], acc[m][nf], 0, 0, 0);
    }

    // ---- epilogue: transform acc in place / write e_out ----
    #pragma unroll
    for (int nf = 0; nf < 3; ++nf) {
        int c = cful[nf];
        if (c < 128) {
            #pragma unroll
            for (int m = 0; m < 4; ++m)
                #pragma unroll
                for (int j = 0; j < 4; ++j) {
                    int r = 16*m + 4*hq + j;
                    float ncv = nconst[(size_t)s_node[r]*192 + c];
                    acc[m][nf][j] = silu_(acc[m][nf][j] + ncv + bias[nf]) * s_sw[r];
                }
        } else {
            int c2 = c - 128;
            #pragma unroll
            for (int m = 0; m < 4; ++m)
                #pragma unroll
                for (int j = 0; j < 4; ++j) {
                    int r = 16*m + 4*hq + j;
                    float ncv = nconst[(size_t)s_node[r]*192 + c];
                    e_out[(size_t)s_eid[r]*64 + c2] =
                        bu2f(sA[r][128 + c2]) + rres[nf] * silu_(acc[m][nf][j] + ncv + bias[nf]);
                }
        }
    }

    // ---- segmented msg reduction ----
    const int nseg = s_nseg;
    for (int s = 0; s < nseg; ++s) {
        int rs = s_segstart[s], re = s_segstart[s+1];
        int nd = s_node[rs];
        #pragma unroll
        for (int nf = 0; nf < 3; ++nf) {
            if (cful[nf] >= 128) continue;
            float v = 0.f;
            #pragma unroll
            for (int m = 0; m < 4; ++m)
                #pragma unroll
                for (int j = 0; j < 4; ++j) {
                    int r = 16*m + 4*hq + j;
                    v += (r >= rs && r < re) ? acc[m][nf][j] : 0.f;
                }
            v += __shfl_xor(v, 16);
            v += __shfl_xor(v, 32);
            if (hq == 0) atomicAdd(&msg[(size_t)nd*128 + cful[nf]], v);
        }
    }
}

// ---------------------------------------------------------------------------
// Per-node h2g2 gather (no atomics, no MFMA, low VGPR -> high occupancy).
// ---------------------------------------------------------------------------
__global__ __launch_bounds__(256) void k_h2g2(
    const float* __restrict__ node_ext, const float* __restrict__ edge_ebd,
    const float* __restrict__ h2,       const float* __restrict__ sw,
    const int* __restrict__ n_ext2e,
    const int* __restrict__ csr,        const int* __restrict__ off,
    float* __restrict__ h2g2_e, float* __restrict__ h2g2_n)
{
    __shared__ __align__(16) u16 sA[64][200];
    __shared__ int   s_eid[64];
    __shared__ int   s_g[64];
    __shared__ float s_sw[64];
    __shared__ float s_h2[64][3];

    const int tid = threadIdx.x;
    const int w = tid >> 6, l = tid & 63;
    const int n = blockIdx.x;
    const int beg = off[n];
    const int cnt0 = off[n+1] - beg;

    float hacc[9] = {0.f,0.f,0.f,0.f,0.f,0.f,0.f,0.f,0.f};

    const float4* node4 = (const float4*)node_ext;
    const float4* edge4 = (const float4*)edge_ebd;

    for (int t0 = 0; t0 < cnt0; t0 += 64) {
        const int rows = min(64, cnt0 - t0);
        __syncthreads();
        if (tid < 64) {
            int r = tid;
            if (r < rows) {
                int e = csr[beg + t0 + r];
                s_eid[r] = e;
                s_g[r]   = n_ext2e[e];
                s_sw[r]  = sw[e];
                s_h2[r][0] = h2[e*3];
                s_h2[r][1] = h2[e*3+1];
                s_h2[r][2] = h2[e*3+2];
            } else {
                s_eid[r] = -1; s_g[r] = 0; s_sw[r] = 0.f;
                s_h2[r][0] = s_h2[r][1] = s_h2[r][2] = 0.f;
            }
        }
        __syncthreads();

        #pragma unroll
        for (int f = tid; f < 2048; f += 256) {
            int r = f >> 5, c = f & 31;
            if (r < rows)
                st_bf16x4(&sA[r][4*c], node4[(size_t)s_g[r]*32 + c]);
            else
                *reinterpret_cast<uint2*>(&sA[r][4*c]) = make_uint2(0,0);
        }
        #pragma unroll
        for (int f = tid; f < 1024; f += 256) {
            int r = f >> 4, c = f & 15;
            if (r < rows)
                st_bf16x4(&sA[r][128 + 4*c], edge4[(size_t)s_eid[r]*16 + c]);
            else
                *reinterpret_cast<uint2*>(&sA[r][128 + 4*c]) = make_uint2(0,0);
        }
        __syncthreads();

        #pragma unroll
        for (int i = 0; i < 16; ++i) {
            int r = 16*w + i;
            float swv = s_sw[r];
            float s0 = s_h2[r][0] * swv;
            float s1 = s_h2[r][1] * swv;
            float s2 = s_h2[r][2] * swv;
            float eb = bu2f(sA[r][128 + l]);
            float n0 = bu2f(sA[r][l]);
            float n1 = bu2f(sA[r][64 + l]);
            hacc[0] = fmaf(s0, eb, hacc[0]);
            hacc[1] = fmaf(s1, eb, hacc[1]);
            hacc[2] = fmaf(s2, eb, hacc[2]);
            hacc[3] = fmaf(s0, n0, hacc[3]);
            hacc[4] = fmaf(s0, n1, hacc[4]);
            hacc[5] = fmaf(s1, n0, hacc[5]);
            hacc[6] = fmaf(s1, n1, hacc[6]);
            hacc[7] = fmaf(s2, n0, hacc[7]);
            hacc[8] = fmaf(s2, n1, hacc[8]);
        }
    }

    __syncthreads();
    float* sred = (float*)&sA[0][0];   // 4 x 576 f32 (sA dead)
    #pragma unroll
    for (int q = 0; q < 3; ++q) sred[w*576 + q*64 + l] = hacc[q];
    #pragma unroll
    for (int q = 0; q < 6; ++q) sred[w*576 + 192 + q*64 + l] = hacc[3+q];
    __syncthreads();
    for (int i = tid; i < 576; i += 256) {
        float v = sred[i] + sred[576 + i] + sred[1152 + i] + sred[1728 + i];
        if (i < 192) h2g2_e[(size_t)n*192 + i] = v;
        else         h2g2_n[(size_t)n*384 + (i - 192)] = v;
    }
}

// ---------------------------------------------------------------------------
// Angle GEMM via MFMA (unchanged).
// ---------------------------------------------------------------------------
__global__ __launch_bounds__(256) void k_angle_mfma(
    const float* __restrict__ node_ext, const float* __restrict__ edge_ebd,
    const float* __restrict__ angle_ebd, const float* __restrict__ a_sw,
    const int* __restrict__ n2a, const int* __restrict__ eij2a, const int* __restrict__ eik2a,
    const u16* __restrict__ WTa,
    const float* __restrict__ b1, const float* __restrict__ bA,
    const float* __restrict__ a_res0,
    float* __restrict__ reduced, float* __restrict__ a_out)
{
    __shared__ u16 sA[64][296];
    __shared__ int s_na[64], s_ij[64], s_ik[64];
    const int tid = threadIdx.x;
    const int a0 = blockIdx.x * 64;

    if (tid < 64) {
        s_na[tid] = n2a[a0 + tid];
        s_ij[tid] = eij2a[a0 + tid];
        s_ik[tid] = eik2a[a0 + tid];
    }
    __syncthreads();

    const float4* ang4  = (const float4*)angle_ebd;
    const float4* node4 = (const float4*)node_ext;
    const float4* edge4 = (const float4*)edge_ebd;
    #pragma unroll
    for (int f = tid; f < 512; f += 256) {
        int a = f >> 3, c = f & 7;
        st_bf16x4(&sA[a][4*c], ang4[(size_t)(a0 + a)*8 + c]);
    }
    #pragma unroll
    for (int f = tid; f < 2048; f += 256) {
        int a = f >> 5, c = f & 31;
        st_bf16x4(&sA[a][32 + 4*c], node4[(size_t)s_na[a]*32 + c]);
    }
    #pragma unroll
    for (int f = tid; f < 1024; f += 256) {
        int a = f >> 4, c = f & 15;
        st_bf16x4(&sA[a][160 + 4*c], edge4[(size_t)s_ik[a]*16 + c]);
    }
    #pragma unroll
    for (int f = tid; f < 1024; f += 256) {
        int a = f >> 4, c = f & 15;
        st_bf16x4(&sA[a][224 + 4*c], edge4[(size_t)s_ij[a]*16 + c]);
    }
    __syncthreads();

    const int w = tid >> 6, l = tid & 63;
    const int lr = l & 15, lk = (l >> 4) * 8;

    f32x4 acc[6] = {};
    #pragma unroll
    for (int kk = 0; kk < 9; ++kk) {
        bf16x8 a = *(const bf16x8*)&sA[16*w + lr][kk*32 + lk];
        #pragma unroll
        for (int n = 0; n < 6; ++n) {
            bf16x8 b = *(const bf16x8*)&WTa[(size_t)(16*n + lr)*288 + kk*32 + lk];
            acc[n] = __builtin_amdgcn_mfma_f32_16x16x32_bf16(a, b, acc[n], 0, 0, 0);
        }
    }

    #pragma unroll
    for (int n = 0; n < 6; ++n) {
        int c = 16*n + lr;
        if (n < 4) {
            float bb = b1[c];
            #pragma unroll
            for (int j = 0; j < 4; ++j) {
                int r = 16*w + ((l >> 4) << 2) + j;
                float ea = silu_(acc[n][j] + bb) * a_sw[a0 + r];
                atomicAdd(&reduced[(size_t)s_ij[r]*64 + c], ea);
            }
        } else {
            int c2 = c - 64;
            float bb = bA[c2], rr = a_res0[c2];
            #pragma unroll
            for (int j = 0; j < 4; ++j) {
                int r = 16*w + ((l >> 4) << 2) + j;
                size_t idx = (size_t)(a0 + r)*32 + c2;
                a_out[idx] = angle_ebd[idx] + rr * silu_(acc[n][j] + bb);
            }
        }
    }
}

// ---------------------------------------------------------------------------
// edge_angle_msg = silu(reduced @ W2 + b2); e_out += e_res1 * msg
// ---------------------------------------------------------------------------
__global__ __launch_bounds__(256) void k_edgefin_mfma(
    const float* __restrict__ reduced, const u16* __restrict__ WT2,
    const float* __restrict__ b2_, const float* __restrict__ e_res1,
    float* __restrict__ e_out)
{
    __shared__ u16 sR[64][72];
    const int tid = threadIdx.x;
    const int e0 = blockIdx.x * 64;
    const float4* red4 = (const float4*)reduced;
    #pragma unroll
    for (int f = tid; f < 1024; f += 256) {
        int e = f >> 4, c = f & 15;
        st_bf16x4(&sR[e][4*c], red4[(size_t)(e0 + e)*16 + c]);
    }
    __syncthreads();

    const int w = tid >> 6, l = tid & 63;
    const int lr = l & 15, lk = (l >> 4) * 8;

    f32x4 acc[4] = {};
    #pragma unroll
    for (int kk = 0; kk < 2; ++kk) {
        bf16x8 b = *(const bf16x8*)&WT2[(size_t)(16*w + lr)*64 + kk*32 + lk];
        #pragma unroll
        for (int m = 0; m < 4; ++m) {
            bf16x8 a = *(const bf16x8*)&sR[16*m + lr][kk*32 + lk];
            acc[m] = __builtin_amdgcn_mfma_f32_16x16x32_bf16(a, b, acc[m], 0, 0, 0);
        }
    }
    int c = 16*w + lr;
    float bb = b2_[c], rr = e_res1[c];
    #pragma unroll
    for (int m = 0; m < 4; ++m)
        #pragma unroll
        for (int j = 0; j < 4; ++j) {
            size_t idx = (size_t)(e0 + 16*m + ((l >> 4) << 2) + j)*64 + c;
            e_out[idx] += rr * silu_(acc[m][j] + bb);
        }
}

// ---------------------------------------------------------------------------
// Per-node finalize (reads ws msg/h2g2).
// ---------------------------------------------------------------------------
__global__ void k_node_final(const float* __restrict__ node_ext,
                             const float* __restrict__ h2g2_e,
                             const float* __restrict__ h2g2_n,
                             const float* __restrict__ msg,
                             const float* __restrict__ Wns,  const float* __restrict__ bns,
                             const float* __restrict__ Wsym, const float* __restrict__ bsym,
                             const float* __restrict__ nr0, const float* __restrict__ nr1,
                             const float* __restrict__ nr2,
                             float* __restrict__ n_out)
{
    __shared__ float x[128];
    __shared__ float he[192];
    __shared__ float hn[384];
    __shared__ float symc[768];

    int n = blockIdx.x;
    int c = threadIdx.x;

    x[c] = node_ext[(size_t)n*128 + c];
    for (int i = c; i < 192; i += 128) he[i] = h2g2_e[(size_t)n*192 + i];
    for (int i = c; i < 384; i += 128) hn[i] = h2g2_n[(size_t)n*384 + i];
    __syncthreads();

    const float SCALE = 1.0f / (6.4f * 3.0f);
    for (int i = c; i < 768; i += 128) {
        float s;
        if (i < 256) {
            int a = i >> 6, j = i & 63;
            s = he[a]*he[j] + he[64+a]*he[64+j] + he[128+a]*he[128+j];
        } else {
            int i2 = i - 256;
            int a = i2 >> 7, j = i2 & 127;
            s = hn[a]*hn[j] + hn[128+a]*hn[128+j] + hn[256+a]*hn[256+j];
        }
        symc[i] = s * SCALE;
    }
    __syncthreads();

    float accs = 0.f;
    #pragma unroll 8
    for (int k = 0; k < 128; ++k) accs = fmaf(x[k], Wns[k*128 + c], accs);
    float self_ = silu_(accs + bns[c]);

    float accy = 0.f;
    #pragma unroll 8
    for (int k = 0; k < 768; ++k) accy = fmaf(symc[k], Wsym[k*128 + c], accy);
    float sym_ = silu_(accy + bsym[c]);

    float m = msg[(size_t)n*128 + c] * (1.0f / 6.4f);
    n_out[(size_t)n*128 + c] = x[c] + nr0[c]*self_ + nr1[c]*sym_ + nr2[c]*m;
}

// ---------------------------------------------------------------------------
extern "C" void kernel_launch(void* const* d_in, const int* in_sizes, int n_in,
                              void* d_out, int out_size, void* d_ws, size_t ws_size,
                              hipStream_t stream)
{
    const float* node_ext  = (const float*)d_in[0];
    const float* edge_ebd  = (const float*)d_in[1];
    const float* h2        = (const float*)d_in[2];
    const float* angle_ebd = (const float*)d_in[3];
    const float* sw        = (const float*)d_in[6];
    const float* a_sw      = (const float*)d_in[9];
    const int*  edge_index  = (const int*)d_in[10];
    const int*  angle_index = (const int*)d_in[11];
    const int* n2e     = edge_index;
    const int* n_ext2e = edge_index + NEDGE_;
    const int* n2a     = angle_index;
    const int* eij2a   = angle_index + NANGLE_;
    const int* eik2a   = angle_index + 2*NANGLE_;

    const float* Wns  = (const float*)d_in[12];
    const float* bns  = (const float*)d_in[13];
    const float* Wsym = (const float*)d_in[14];
    const float* bsym = (const float*)d_in[15];
    const float* Wne  = (const float*)d_in[16];
    const float* bne  = (const float*)d_in[17];
    const float* Wes  = (const float*)d_in[18];
    const float* bes  = (const float*)d_in[19];
    const float* W1   = (const float*)d_in[20];
    const float* b1   = (const float*)d_in[21];
    const float* W2   = (const float*)d_in[22];
    const float* b2_  = (const float*)d_in[23];
    const float* WA   = (const float*)d_in[24];
    const float* bA   = (const float*)d_in[25];
    const float* nr0  = (const float*)d_in[26];
    const float* nr1  = (const float*)d_in[27];
    const float* nr2  = (const float*)d_in[28];
    const float* er0  = (const float*)d_in[29];
    const float* er1  = (const float*)d_in[30];
    const float* ar0  = (const float*)d_in[31];

    // workspace layout: [reduced | cnt | msg] contiguous (zeroed together)
    char* wsp = (char*)d_ws;
    float* reduced = (float*)wsp;  wsp += (size_t)NEDGE_ * 64 * 4;
    int*   cnt     = (int*)wsp;    wsp += 4096 * 4;
    float* msg     = (float*)wsp;  wsp += (size_t)NLOC_ * 128 * 4;
    int*   off     = (int*)wsp;    wsp += 4104 * 4;
    int*   cursor  = (int*)wsp;    wsp += 4096 * 4;
    int*   csr     = (int*)wsp;    wsp += (size_t)NEDGE_ * 4;
    float* h2g2_e  = (float*)wsp;  wsp += (size_t)NLOC_ * 192 * 4;
    float* h2g2_n  = (float*)wsp;  wsp += (size_t)NLOC_ * 384 * 4;
    float* nconst  = (float*)wsp;  wsp += (size_t)NLOC_ * 192 * 4;
    wsp = (char*)(((uintptr_t)wsp + 63) & ~(uintptr_t)63);
    u16*   WTe     = (u16*)wsp;    wsp += 192 * 320 * 2;
    u16*   WTa     = (u16*)wsp;    wsp += 96 * 288 * 2;
    u16*   WT2     = (u16*)wsp;    wsp += 64 * 64 * 2;

    hipMemsetAsync(reduced, 0,
                   (size_t)NEDGE_ * 64 * 4 + 4096 * 4 + (size_t)NLOC_ * 128 * 4,
                   stream);

    float* n_out = (float*)d_out;
    float* e_out = n_out + (size_t)NLOC_ * 128;
    float* a_out = e_out + (size_t)NEDGE_ * 64;

    k_prep   <<<352, 320, 0, stream>>>(Wne, Wes, W1, WA, W2, WTe, WTa, WT2);
    k_nconst <<<NLOC_/64, 256, 0, stream>>>(node_ext, WTe, nconst);
    k_count  <<<NEDGE_/256, 256, 0, stream>>>(n2e, cnt);
    k_scan   <<<1, 1024, 0, stream>>>(cnt, off, cursor);
    k_fill   <<<NEDGE_/256, 256, 0, stream>>>(n2e, cursor, csr);

    k_edge_flat <<<NEDGE_/64, 256, 0, stream>>>(node_ext, edge_ebd, sw,
                                                n2e, n_ext2e, csr,
                                                WTe, nconst, bne, bes, er0,
                                                msg, e_out);
    k_h2g2      <<<NLOC_, 256, 0, stream>>>(node_ext, edge_ebd, h2, sw,
                                            n_ext2e, csr, off, h2g2_e, h2g2_n);
    k_angle_mfma <<<NANGLE_/64, 256, 0, stream>>>(node_ext, edge_ebd, angle_ebd, a_sw,
                                                  n2a, eij2a, eik2a,
                                                  WTa, b1, bA, ar0, reduced, a_out);
    k_edgefin_mfma <<<NEDGE_/64, 256, 0, stream>>>(reduced, WT2, b2_, er1, e_out);
    k_node_final <<<NLOC_, 128, 0, stream>>>(node_ext, h2g2_e, h2g2_n, msg,
                                             Wns, bns, Wsym, bsym,
                                             nr0, nr1, nr2, n_out);
}

// Round 7
// 536.699 us; speedup vs baseline: 7.9512x; 1.0684x over previous
//
#include <hip/hip_runtime.h>
#include <hip/hip_bf16.h>

#define NLOC_   4096
#define NALL_   6144
#define NEDGE_  262144
#define NANGLE_ 409600

typedef __bf16 bf16x8 __attribute__((ext_vector_type(8)));
typedef float  f32x4  __attribute__((ext_vector_type(4)));
typedef unsigned short u16;

__device__ __forceinline__ float silu_(float x){ return x / (1.0f + __expf(-x)); }

__device__ __forceinline__ u16 f2bu(float f){
    union { float f; unsigned u; } v; v.f = f;
    unsigned r = v.u + 0x7fffu + ((v.u >> 16) & 1u);
    return (u16)(r >> 16);
}
__device__ __forceinline__ float bu2f(u16 b){
    union { unsigned u; float f; } v; v.u = ((unsigned)b) << 16; return v.f;
}
__device__ __forceinline__ void st_bf16x4(u16* dst, float4 v){
    unsigned lo = (unsigned)f2bu(v.x) | ((unsigned)f2bu(v.y) << 16);
    unsigned hi = (unsigned)f2bu(v.z) | ((unsigned)f2bu(v.w) << 16);
    *reinterpret_cast<uint2*>(dst) = make_uint2(lo, hi);
}

// ---------------------------------------------------------------------------
// Weight prep (f32 -> bf16 transposed).
// ---------------------------------------------------------------------------
__global__ void k_prep(const float* __restrict__ Wne, const float* __restrict__ Wes,
                       const float* __restrict__ W1,  const float* __restrict__ WA,
                       const float* __restrict__ W2,
                       u16* __restrict__ WTe, u16* __restrict__ WTa, u16* __restrict__ WT2)
{
    int b = blockIdx.x, t = threadIdx.x;
    if (b < 192) {
        if (t < 320) WTe[b*320 + t] = f2bu(b < 128 ? Wne[t*128 + b] : Wes[t*64 + (b-128)]);
    } else if (b < 288) {
        int n = b - 192;
        if (t < 288) WTa[n*288 + t] = f2bu(n < 64 ? W1[t*64 + n] : WA[t*32 + (n-64)]);
    } else {
        int n = b - 288;
        if (t < 64)  WT2[n*64 + t] = f2bu(W2[t*64 + n]);
    }
}

// ---------------------------------------------------------------------------
// Generic f32 -> bf16 table conversion (n4 = #float4 elements).
// ---------------------------------------------------------------------------
__global__ void k_cvt(const float* __restrict__ src, u16* __restrict__ dst, int n4)
{
    int i = blockIdx.x * 256 + threadIdx.x;
    int stride = gridDim.x * 256;
    for (; i < n4; i += stride) {
        float4 v = ((const float4*)src)[i];
        st_bf16x4(&dst[(size_t)i*4], v);
    }
}

// ---------------------------------------------------------------------------
// nconst[n][c] = node_ebd[n] @ W[0:128][c]  (MFMA, staged from bf16 table).
// ---------------------------------------------------------------------------
__global__ __launch_bounds__(256) void k_nconst(
    const u16* __restrict__ NB, const u16* __restrict__ WTe,
    float* __restrict__ nconst)
{
    __shared__ __align__(16) u16 sN[64][136];
    const int tid = threadIdx.x;
    const int e0 = blockIdx.x * 64;
    #pragma unroll
    for (int f = tid; f < 1024; f += 256) {
        int r = f >> 4, c = f & 15;
        *(uint4*)&sN[r][8*c] = ((const uint4*)&NB[(size_t)(e0 + r)*128])[c];
    }
    __syncthreads();

    const int w = tid >> 6, l = tid & 63;
    const int lr = l & 15, hq = l >> 4, lk = hq * 8;

    f32x4 acc[4][3] = {};
    #pragma unroll
    for (int kk = 0; kk < 4; ++kk) {
        bf16x8 a[4], b[3];
        #pragma unroll
        for (int m = 0; m < 4; ++m)
            a[m] = *(const bf16x8*)&sN[16*m + lr][kk*32 + lk];
        #pragma unroll
        for (int nf = 0; nf < 3; ++nf)
            b[nf] = *(const bf16x8*)&WTe[(size_t)(48*w + 16*nf + lr)*320 + kk*32 + lk];
        #pragma unroll
        for (int m = 0; m < 4; ++m)
            #pragma unroll
            for (int nf = 0; nf < 3; ++nf)
                acc[m][nf] = __builtin_amdgcn_mfma_f32_16x16x32_bf16(a[m], b[nf], acc[m][nf], 0, 0, 0);
    }
    #pragma unroll
    for (int nf = 0; nf < 3; ++nf) {
        int c = 48*w + 16*nf + lr;
        #pragma unroll
        for (int m = 0; m < 4; ++m)
            #pragma unroll
            for (int j = 0; j < 4; ++j) {
                int r = 16*m + 4*hq + j;
                nconst[(size_t)(e0 + r)*192 + c] = acc[m][nf][j];
            }
    }
}

// ---------------------------------------------------------------------------
// Node CSR build (4096 segments).
// ---------------------------------------------------------------------------
__global__ void k_count(const int* __restrict__ key, int* __restrict__ cnt)
{
    int e = blockIdx.x * 256 + threadIdx.x;
    atomicAdd(&cnt[key[e]], 1);
}

__global__ void k_scan(const int* __restrict__ cnt, int* __restrict__ off,
                       int* __restrict__ cursor)
{
    __shared__ int wa[1024];
    int t = threadIdx.x;
    int a0 = cnt[4*t], a1 = cnt[4*t+1], a2 = cnt[4*t+2], a3 = cnt[4*t+3];
    int s1 = a0 + a1, s2 = s1 + a2, s3 = s2 + a3;
    wa[t] = s3;
    __syncthreads();
    for (int d = 1; d < 1024; d <<= 1) {
        int x = wa[t];
        int y = (t >= d) ? wa[t-d] : 0;
        __syncthreads();
        wa[t] = x + y;
        __syncthreads();
    }
    int excl = (t == 0) ? 0 : wa[t-1];
    off[4*t]   = excl;        cursor[4*t]   = excl;
    off[4*t+1] = excl + a0;   cursor[4*t+1] = excl + a0;
    off[4*t+2] = excl + s1;   cursor[4*t+2] = excl + s1;
    off[4*t+3] = excl + s2;   cursor[4*t+3] = excl + s2;
    if (t == 1023) off[4096] = excl + s3;
}

__global__ void k_fill(const int* __restrict__ key, int* __restrict__ cursor,
                       int* __restrict__ csr)
{
    int e = blockIdx.x * 256 + threadIdx.x;
    int pos = atomicAdd(&cursor[key[e]], 1);
    csr[pos] = e;
}

// ---------------------------------------------------------------------------
// Angle CSR build over eij2a (262144 segments): count -> 3-phase scan -> fill.
// ---------------------------------------------------------------------------
__global__ void k_scan2a(const int* __restrict__ cnt2, int* __restrict__ bsum)
{
    __shared__ int wa[256];
    int b = blockIdx.x, t = threadIdx.x;
    int4 v = ((const int4*)cnt2)[b*256 + t];
    wa[t] = v.x + v.y + v.z + v.w;
    __syncthreads();
    for (int d = 128; d > 0; d >>= 1) {
        if (t < d) wa[t] += wa[t+d];
        __syncthreads();
    }
    if (t == 0) bsum[b] = wa[0];
}

__global__ void k_scan2b(const int* __restrict__ bsum, int* __restrict__ boff)
{
    __shared__ int wa[256];
    int t = threadIdx.x;
    wa[t] = bsum[t];
    __syncthreads();
    for (int d = 1; d < 256; d <<= 1) {
        int x = wa[t];
        int y = (t >= d) ? wa[t-d] : 0;
        __syncthreads();
        wa[t] = x + y;
        __syncthreads();
    }
    boff[t] = (t == 0) ? 0 : wa[t-1];
}

__global__ void k_scan2c(const int* __restrict__ cnt2, const int* __restrict__ boff,
                         int* __restrict__ off2, int* __restrict__ cursor2)
{
    __shared__ int wa[256];
    int b = blockIdx.x, t = threadIdx.x;
    int4 v = ((const int4*)cnt2)[b*256 + t];
    int s1 = v.x, s2 = s1 + v.y, s3 = s2 + v.z, s4 = s3 + v.w;
    wa[t] = s4;
    __syncthreads();
    for (int d = 1; d < 256; d <<= 1) {
        int x = wa[t];
        int y = (t >= d) ? wa[t-d] : 0;
        __syncthreads();
        wa[t] = x + y;
        __syncthreads();
    }
    int base = boff[b] + ((t == 0) ? 0 : wa[t-1]);
    int i = (b*256 + t)*4;
    off2[i]   = base;      cursor2[i]   = base;
    off2[i+1] = base + s1; cursor2[i+1] = base + s1;
    off2[i+2] = base + s2; cursor2[i+2] = base + s2;
    off2[i+3] = base + s3; cursor2[i+3] = base + s3;
    if (b == 255 && t == 255) off2[NEDGE_] = NANGLE_;
}

// ---------------------------------------------------------------------------
// Flat edge GEMM over CSR-ordered tiles (bf16-table staging).
// ---------------------------------------------------------------------------
__global__ __launch_bounds__(256, 4) void k_edge_flat(
    const u16* __restrict__ NB, const u16* __restrict__ EB,
    const float* __restrict__ sw,
    const int* __restrict__ n2e, const int* __restrict__ n_ext2e,
    const int* __restrict__ csr,
    const u16* __restrict__ WTe, const float* __restrict__ nconst,
    const float* __restrict__ bne, const float* __restrict__ bes,
    const float* __restrict__ e_res0,
    float* __restrict__ msg, float* __restrict__ e_out)
{
    __shared__ __align__(16) u16 sA[64][200];
    __shared__ int   s_eid[64];
    __shared__ int   s_node[64];
    __shared__ int   s_g[64];
    __shared__ float s_sw[64];
    __shared__ int   s_segstart[65];
    __shared__ int   s_nseg;

    const int tid = threadIdx.x;
    const int w  = tid >> 6, l = tid & 63;
    const int lr = l & 15, hq = l >> 4, lk = hq * 8;
    const int base = blockIdx.x * 64;

    if (tid < 64) {
        int e = csr[base + tid];
        s_eid[tid]  = e;
        s_node[tid] = n2e[e];
        s_g[tid]    = n_ext2e[e];
        s_sw[tid]   = sw[e];
    }
    __syncthreads();

    if (tid < 64) {
        bool flag = (tid == 0) || (s_node[tid] != s_node[tid-1]);
        unsigned long long mask = __ballot(flag);
        if (flag) {
            int sid = __popcll(mask & ((1ull << tid) - 1ull));
            s_segstart[sid] = tid;
        }
        if (tid == 0) {
            int ns = __popcll(mask);
            s_nseg = ns;
            s_segstart[ns] = 64;
        }
    }

    #pragma unroll
    for (int f = tid; f < 1024; f += 256) {        // nei node -> cols 0-127
        int r = f >> 4, c = f & 15;
        *(uint4*)&sA[r][8*c] = ((const uint4*)&NB[(size_t)s_g[r]*128])[c];
    }
    #pragma unroll
    for (int f = tid; f < 512; f += 256) {         // edge -> cols 128-191
        int r = f >> 3, c = f & 7;
        *(uint4*)&sA[r][128 + 8*c] = ((const uint4*)&EB[(size_t)s_eid[r]*64])[c];
    }
    __syncthreads();

    float bias[3], rres[3];
    int   cful[3];
    #pragma unroll
    for (int nf = 0; nf < 3; ++nf) {
        int c = 48*w + 16*nf + lr;
        cful[nf] = c;
        bias[nf] = (c < 128) ? bne[c] : bes[c-128];
        rres[nf] = (c < 128) ? 0.f    : e_res0[c-128];
    }

    f32x4 acc[4][3] = {};
    #pragma unroll
    for (int kk = 0; kk < 6; ++kk) {
        bf16x8 a[4], b[3];
        #pragma unroll
        for (int m = 0; m < 4; ++m)
            a[m] = *(const bf16x8*)&sA[16*m + lr][kk*32 + lk];
        #pragma unroll
        for (int nf = 0; nf < 3; ++nf)
            b[nf] = *(const bf16x8*)&WTe[(size_t)cful[nf]*320 + 128 + kk*32 + lk];
        #pragma unroll
        for (int m = 0; m < 4; ++m)
            #pragma unroll
            for (int nf = 0; nf < 3; ++nf)
                acc[m][nf] = __builtin_amdgcn_mfma_f32_16x16x32_bf16(a[m], b[nf], acc[m][nf], 0, 0, 0);
    }

    #pragma unroll
    for (int nf = 0; nf < 3; ++nf) {
        int c = cful[nf];
        if (c < 128) {
            #pragma unroll
            for (int m = 0; m < 4; ++m)
                #pragma unroll
                for (int j = 0; j < 4; ++j) {
                    int r = 16*m + 4*hq + j;
                    float ncv = nconst[(size_t)s_node[r]*192 + c];
                    acc[m][nf][j] = silu_(acc[m][nf][j] + ncv + bias[nf]) * s_sw[r];
                }
        } else {
            int c2 = c - 128;
            #pragma unroll
            for (int m = 0; m < 4; ++m)
                #pragma unroll
                for (int j = 0; j < 4; ++j) {
                    int r = 16*m + 4*hq + j;
                    float ncv = nconst[(size_t)s_node[r]*192 + c];
                    e_out[(size_t)s_eid[r]*64 + c2] =
                        bu2f(sA[r][128 + c2]) + rres[nf] * silu_(acc[m][nf][j] + ncv + bias[nf]);
                }
        }
    }

    const int nseg = s_nseg;
    for (int s = 0; s < nseg; ++s) {
        int rs = s_segstart[s], re = s_segstart[s+1];
        int nd = s_node[rs];
        #pragma unroll
        for (int nf = 0; nf < 3; ++nf) {
            if (cful[nf] >= 128) continue;
            float v = 0.f;
            #pragma unroll
            for (int m = 0; m < 4; ++m)
                #pragma unroll
                for (int j = 0; j < 4; ++j) {
                    int r = 16*m + 4*hq + j;
                    v += (r >= rs && r < re) ? acc[m][nf][j] : 0.f;
                }
            v += __shfl_xor(v, 16);
            v += __shfl_xor(v, 32);
            if (hq == 0) atomicAdd(&msg[(size_t)nd*128 + cful[nf]], v);
        }
    }
}

// ---------------------------------------------------------------------------
// Per-node h2g2 gather (bf16-table staging, no atomics).
// ---------------------------------------------------------------------------
__global__ __launch_bounds__(256) void k_h2g2(
    const u16* __restrict__ NB, const u16* __restrict__ EB,
    const float* __restrict__ h2, const float* __restrict__ sw,
    const int* __restrict__ n_ext2e,
    const int* __restrict__ csr, const int* __restrict__ off,
    float* __restrict__ h2g2_e, float* __restrict__ h2g2_n)
{
    __shared__ __align__(16) u16 sA[64][200];
    __shared__ int   s_eid[64];
    __shared__ int   s_g[64];
    __shared__ float s_sw[64];
    __shared__ float s_h2[64][3];

    const int tid = threadIdx.x;
    const int w = tid >> 6, l = tid & 63;
    const int n = blockIdx.x;
    const int beg = off[n];
    const int cnt0 = off[n+1] - beg;

    float hacc[9] = {0.f,0.f,0.f,0.f,0.f,0.f,0.f,0.f,0.f};
    const uint4 z4 = make_uint4(0,0,0,0);

    for (int t0 = 0; t0 < cnt0; t0 += 64) {
        const int rows = min(64, cnt0 - t0);
        __syncthreads();
        if (tid < 64) {
            int r = tid;
            if (r < rows) {
                int e = csr[beg + t0 + r];
                s_eid[r] = e;
                s_g[r]   = n_ext2e[e];
                s_sw[r]  = sw[e];
                s_h2[r][0] = h2[e*3];
                s_h2[r][1] = h2[e*3+1];
                s_h2[r][2] = h2[e*3+2];
            } else {
                s_eid[r] = -1; s_g[r] = 0; s_sw[r] = 0.f;
                s_h2[r][0] = s_h2[r][1] = s_h2[r][2] = 0.f;
            }
        }
        __syncthreads();

        #pragma unroll
        for (int f = tid; f < 1024; f += 256) {
            int r = f >> 4, c = f & 15;
            *(uint4*)&sA[r][8*c] =
                (r < rows) ? ((const uint4*)&NB[(size_t)s_g[r]*128])[c] : z4;
        }
        #pragma unroll
        for (int f = tid; f < 512; f += 256) {
            int r = f >> 3, c = f & 7;
            *(uint4*)&sA[r][128 + 8*c] =
                (r < rows) ? ((const uint4*)&EB[(size_t)s_eid[r]*64])[c] : z4;
        }
        __syncthreads();

        #pragma unroll
        for (int i = 0; i < 16; ++i) {
            int r = 16*w + i;
            float swv = s_sw[r];
            float s0 = s_h2[r][0] * swv;
            float s1 = s_h2[r][1] * swv;
            float s2 = s_h2[r][2] * swv;
            float eb = bu2f(sA[r][128 + l]);
            float n0 = bu2f(sA[r][l]);
            float n1 = bu2f(sA[r][64 + l]);
            hacc[0] = fmaf(s0, eb, hacc[0]);
            hacc[1] = fmaf(s1, eb, hacc[1]);
            hacc[2] = fmaf(s2, eb, hacc[2]);
            hacc[3] = fmaf(s0, n0, hacc[3]);
            hacc[4] = fmaf(s0, n1, hacc[4]);
            hacc[5] = fmaf(s1, n0, hacc[5]);
            hacc[6] = fmaf(s1, n1, hacc[6]);
            hacc[7] = fmaf(s2, n0, hacc[7]);
            hacc[8] = fmaf(s2, n1, hacc[8]);
        }
    }

    __syncthreads();
    float* sred = (float*)&sA[0][0];   // 4 x 576 f32 (sA dead)
    #pragma unroll
    for (int q = 0; q < 3; ++q) sred[w*576 + q*64 + l] = hacc[q];
    #pragma unroll
    for (int q = 0; q < 6; ++q) sred[w*576 + 192 + q*64 + l] = hacc[3+q];
    __syncthreads();
    for (int i = tid; i < 576; i += 256) {
        float v = sred[i] + sred[576 + i] + sred[1152 + i] + sred[1728 + i];
        if (i < 192) h2g2_e[(size_t)n*192 + i] = v;
        else         h2g2_n[(size_t)n*384 + (i - 192)] = v;
    }
}

// ---------------------------------------------------------------------------
// Angle GEMM via MFMA: writes per-angle ea rows (bf16) + a_out. NO atomics.
// ---------------------------------------------------------------------------
__global__ __launch_bounds__(256) void k_angle_mfma(
    const u16* __restrict__ NB, const u16* __restrict__ EB,
    const float* __restrict__ angle_ebd, const float* __restrict__ a_sw,
    const int* __restrict__ n2a, const int* __restrict__ eij2a, const int* __restrict__ eik2a,
    const u16* __restrict__ WTa,
    const float* __restrict__ b1, const float* __restrict__ bA,
    const float* __restrict__ a_res0,
    u16* __restrict__ ea, float* __restrict__ a_out)
{
    __shared__ __align__(16) u16 sA[64][296];
    __shared__ int s_na[64], s_ij[64], s_ik[64];
    const int tid = threadIdx.x;
    const int a0 = blockIdx.x * 64;

    if (tid < 64) {
        s_na[tid] = n2a[a0 + tid];
        s_ij[tid] = eij2a[a0 + tid];
        s_ik[tid] = eik2a[a0 + tid];
    }
    __syncthreads();

    const float4* ang4 = (const float4*)angle_ebd;
    #pragma unroll
    for (int f = tid; f < 512; f += 256) {          // angle_ebd (f32 -> bf16)
        int a = f >> 3, c = f & 7;
        st_bf16x4(&sA[a][4*c], ang4[(size_t)(a0 + a)*8 + c]);
    }
    #pragma unroll
    for (int f = tid; f < 1024; f += 256) {         // node from NB
        int a = f >> 4, c = f & 15;
        *(uint4*)&sA[a][32 + 8*c] = ((const uint4*)&NB[(size_t)s_na[a]*128])[c];
    }
    #pragma unroll
    for (int f = tid; f < 512; f += 256) {          // edge_ik from EB
        int a = f >> 3, c = f & 7;
        *(uint4*)&sA[a][160 + 8*c] = ((const uint4*)&EB[(size_t)s_ik[a]*64])[c];
    }
    #pragma unroll
    for (int f = tid; f < 512; f += 256) {          // edge_ij from EB
        int a = f >> 3, c = f & 7;
        *(uint4*)&sA[a][224 + 8*c] = ((const uint4*)&EB[(size_t)s_ij[a]*64])[c];
    }
    __syncthreads();

    const int w = tid >> 6, l = tid & 63;
    const int lr = l & 15, lk = (l >> 4) * 8;

    f32x4 acc[6] = {};
    #pragma unroll
    for (int kk = 0; kk < 9; ++kk) {
        bf16x8 a = *(const bf16x8*)&sA[16*w + lr][kk*32 + lk];
        #pragma unroll
        for (int n = 0; n < 6; ++n) {
            bf16x8 b = *(const bf16x8*)&WTa[(size_t)(16*n + lr)*288 + kk*32 + lk];
            acc[n] = __builtin_amdgcn_mfma_f32_16x16x32_bf16(a, b, acc[n], 0, 0, 0);
        }
    }

    #pragma unroll
    for (int n = 0; n < 6; ++n) {
        int c = 16*n + lr;
        if (n < 4) {
            float bb = b1[c];
            #pragma unroll
            for (int j = 0; j < 4; ++j) {
                int r = 16*w + ((l >> 4) << 2) + j;
                float eav = silu_(acc[n][j] + bb) * a_sw[a0 + r];
                ea[(size_t)(a0 + r)*64 + c] = f2bu(eav);
            }
        } else {
            int c2 = c - 64;
            float bb = bA[c2], rr = a_res0[c2];
            #pragma unroll
            for (int j = 0; j < 4; ++j) {
                int r = 16*w + ((l >> 4) << 2) + j;
                size_t idx = (size_t)(a0 + r)*32 + c2;
                a_out[idx] = angle_ebd[idx] + rr * silu_(acc[n][j] + bb);
            }
        }
    }
}

// ---------------------------------------------------------------------------
// Gather ea rows per edge (CSR2), sum -> W2 MFMA -> e_out += e_res1 * msg.
// ---------------------------------------------------------------------------
__global__ __launch_bounds__(256) void k_edgefin_mfma(
    const u16* __restrict__ ea,
    const int* __restrict__ off2, const int* __restrict__ csr2,
    const u16* __restrict__ WT2,
    const float* __restrict__ b2_, const float* __restrict__ e_res1,
    float* __restrict__ e_out)
{
    __shared__ __align__(16) u16 sR[64][72];
    const int tid = threadIdx.x;
    const int e0 = blockIdx.x * 64;
    const int w = tid >> 6, l = tid & 63;

    #pragma unroll
    for (int r16 = 0; r16 < 16; ++r16) {
        int r = w*16 + r16;
        int e = e0 + r;
        float s = 0.f;
        for (int j = off2[e]; j < off2[e+1]; ++j) {
            int a = csr2[j];
            s += bu2f(ea[(size_t)a*64 + l]);
        }
        sR[r][l] = f2bu(s);
    }
    __syncthreads();

    const int lr = l & 15, lk = (l >> 4) * 8;

    f32x4 acc[4] = {};
    #pragma unroll
    for (int kk = 0; kk < 2; ++kk) {
        bf16x8 b = *(const bf16x8*)&WT2[(size_t)(16*w + lr)*64 + kk*32 + lk];
        #pragma unroll
        for (int m = 0; m < 4; ++m) {
            bf16x8 a = *(const bf16x8*)&sR[16*m + lr][kk*32 + lk];
            acc[m] = __builtin_amdgcn_mfma_f32_16x16x32_bf16(a, b, acc[m], 0, 0, 0);
        }
    }
    int c = 16*w + lr;
    float bb = b2_[c], rr = e_res1[c];
    #pragma unroll
    for (int m = 0; m < 4; ++m)
        #pragma unroll
        for (int j = 0; j < 4; ++j) {
            size_t idx = (size_t)(e0 + 16*m + ((l >> 4) << 2) + j)*64 + c;
            e_out[idx] += rr * silu_(acc[m][j] + bb);
        }
}

// ---------------------------------------------------------------------------
// Per-node finalize.
// ---------------------------------------------------------------------------
__global__ void k_node_final(const float* __restrict__ node_ext,
                             const float* __restrict__ h2g2_e,
                             const float* __restrict__ h2g2_n,
                             const float* __restrict__ msg,
                             const float* __restrict__ Wns,  const float* __restrict__ bns,
                             const float* __restrict__ Wsym, const float* __restrict__ bsym,
                             const float* __restrict__ nr0, const float* __restrict__ nr1,
                             const float* __restrict__ nr2,
                             float* __restrict__ n_out)
{
    __shared__ float x[128];
    __shared__ float he[192];
    __shared__ float hn[384];
    __shared__ float symc[768];

    int n = blockIdx.x;
    int c = threadIdx.x;

    x[c] = node_ext[(size_t)n*128 + c];
    for (int i = c; i < 192; i += 128) he[i] = h2g2_e[(size_t)n*192 + i];
    for (int i = c; i < 384; i += 128) hn[i] = h2g2_n[(size_t)n*384 + i];
    __syncthreads();

    const float SCALE = 1.0f / (6.4f * 3.0f);
    for (int i = c; i < 768; i += 128) {
        float s;
        if (i < 256) {
            int a = i >> 6, j = i & 63;
            s = he[a]*he[j] + he[64+a]*he[64+j] + he[128+a]*he[128+j];
        } else {
            int i2 = i - 256;
            int a = i2 >> 7, j = i2 & 127;
            s = hn[a]*hn[j] + hn[128+a]*hn[128+j] + hn[256+a]*hn[256+j];
        }
        symc[i] = s * SCALE;
    }
    __syncthreads();

    float accs = 0.f;
    #pragma unroll 8
    for (int k = 0; k < 128; ++k) accs = fmaf(x[k], Wns[k*128 + c], accs);
    float self_ = silu_(accs + bns[c]);

    float accy = 0.f;
    #pragma unroll 8
    for (int k = 0; k < 768; ++k) accy = fmaf(symc[k], Wsym[k*128 + c], accy);
    float sym_ = silu_(accy + bsym[c]);

    float m = msg[(size_t)n*128 + c] * (1.0f / 6.4f);
    n_out[(size_t)n*128 + c] = x[c] + nr0[c]*self_ + nr1[c]*sym_ + nr2[c]*m;
}

// ---------------------------------------------------------------------------
extern "C" void kernel_launch(void* const* d_in, const int* in_sizes, int n_in,
                              void* d_out, int out_size, void* d_ws, size_t ws_size,
                              hipStream_t stream)
{
    const float* node_ext  = (const float*)d_in[0];
    const float* edge_ebd  = (const float*)d_in[1];
    const float* h2        = (const float*)d_in[2];
    const float* angle_ebd = (const float*)d_in[3];
    const float* sw        = (const float*)d_in[6];
    const float* a_sw      = (const float*)d_in[9];
    const int*  edge_index  = (const int*)d_in[10];
    const int*  angle_index = (const int*)d_in[11];
    const int* n2e     = edge_index;
    const int* n_ext2e = edge_index + NEDGE_;
    const int* n2a     = angle_index;
    const int* eij2a   = angle_index + NANGLE_;
    const int* eik2a   = angle_index + 2*NANGLE_;

    const float* Wns  = (const float*)d_in[12];
    const float* bns  = (const float*)d_in[13];
    const float* Wsym = (const float*)d_in[14];
    const float* bsym = (const float*)d_in[15];
    const float* Wne  = (const float*)d_in[16];
    const float* bne  = (const float*)d_in[17];
    const float* Wes  = (const float*)d_in[18];
    const float* bes  = (const float*)d_in[19];
    const float* W1   = (const float*)d_in[20];
    const float* b1   = (const float*)d_in[21];
    const float* W2   = (const float*)d_in[22];
    const float* b2_  = (const float*)d_in[23];
    const float* WA   = (const float*)d_in[24];
    const float* bA   = (const float*)d_in[25];
    const float* nr0  = (const float*)d_in[26];
    const float* nr1  = (const float*)d_in[27];
    const float* nr2  = (const float*)d_in[28];
    const float* er0  = (const float*)d_in[29];
    const float* er1  = (const float*)d_in[30];
    const float* ar0  = (const float*)d_in[31];

    // workspace layout
    char* wsp = (char*)d_ws;
    u16*   ea      = (u16*)wsp;    wsp += (size_t)NANGLE_ * 64 * 2;   // 52.4 MB
    u16*   EB      = (u16*)wsp;    wsp += (size_t)NEDGE_ * 64 * 2;    // 33.6 MB
    u16*   NB      = (u16*)wsp;    wsp += (size_t)NALL_ * 128 * 2;    // 1.6 MB
    // zeroed region: [cnt | cnt2 | msg]
    int*   cnt     = (int*)wsp;    wsp += 4096 * 4;
    int*   cnt2    = (int*)wsp;    wsp += (size_t)NEDGE_ * 4;
    float* msg     = (float*)wsp;  wsp += (size_t)NLOC_ * 128 * 4;
    size_t zero_bytes = 4096*4 + (size_t)NEDGE_*4 + (size_t)NLOC_*128*4;
    int*   off     = (int*)wsp;    wsp += 4104 * 4;
    int*   cursor  = (int*)wsp;    wsp += 4096 * 4;
    int*   csr     = (int*)wsp;    wsp += (size_t)NEDGE_ * 4;
    int*   off2    = (int*)wsp;    wsp += ((size_t)NEDGE_ + 16) * 4;
    int*   cursor2 = (int*)wsp;    wsp += (size_t)NEDGE_ * 4;
    int*   bsum    = (int*)wsp;    wsp += 256 * 4;
    int*   boff    = (int*)wsp;    wsp += 256 * 4;
    int*   csr2    = (int*)wsp;    wsp += (size_t)NANGLE_ * 4;
    float* h2g2_e  = (float*)wsp;  wsp += (size_t)NLOC_ * 192 * 4;
    float* h2g2_n  = (float*)wsp;  wsp += (size_t)NLOC_ * 384 * 4;
    float* nconst  = (float*)wsp;  wsp += (size_t)NLOC_ * 192 * 4;
    u16*   WTe     = (u16*)wsp;    wsp += 192 * 320 * 2;
    u16*   WTa     = (u16*)wsp;    wsp += 96 * 288 * 2;
    u16*   WT2     = (u16*)wsp;    wsp += 64 * 64 * 2;

    hipMemsetAsync(cnt, 0, zero_bytes, stream);

    float* n_out = (float*)d_out;
    float* e_out = n_out + (size_t)NLOC_ * 128;
    float* a_out = e_out + (size_t)NEDGE_ * 64;

    // prep: weights, bf16 tables, CSRs
    k_prep   <<<352, 320, 0, stream>>>(Wne, Wes, W1, WA, W2, WTe, WTa, WT2);
    k_cvt    <<<768, 256, 0, stream>>>(node_ext, NB, NALL_*128/4);
    k_cvt    <<<4096, 256, 0, stream>>>(edge_ebd, EB, NEDGE_*64/4);
    k_count  <<<NEDGE_/256, 256, 0, stream>>>(n2e, cnt);
    k_scan   <<<1, 1024, 0, stream>>>(cnt, off, cursor);
    k_fill   <<<NEDGE_/256, 256, 0, stream>>>(n2e, cursor, csr);
    k_count  <<<NANGLE_/256, 256, 0, stream>>>(eij2a, cnt2);
    k_scan2a <<<256, 256, 0, stream>>>(cnt2, bsum);
    k_scan2b <<<1, 256, 0, stream>>>(bsum, boff);
    k_scan2c <<<256, 256, 0, stream>>>(cnt2, boff, off2, cursor2);
    k_fill   <<<NANGLE_/256, 256, 0, stream>>>(eij2a, cursor2, csr2);

    k_nconst <<<NLOC_/64, 256, 0, stream>>>(NB, WTe, nconst);
    k_edge_flat <<<NEDGE_/64, 256, 0, stream>>>(NB, EB, sw, n2e, n_ext2e, csr,
                                                WTe, nconst, bne, bes, er0,
                                                msg, e_out);
    k_h2g2   <<<NLOC_, 256, 0, stream>>>(NB, EB, h2, sw, n_ext2e, csr, off,
                                         h2g2_e, h2g2_n);
    k_angle_mfma <<<NANGLE_/64, 256, 0, stream>>>(NB, EB, angle_ebd, a_sw,
                                                  n2a, eij2a, eik2a,
                                                  WTa, b1, bA, ar0, ea, a_out);
    k_edgefin_mfma <<<NEDGE_/64, 256, 0, stream>>>(ea, off2, csr2, WT2, b2_, er1, e_out);
    k_node_final <<<NLOC_, 128, 0, stream>>>(node_ext, h2g2_e, h2g2_n, msg,
                                             Wns, bns, Wsym, bsym,
                                             nr0, nr1, nr2, n_out);
}

// Round 8
// 497.463 us; speedup vs baseline: 8.5783x; 1.0789x over previous
//
#include <hip/hip_runtime.h>
#include <hip/hip_bf16.h>

#define NLOC_   4096
#define NALL_   6144
#define NEDGE_  262144
#define NANGLE_ 409600

typedef __bf16 bf16x8 __attribute__((ext_vector_type(8)));
typedef float  f32x4  __attribute__((ext_vector_type(4)));
typedef unsigned short u16;

__device__ __forceinline__ float silu_(float x){ return x / (1.0f + __expf(-x)); }

__device__ __forceinline__ u16 f2bu(float f){
    union { float f; unsigned u; } v; v.f = f;
    unsigned r = v.u + 0x7fffu + ((v.u >> 16) & 1u);
    return (u16)(r >> 16);
}
__device__ __forceinline__ float bu2f(u16 b){
    union { unsigned u; float f; } v; v.u = ((unsigned)b) << 16; return v.f;
}
__device__ __forceinline__ void st_bf16x4(u16* dst, float4 v){
    unsigned lo = (unsigned)f2bu(v.x) | ((unsigned)f2bu(v.y) << 16);
    unsigned hi = (unsigned)f2bu(v.z) | ((unsigned)f2bu(v.w) << 16);
    *reinterpret_cast<uint2*>(dst) = make_uint2(lo, hi);
}

// ---------------------------------------------------------------------------
// Weight prep (f32 -> bf16 transposed).
// ---------------------------------------------------------------------------
__global__ void k_prep(const float* __restrict__ Wne, const float* __restrict__ Wes,
                       const float* __restrict__ W1,  const float* __restrict__ WA,
                       const float* __restrict__ W2,
                       u16* __restrict__ WTe, u16* __restrict__ WTa, u16* __restrict__ WT2)
{
    int b = blockIdx.x, t = threadIdx.x;
    if (b < 192) {
        if (t < 320) WTe[b*320 + t] = f2bu(b < 128 ? Wne[t*128 + b] : Wes[t*64 + (b-128)]);
    } else if (b < 288) {
        int n = b - 192;
        if (t < 288) WTa[n*288 + t] = f2bu(n < 64 ? W1[t*64 + n] : WA[t*32 + (n-64)]);
    } else {
        int n = b - 288;
        if (t < 64)  WT2[n*64 + t] = f2bu(W2[t*64 + n]);
    }
}

// ---------------------------------------------------------------------------
// Generic f32 -> bf16 table conversion.
// ---------------------------------------------------------------------------
__global__ void k_cvt(const float* __restrict__ src, u16* __restrict__ dst, int n4)
{
    int i = blockIdx.x * 256 + threadIdx.x;
    int stride = gridDim.x * 256;
    for (; i < n4; i += stride) {
        float4 v = ((const float4*)src)[i];
        st_bf16x4(&dst[(size_t)i*4], v);
    }
}

// ---------------------------------------------------------------------------
// nconst[n][c] = node_ebd[n] @ W[0:128][c]  (MFMA).
// ---------------------------------------------------------------------------
__global__ __launch_bounds__(256) void k_nconst(
    const u16* __restrict__ NB, const u16* __restrict__ WTe,
    float* __restrict__ nconst)
{
    __shared__ __align__(16) u16 sN[64][136];
    const int tid = threadIdx.x;
    const int e0 = blockIdx.x * 64;
    #pragma unroll
    for (int f = tid; f < 1024; f += 256) {
        int r = f >> 4, c = f & 15;
        *(uint4*)&sN[r][8*c] = ((const uint4*)&NB[(size_t)(e0 + r)*128])[c];
    }
    __syncthreads();

    const int w = tid >> 6, l = tid & 63;
    const int lr = l & 15, hq = l >> 4, lk = hq * 8;

    f32x4 acc[4][3] = {};
    #pragma unroll
    for (int kk = 0; kk < 4; ++kk) {
        bf16x8 a[4], b[3];
        #pragma unroll
        for (int m = 0; m < 4; ++m)
            a[m] = *(const bf16x8*)&sN[16*m + lr][kk*32 + lk];
        #pragma unroll
        for (int nf = 0; nf < 3; ++nf)
            b[nf] = *(const bf16x8*)&WTe[(size_t)(48*w + 16*nf + lr)*320 + kk*32 + lk];
        #pragma unroll
        for (int m = 0; m < 4; ++m)
            #pragma unroll
            for (int nf = 0; nf < 3; ++nf)
                acc[m][nf] = __builtin_amdgcn_mfma_f32_16x16x32_bf16(a[m], b[nf], acc[m][nf], 0, 0, 0);
    }
    #pragma unroll
    for (int nf = 0; nf < 3; ++nf) {
        int c = 48*w + 16*nf + lr;
        #pragma unroll
        for (int m = 0; m < 4; ++m)
            #pragma unroll
            for (int j = 0; j < 4; ++j) {
                int r = 16*m + 4*hq + j;
                nconst[(size_t)(e0 + r)*192 + c] = acc[m][nf][j];
            }
    }
}

// ---------------------------------------------------------------------------
// CSR builds.
// ---------------------------------------------------------------------------
__global__ void k_count(const int* __restrict__ key, int* __restrict__ cnt)
{
    int e = blockIdx.x * 256 + threadIdx.x;
    atomicAdd(&cnt[key[e]], 1);
}

__global__ void k_scan(const int* __restrict__ cnt, int* __restrict__ off,
                       int* __restrict__ cursor)
{
    __shared__ int wa[1024];
    int t = threadIdx.x;
    int a0 = cnt[4*t], a1 = cnt[4*t+1], a2 = cnt[4*t+2], a3 = cnt[4*t+3];
    int s1 = a0 + a1, s2 = s1 + a2, s3 = s2 + a3;
    wa[t] = s3;
    __syncthreads();
    for (int d = 1; d < 1024; d <<= 1) {
        int x = wa[t];
        int y = (t >= d) ? wa[t-d] : 0;
        __syncthreads();
        wa[t] = x + y;
        __syncthreads();
    }
    int excl = (t == 0) ? 0 : wa[t-1];
    off[4*t]   = excl;        cursor[4*t]   = excl;
    off[4*t+1] = excl + a0;   cursor[4*t+1] = excl + a0;
    off[4*t+2] = excl + s1;   cursor[4*t+2] = excl + s1;
    off[4*t+3] = excl + s2;   cursor[4*t+3] = excl + s2;
    if (t == 1023) off[4096] = excl + s3;
}

__global__ void k_fill(const int* __restrict__ key, int* __restrict__ cursor,
                       int* __restrict__ csr)
{
    int e = blockIdx.x * 256 + threadIdx.x;
    int pos = atomicAdd(&cursor[key[e]], 1);
    csr[pos] = e;
}

__global__ void k_fill_rank(const int* __restrict__ key, int* __restrict__ cursor,
                            int* __restrict__ rank)
{
    int e = blockIdx.x * 256 + threadIdx.x;
    int pos = atomicAdd(&cursor[key[e]], 1);
    rank[e] = pos;
}

// ---------------------------------------------------------------------------
// Angle CSR scan over eij2a (262144 segments): 3-phase scan.
// ---------------------------------------------------------------------------
__global__ void k_scan2a(const int* __restrict__ cnt2, int* __restrict__ bsum)
{
    __shared__ int wa[256];
    int b = blockIdx.x, t = threadIdx.x;
    int4 v = ((const int4*)cnt2)[b*256 + t];
    wa[t] = v.x + v.y + v.z + v.w;
    __syncthreads();
    for (int d = 128; d > 0; d >>= 1) {
        if (t < d) wa[t] += wa[t+d];
        __syncthreads();
    }
    if (t == 0) bsum[b] = wa[0];
}

__global__ void k_scan2b(const int* __restrict__ bsum, int* __restrict__ boff)
{
    __shared__ int wa[256];
    int t = threadIdx.x;
    wa[t] = bsum[t];
    __syncthreads();
    for (int d = 1; d < 256; d <<= 1) {
        int x = wa[t];
        int y = (t >= d) ? wa[t-d] : 0;
        __syncthreads();
        wa[t] = x + y;
        __syncthreads();
    }
    boff[t] = (t == 0) ? 0 : wa[t-1];
}

__global__ void k_scan2c(const int* __restrict__ cnt2, const int* __restrict__ boff,
                         int* __restrict__ off2, int* __restrict__ cursor2)
{
    __shared__ int wa[256];
    int b = blockIdx.x, t = threadIdx.x;
    int4 v = ((const int4*)cnt2)[b*256 + t];
    int s1 = v.x, s2 = s1 + v.y, s3 = s2 + v.z, s4 = s3 + v.w;
    wa[t] = s4;
    __syncthreads();
    for (int d = 1; d < 256; d <<= 1) {
        int x = wa[t];
        int y = (t >= d) ? wa[t-d] : 0;
        __syncthreads();
        wa[t] = x + y;
        __syncthreads();
    }
    int base = boff[b] + ((t == 0) ? 0 : wa[t-1]);
    int i = (b*256 + t)*4;
    off2[i]   = base;      cursor2[i]   = base;
    off2[i+1] = base + s1; cursor2[i+1] = base + s1;
    off2[i+2] = base + s2; cursor2[i+2] = base + s2;
    off2[i+3] = base + s3; cursor2[i+3] = base + s3;
    if (b == 255 && t == 255) off2[NEDGE_] = NANGLE_;
}

// ---------------------------------------------------------------------------
// Flat edge GEMM over CSR-ordered tiles + fused segmented h2g2.
// ---------------------------------------------------------------------------
__global__ __launch_bounds__(256, 4) void k_edge_flat(
    const u16* __restrict__ NB, const u16* __restrict__ EB,
    const float* __restrict__ h2, const float* __restrict__ sw,
    const int* __restrict__ n2e, const int* __restrict__ n_ext2e,
    const int* __restrict__ csr,
    const u16* __restrict__ WTe, const float* __restrict__ nconst,
    const float* __restrict__ bne, const float* __restrict__ bes,
    const float* __restrict__ e_res0,
    float* __restrict__ msg,
    float* __restrict__ h2g2_e, float* __restrict__ h2g2_n,
    float* __restrict__ e_out)
{
    __shared__ __align__(16) u16 sA[64][200];
    __shared__ float sH[4][576];
    __shared__ int   s_eid[64];
    __shared__ int   s_node[64];
    __shared__ int   s_g[64];
    __shared__ float s_sw[64];
    __shared__ float s_h2[64][3];
    __shared__ int   s_segstart[65];
    __shared__ int   s_nseg;

    const int tid = threadIdx.x;
    const int w  = tid >> 6, l = tid & 63;
    const int lr = l & 15, hq = l >> 4, lk = hq * 8;
    const int base = blockIdx.x * 64;

    if (tid < 64) {
        int e = csr[base + tid];
        s_eid[tid]  = e;
        s_node[tid] = n2e[e];
        s_g[tid]    = n_ext2e[e];
        s_sw[tid]   = sw[e];
        s_h2[tid][0] = h2[e*3];
        s_h2[tid][1] = h2[e*3+1];
        s_h2[tid][2] = h2[e*3+2];
    }
    __syncthreads();

    if (tid < 64) {
        bool flag = (tid == 0) || (s_node[tid] != s_node[tid-1]);
        unsigned long long mask = __ballot(flag);
        if (flag) {
            int sid = __popcll(mask & ((1ull << tid) - 1ull));
            s_segstart[sid] = tid;
        }
        if (tid == 0) {
            int ns = __popcll(mask);
            s_nseg = ns;
            s_segstart[ns] = 64;
        }
    }

    #pragma unroll
    for (int f = tid; f < 1024; f += 256) {
        int r = f >> 4, c = f & 15;
        *(uint4*)&sA[r][8*c] = ((const uint4*)&NB[(size_t)s_g[r]*128])[c];
    }
    #pragma unroll
    for (int f = tid; f < 512; f += 256) {
        int r = f >> 3, c = f & 7;
        *(uint4*)&sA[r][128 + 8*c] = ((const uint4*)&EB[(size_t)s_eid[r]*64])[c];
    }
    __syncthreads();

    float bias[3], rres[3];
    int   cful[3];
    #pragma unroll
    for (int nf = 0; nf < 3; ++nf) {
        int c = 48*w + 16*nf + lr;
        cful[nf] = c;
        bias[nf] = (c < 128) ? bne[c] : bes[c-128];
        rres[nf] = (c < 128) ? 0.f    : e_res0[c-128];
    }

    f32x4 acc[4][3] = {};
    #pragma unroll
    for (int kk = 0; kk < 6; ++kk) {
        bf16x8 a[4], b[3];
        #pragma unroll
        for (int m = 0; m < 4; ++m)
            a[m] = *(const bf16x8*)&sA[16*m + lr][kk*32 + lk];
        #pragma unroll
        for (int nf = 0; nf < 3; ++nf)
            b[nf] = *(const bf16x8*)&WTe[(size_t)cful[nf]*320 + 128 + kk*32 + lk];
        #pragma unroll
        for (int m = 0; m < 4; ++m)
            #pragma unroll
            for (int nf = 0; nf < 3; ++nf)
                acc[m][nf] = __builtin_amdgcn_mfma_f32_16x16x32_bf16(a[m], b[nf], acc[m][nf], 0, 0, 0);
    }

    #pragma unroll
    for (int nf = 0; nf < 3; ++nf) {
        int c = cful[nf];
        if (c < 128) {
            #pragma unroll
            for (int m = 0; m < 4; ++m)
                #pragma unroll
                for (int j = 0; j < 4; ++j) {
                    int r = 16*m + 4*hq + j;
                    float ncv = nconst[(size_t)s_node[r]*192 + c];
                    acc[m][nf][j] = silu_(acc[m][nf][j] + ncv + bias[nf]) * s_sw[r];
                }
        } else {
            int c2 = c - 128;
            #pragma unroll
            for (int m = 0; m < 4; ++m)
                #pragma unroll
                for (int j = 0; j < 4; ++j) {
                    int r = 16*m + 4*hq + j;
                    float ncv = nconst[(size_t)s_node[r]*192 + c];
                    e_out[(size_t)s_eid[r]*64 + c2] =
                        bu2f(sA[r][128 + c2]) + rres[nf] * silu_(acc[m][nf][j] + ncv + bias[nf]);
                }
        }
    }

    // ---- segmented msg reduction ----
    const int nseg = s_nseg;
    for (int s = 0; s < nseg; ++s) {
        int rs = s_segstart[s], re = s_segstart[s+1];
        int nd = s_node[rs];
        #pragma unroll
        for (int nf = 0; nf < 3; ++nf) {
            if (cful[nf] >= 128) continue;
            float v = 0.f;
            #pragma unroll
            for (int m = 0; m < 4; ++m)
                #pragma unroll
                for (int j = 0; j < 4; ++j) {
                    int r = 16*m + 4*hq + j;
                    v += (r >= rs && r < re) ? acc[m][nf][j] : 0.f;
                }
            v += __shfl_xor(v, 16);
            v += __shfl_xor(v, 32);
            if (hq == 0) atomicAdd(&msg[(size_t)nd*128 + cful[nf]], v);
        }
    }

    // ---- segmented h2g2 accumulation ----
    for (int s = 0; s < nseg; ++s) {
        int rs = s_segstart[s], re = s_segstart[s+1];
        int nd = s_node[rs];
        int lo = max(16*w, rs), hi = min(16*w + 16, re);
        float hacc[9] = {0.f,0.f,0.f,0.f,0.f,0.f,0.f,0.f,0.f};
        for (int r = lo; r < hi; ++r) {
            float swv = s_sw[r];
            float s0 = s_h2[r][0] * swv;
            float s1 = s_h2[r][1] * swv;
            float s2 = s_h2[r][2] * swv;
            float eb = bu2f(sA[r][128 + l]);
            float n0 = bu2f(sA[r][l]);
            float n1 = bu2f(sA[r][64 + l]);
            hacc[0] = fmaf(s0, eb, hacc[0]);
            hacc[1] = fmaf(s1, eb, hacc[1]);
            hacc[2] = fmaf(s2, eb, hacc[2]);
            hacc[3] = fmaf(s0, n0, hacc[3]);
            hacc[4] = fmaf(s0, n1, hacc[4]);
            hacc[5] = fmaf(s1, n0, hacc[5]);
            hacc[6] = fmaf(s1, n1, hacc[6]);
            hacc[7] = fmaf(s2, n0, hacc[7]);
            hacc[8] = fmaf(s2, n1, hacc[8]);
        }
        #pragma unroll
        for (int q = 0; q < 3; ++q) sH[w][q*64 + l] = hacc[q];
        #pragma unroll
        for (int q = 0; q < 6; ++q) sH[w][192 + q*64 + l] = hacc[3+q];
        __syncthreads();
        for (int i = tid; i < 576; i += 256) {
            float v = sH[0][i] + sH[1][i] + sH[2][i] + sH[3][i];
            if (i < 192) atomicAdd(&h2g2_e[(size_t)nd*192 + i], v);
            else         atomicAdd(&h2g2_n[(size_t)nd*384 + (i - 192)], v);
        }
        __syncthreads();
    }
}

// ---------------------------------------------------------------------------
// Angle GEMM via MFMA: rank-permuted ea writes (bf16) + a_out. NO atomics.
// ---------------------------------------------------------------------------
__global__ __launch_bounds__(256) void k_angle_mfma(
    const u16* __restrict__ NB, const u16* __restrict__ EB,
    const u16* __restrict__ AB, const float* __restrict__ a_sw,
    const int* __restrict__ n2a, const int* __restrict__ eij2a,
    const int* __restrict__ eik2a, const int* __restrict__ rank2,
    const u16* __restrict__ WTa,
    const float* __restrict__ b1, const float* __restrict__ bA,
    const float* __restrict__ a_res0,
    u16* __restrict__ ea, float* __restrict__ a_out)
{
    __shared__ __align__(16) u16 sA[64][296];
    __shared__ int s_na[64], s_ij[64], s_ik[64], s_rk[64];
    const int tid = threadIdx.x;
    const int a0 = blockIdx.x * 64;

    if (tid < 64) {
        s_na[tid] = n2a[a0 + tid];
        s_ij[tid] = eij2a[a0 + tid];
        s_ik[tid] = eik2a[a0 + tid];
        s_rk[tid] = rank2[a0 + tid];
    }
    __syncthreads();

    #pragma unroll
    for (int f = tid; f < 256; f += 256) {          // angle_ebd from AB (bf16)
        int a = f >> 2, c = f & 3;
        *(uint4*)&sA[a][8*c] = ((const uint4*)&AB[(size_t)(a0 + a)*32])[c];
    }
    #pragma unroll
    for (int f = tid; f < 1024; f += 256) {         // node from NB
        int a = f >> 4, c = f & 15;
        *(uint4*)&sA[a][32 + 8*c] = ((const uint4*)&NB[(size_t)s_na[a]*128])[c];
    }
    #pragma unroll
    for (int f = tid; f < 512; f += 256) {          // edge_ik from EB
        int a = f >> 3, c = f & 7;
        *(uint4*)&sA[a][160 + 8*c] = ((const uint4*)&EB[(size_t)s_ik[a]*64])[c];
    }
    #pragma unroll
    for (int f = tid; f < 512; f += 256) {          // edge_ij from EB
        int a = f >> 3, c = f & 7;
        *(uint4*)&sA[a][224 + 8*c] = ((const uint4*)&EB[(size_t)s_ij[a]*64])[c];
    }
    __syncthreads();

    const int w = tid >> 6, l = tid & 63;
    const int lr = l & 15, lk = (l >> 4) * 8;

    f32x4 acc[6] = {};
    #pragma unroll
    for (int kk = 0; kk < 9; ++kk) {
        bf16x8 a = *(const bf16x8*)&sA[16*w + lr][kk*32 + lk];
        #pragma unroll
        for (int n = 0; n < 6; ++n) {
            bf16x8 b = *(const bf16x8*)&WTa[(size_t)(16*n + lr)*288 + kk*32 + lk];
            acc[n] = __builtin_amdgcn_mfma_f32_16x16x32_bf16(a, b, acc[n], 0, 0, 0);
        }
    }

    #pragma unroll
    for (int n = 0; n < 6; ++n) {
        int c = 16*n + lr;
        if (n < 4) {
            float bb = b1[c];
            #pragma unroll
            for (int j = 0; j < 4; ++j) {
                int r = 16*w + ((l >> 4) << 2) + j;
                float eav = silu_(acc[n][j] + bb) * a_sw[a0 + r];
                ea[(size_t)s_rk[r]*64 + c] = f2bu(eav);
            }
        } else {
            int c2 = c - 64;
            float bb = bA[c2], rr = a_res0[c2];
            #pragma unroll
            for (int j = 0; j < 4; ++j) {
                int r = 16*w + ((l >> 4) << 2) + j;
                size_t idx = (size_t)(a0 + r)*32 + c2;
                a_out[idx] = bu2f(sA[r][c2]) + rr * silu_(acc[n][j] + bb);
            }
        }
    }
}

// ---------------------------------------------------------------------------
// Contiguous ea gather per edge -> W2 MFMA -> e_out += e_res1 * msg.
// ---------------------------------------------------------------------------
__global__ __launch_bounds__(256) void k_edgefin_mfma(
    const u16* __restrict__ ea,
    const int* __restrict__ off2,
    const u16* __restrict__ WT2,
    const float* __restrict__ b2_, const float* __restrict__ e_res1,
    float* __restrict__ e_out)
{
    __shared__ __align__(16) u16 sR[64][72];
    const int tid = threadIdx.x;
    const int e0 = blockIdx.x * 64;
    const int w = tid >> 6, l = tid & 63;

    #pragma unroll
    for (int r16 = 0; r16 < 16; ++r16) {
        int r = w*16 + r16;
        int e = e0 + r;
        float s = 0.f;
        int jb = off2[e], je = off2[e+1];
        for (int j = jb; j < je; ++j)
            s += bu2f(ea[(size_t)j*64 + l]);
        sR[r][l] = f2bu(s);
    }
    __syncthreads();

    const int lr = l & 15, lk = (l >> 4) * 8;

    f32x4 acc[4] = {};
    #pragma unroll
    for (int kk = 0; kk < 2; ++kk) {
        bf16x8 b = *(const bf16x8*)&WT2[(size_t)(16*w + lr)*64 + kk*32 + lk];
        #pragma unroll
        for (int m = 0; m < 4; ++m) {
            bf16x8 a = *(const bf16x8*)&sR[16*m + lr][kk*32 + lk];
            acc[m] = __builtin_amdgcn_mfma_f32_16x16x32_bf16(a, b, acc[m], 0, 0, 0);
        }
    }
    int c = 16*w + lr;
    float bb = b2_[c], rr = e_res1[c];
    #pragma unroll
    for (int m = 0; m < 4; ++m)
        #pragma unroll
        for (int j = 0; j < 4; ++j) {
            size_t idx = (size_t)(e0 + 16*m + ((l >> 4) << 2) + j)*64 + c;
            e_out[idx] += rr * silu_(acc[m][j] + bb);
        }
}

// ---------------------------------------------------------------------------
// Per-node finalize.
// ---------------------------------------------------------------------------
__global__ void k_node_final(const float* __restrict__ node_ext,
                             const float* __restrict__ h2g2_e,
                             const float* __restrict__ h2g2_n,
                             const float* __restrict__ msg,
                             const float* __restrict__ Wns,  const float* __restrict__ bns,
                             const float* __restrict__ Wsym, const float* __restrict__ bsym,
                             const float* __restrict__ nr0, const float* __restrict__ nr1,
                             const float* __restrict__ nr2,
                             float* __restrict__ n_out)
{
    __shared__ float x[128];
    __shared__ float he[192];
    __shared__ float hn[384];
    __shared__ float symc[768];

    int n = blockIdx.x;
    int c = threadIdx.x;

    x[c] = node_ext[(size_t)n*128 + c];
    for (int i = c; i < 192; i += 128) he[i] = h2g2_e[(size_t)n*192 + i];
    for (int i = c; i < 384; i += 128) hn[i] = h2g2_n[(size_t)n*384 + i];
    __syncthreads();

    const float SCALE = 1.0f / (6.4f * 3.0f);
    for (int i = c; i < 768; i += 128) {
        float s;
        if (i < 256) {
            int a = i >> 6, j = i & 63;
            s = he[a]*he[j] + he[64+a]*he[64+j] + he[128+a]*he[128+j];
        } else {
            int i2 = i - 256;
            int a = i2 >> 7, j = i2 & 127;
            s = hn[a]*hn[j] + hn[128+a]*hn[128+j] + hn[256+a]*hn[256+j];
        }
        symc[i] = s * SCALE;
    }
    __syncthreads();

    float accs = 0.f;
    #pragma unroll 8
    for (int k = 0; k < 128; ++k) accs = fmaf(x[k], Wns[k*128 + c], accs);
    float self_ = silu_(accs + bns[c]);

    float accy = 0.f;
    #pragma unroll 8
    for (int k = 0; k < 768; ++k) accy = fmaf(symc[k], Wsym[k*128 + c], accy);
    float sym_ = silu_(accy + bsym[c]);

    float m = msg[(size_t)n*128 + c] * (1.0f / 6.4f);
    n_out[(size_t)n*128 + c] = x[c] + nr0[c]*self_ + nr1[c]*sym_ + nr2[c]*m;
}

// ---------------------------------------------------------------------------
extern "C" void kernel_launch(void* const* d_in, const int* in_sizes, int n_in,
                              void* d_out, int out_size, void* d_ws, size_t ws_size,
                              hipStream_t stream)
{
    const float* node_ext  = (const float*)d_in[0];
    const float* edge_ebd  = (const float*)d_in[1];
    const float* h2        = (const float*)d_in[2];
    const float* angle_ebd = (const float*)d_in[3];
    const float* sw        = (const float*)d_in[6];
    const float* a_sw      = (const float*)d_in[9];
    const int*  edge_index  = (const int*)d_in[10];
    const int*  angle_index = (const int*)d_in[11];
    const int* n2e     = edge_index;
    const int* n_ext2e = edge_index + NEDGE_;
    const int* n2a     = angle_index;
    const int* eij2a   = angle_index + NANGLE_;
    const int* eik2a   = angle_index + 2*NANGLE_;

    const float* Wns  = (const float*)d_in[12];
    const float* bns  = (const float*)d_in[13];
    const float* Wsym = (const float*)d_in[14];
    const float* bsym = (const float*)d_in[15];
    const float* Wne  = (const float*)d_in[16];
    const float* bne  = (const float*)d_in[17];
    const float* Wes  = (const float*)d_in[18];
    const float* bes  = (const float*)d_in[19];
    const float* W1   = (const float*)d_in[20];
    const float* b1   = (const float*)d_in[21];
    const float* W2   = (const float*)d_in[22];
    const float* b2_  = (const float*)d_in[23];
    const float* WA   = (const float*)d_in[24];
    const float* bA   = (const float*)d_in[25];
    const float* nr0  = (const float*)d_in[26];
    const float* nr1  = (const float*)d_in[27];
    const float* nr2  = (const float*)d_in[28];
    const float* er0  = (const float*)d_in[29];
    const float* er1  = (const float*)d_in[30];
    const float* ar0  = (const float*)d_in[31];

    // workspace layout
    char* wsp = (char*)d_ws;
    u16*   ea      = (u16*)wsp;    wsp += (size_t)NANGLE_ * 64 * 2;
    u16*   EB      = (u16*)wsp;    wsp += (size_t)NEDGE_ * 64 * 2;
    u16*   NB      = (u16*)wsp;    wsp += (size_t)NALL_ * 128 * 2;
    u16*   AB      = (u16*)wsp;    wsp += (size_t)NANGLE_ * 32 * 2;
    // zeroed region: [cnt | cnt2 | msg | h2g2_e | h2g2_n]
    int*   cnt     = (int*)wsp;    wsp += 4096 * 4;
    int*   cnt2    = (int*)wsp;    wsp += (size_t)NEDGE_ * 4;
    float* msg     = (float*)wsp;  wsp += (size_t)NLOC_ * 128 * 4;
    float* h2g2_e  = (float*)wsp;  wsp += (size_t)NLOC_ * 192 * 4;
    float* h2g2_n  = (float*)wsp;  wsp += (size_t)NLOC_ * 384 * 4;
    size_t zero_bytes = 4096*4 + (size_t)NEDGE_*4 + (size_t)NLOC_*128*4
                      + (size_t)NLOC_*192*4 + (size_t)NLOC_*384*4;
    int*   off     = (int*)wsp;    wsp += 4104 * 4;
    int*   cursor  = (int*)wsp;    wsp += 4096 * 4;
    int*   csr     = (int*)wsp;    wsp += (size_t)NEDGE_ * 4;
    int*   off2    = (int*)wsp;    wsp += ((size_t)NEDGE_ + 16) * 4;
    int*   cursor2 = (int*)wsp;    wsp += (size_t)NEDGE_ * 4;
    int*   bsum    = (int*)wsp;    wsp += 256 * 4;
    int*   boff    = (int*)wsp;    wsp += 256 * 4;
    int*   rank2   = (int*)wsp;    wsp += (size_t)NANGLE_ * 4;
    float* nconst  = (float*)wsp;  wsp += (size_t)NLOC_ * 192 * 4;
    u16*   WTe     = (u16*)wsp;    wsp += 192 * 320 * 2;
    u16*   WTa     = (u16*)wsp;    wsp += 96 * 288 * 2;
    u16*   WT2     = (u16*)wsp;    wsp += 64 * 64 * 2;

    hipMemsetAsync(cnt, 0, zero_bytes, stream);

    float* n_out = (float*)d_out;
    float* e_out = n_out + (size_t)NLOC_ * 128;
    float* a_out = e_out + (size_t)NEDGE_ * 64;

    k_prep   <<<352, 320, 0, stream>>>(Wne, Wes, W1, WA, W2, WTe, WTa, WT2);
    k_cvt    <<<768, 256, 0, stream>>>(node_ext, NB, NALL_*128/4);
    k_cvt    <<<4096, 256, 0, stream>>>(edge_ebd, EB, NEDGE_*64/4);
    k_cvt    <<<4096, 256, 0, stream>>>(angle_ebd, AB, NANGLE_*32/4);
    k_count  <<<NEDGE_/256, 256, 0, stream>>>(n2e, cnt);
    k_scan   <<<1, 1024, 0, stream>>>(cnt, off, cursor);
    k_fill   <<<NEDGE_/256, 256, 0, stream>>>(n2e, cursor, csr);
    k_count  <<<NANGLE_/256, 256, 0, stream>>>(eij2a, cnt2);
    k_scan2a <<<256, 256, 0, stream>>>(cnt2, bsum);
    k_scan2b <<<1, 256, 0, stream>>>(bsum, boff);
    k_scan2c <<<256, 256, 0, stream>>>(cnt2, boff, off2, cursor2);
    k_fill_rank <<<NANGLE_/256, 256, 0, stream>>>(eij2a, cursor2, rank2);

    k_nconst <<<NLOC_/64, 256, 0, stream>>>(NB, WTe, nconst);
    k_edge_flat <<<NEDGE_/64, 256, 0, stream>>>(NB, EB, h2, sw, n2e, n_ext2e, csr,
                                                WTe, nconst, bne, bes, er0,
                                                msg, h2g2_e, h2g2_n, e_out);
    k_angle_mfma <<<NANGLE_/64, 256, 0, stream>>>(NB, EB, AB, a_sw,
                                                  n2a, eij2a, eik2a, rank2,
                                                  WTa, b1, bA, ar0, ea, a_out);
    k_edgefin_mfma <<<NEDGE_/64, 256, 0, stream>>>(ea, off2, WT2, b2_, er1, e_out);
    k_node_final <<<NLOC_, 128, 0, stream>>>(node_ext, h2g2_e, h2g2_n, msg,
                                             Wns, bns, Wsym, bsym,
                                             nr0, nr1, nr2, n_out);
}

// Round 9
// 454.309 us; speedup vs baseline: 9.3931x; 1.0950x over previous
//
#include <hip/hip_runtime.h>
#include <hip/hip_bf16.h>

#define NLOC_   4096
#define NALL_   6144
#define NEDGE_  262144
#define NANGLE_ 409600

typedef __bf16 bf16x8 __attribute__((ext_vector_type(8)));
typedef float  f32x4  __attribute__((ext_vector_type(4)));
typedef unsigned short u16;

__device__ __forceinline__ float silu_(float x){ return x / (1.0f + __expf(-x)); }

__device__ __forceinline__ u16 f2bu(float f){
    union { float f; unsigned u; } v; v.f = f;
    unsigned r = v.u + 0x7fffu + ((v.u >> 16) & 1u);
    return (u16)(r >> 16);
}
__device__ __forceinline__ float bu2f(u16 b){
    union { unsigned u; float f; } v; v.u = ((unsigned)b) << 16; return v.f;
}
__device__ __forceinline__ void st_bf16x4(u16* dst, float4 v){
    unsigned lo = (unsigned)f2bu(v.x) | ((unsigned)f2bu(v.y) << 16);
    unsigned hi = (unsigned)f2bu(v.z) | ((unsigned)f2bu(v.w) << 16);
    *reinterpret_cast<uint2*>(dst) = make_uint2(lo, hi);
}

// ---------------------------------------------------------------------------
// Weight prep (f32 -> bf16 transposed): WTe[192][320], WTa[96][288],
// WT2[64][64], WsymT[128][768], WnsT[128][128].
// ---------------------------------------------------------------------------
__global__ void k_prep(const float* __restrict__ Wne, const float* __restrict__ Wes,
                       const float* __restrict__ W1,  const float* __restrict__ WA,
                       const float* __restrict__ W2,  const float* __restrict__ Wsym,
                       const float* __restrict__ Wns,
                       u16* __restrict__ WTe, u16* __restrict__ WTa, u16* __restrict__ WT2,
                       u16* __restrict__ WsymT, u16* __restrict__ WnsT)
{
    int b = blockIdx.x, t = threadIdx.x;
    if (b < 192) {
        if (t < 320) WTe[b*320 + t] = f2bu(b < 128 ? Wne[t*128 + b] : Wes[t*64 + (b-128)]);
    } else if (b < 288) {
        int n = b - 192;
        if (t < 288) WTa[n*288 + t] = f2bu(n < 64 ? W1[t*64 + n] : WA[t*32 + (n-64)]);
    } else if (b < 352) {
        int n = b - 288;
        if (t < 64)  WT2[n*64 + t] = f2bu(W2[t*64 + n]);
    } else if (b < 480) {
        int n = b - 352;
        if (t < 768) WsymT[n*768 + t] = f2bu(Wsym[t*128 + n]);
    } else {
        int n = b - 480;
        if (t < 128) WnsT[n*128 + t] = f2bu(Wns[t*128 + n]);
    }
}

// ---------------------------------------------------------------------------
// Generic f32 -> bf16 table conversion.
// ---------------------------------------------------------------------------
__global__ void k_cvt(const float* __restrict__ src, u16* __restrict__ dst, int n4)
{
    int i = blockIdx.x * 256 + threadIdx.x;
    int stride = gridDim.x * 256;
    for (; i < n4; i += stride) {
        float4 v = ((const float4*)src)[i];
        st_bf16x4(&dst[(size_t)i*4], v);
    }
}

// ---------------------------------------------------------------------------
// nconst[n][c] = node_ebd[n] @ W[0:128][c]  (MFMA).
// ---------------------------------------------------------------------------
__global__ __launch_bounds__(256) void k_nconst(
    const u16* __restrict__ NB, const u16* __restrict__ WTe,
    float* __restrict__ nconst)
{
    __shared__ __align__(16) u16 sN[64][136];
    const int tid = threadIdx.x;
    const int e0 = blockIdx.x * 64;
    #pragma unroll
    for (int f = tid; f < 1024; f += 256) {
        int r = f >> 4, c = f & 15;
        *(uint4*)&sN[r][8*c] = ((const uint4*)&NB[(size_t)(e0 + r)*128])[c];
    }
    __syncthreads();

    const int w = tid >> 6, l = tid & 63;
    const int lr = l & 15, hq = l >> 4, lk = hq * 8;

    f32x4 acc[4][3] = {};
    #pragma unroll
    for (int kk = 0; kk < 4; ++kk) {
        bf16x8 a[4], b[3];
        #pragma unroll
        for (int m = 0; m < 4; ++m)
            a[m] = *(const bf16x8*)&sN[16*m + lr][kk*32 + lk];
        #pragma unroll
        for (int nf = 0; nf < 3; ++nf)
            b[nf] = *(const bf16x8*)&WTe[(size_t)(48*w + 16*nf + lr)*320 + kk*32 + lk];
        #pragma unroll
        for (int m = 0; m < 4; ++m)
            #pragma unroll
            for (int nf = 0; nf < 3; ++nf)
                acc[m][nf] = __builtin_amdgcn_mfma_f32_16x16x32_bf16(a[m], b[nf], acc[m][nf], 0, 0, 0);
    }
    #pragma unroll
    for (int nf = 0; nf < 3; ++nf) {
        int c = 48*w + 16*nf + lr;
        #pragma unroll
        for (int m = 0; m < 4; ++m)
            #pragma unroll
            for (int j = 0; j < 4; ++j) {
                int r = 16*m + 4*hq + j;
                nconst[(size_t)(e0 + r)*192 + c] = acc[m][nf][j];
            }
    }
}

// ---------------------------------------------------------------------------
// CSR builds.
// ---------------------------------------------------------------------------
__global__ void k_count(const int* __restrict__ key, int* __restrict__ cnt)
{
    int e = blockIdx.x * 256 + threadIdx.x;
    atomicAdd(&cnt[key[e]], 1);
}

__global__ void k_scan(const int* __restrict__ cnt, int* __restrict__ off,
                       int* __restrict__ cursor)
{
    __shared__ int wa[1024];
    int t = threadIdx.x;
    int a0 = cnt[4*t], a1 = cnt[4*t+1], a2 = cnt[4*t+2], a3 = cnt[4*t+3];
    int s1 = a0 + a1, s2 = s1 + a2, s3 = s2 + a3;
    wa[t] = s3;
    __syncthreads();
    for (int d = 1; d < 1024; d <<= 1) {
        int x = wa[t];
        int y = (t >= d) ? wa[t-d] : 0;
        __syncthreads();
        wa[t] = x + y;
        __syncthreads();
    }
    int excl = (t == 0) ? 0 : wa[t-1];
    off[4*t]   = excl;        cursor[4*t]   = excl;
    off[4*t+1] = excl + a0;   cursor[4*t+1] = excl + a0;
    off[4*t+2] = excl + s1;   cursor[4*t+2] = excl + s1;
    off[4*t+3] = excl + s2;   cursor[4*t+3] = excl + s2;
    if (t == 1023) off[4096] = excl + s3;
}

// fill both csr list and inverse rank
__global__ void k_fill_both(const int* __restrict__ key, int* __restrict__ cursor,
                            int* __restrict__ csr, int* __restrict__ rank)
{
    int e = blockIdx.x * 256 + threadIdx.x;
    int pos = atomicAdd(&cursor[key[e]], 1);
    csr[pos] = e;
    rank[e] = pos;
}

__global__ void k_fill_rank(const int* __restrict__ key, int* __restrict__ cursor,
                            int* __restrict__ rank)
{
    int e = blockIdx.x * 256 + threadIdx.x;
    int pos = atomicAdd(&cursor[key[e]], 1);
    rank[e] = pos;
}

// ---------------------------------------------------------------------------
// Angle CSR scan over eij2a (262144 segments): 3-phase scan.
// ---------------------------------------------------------------------------
__global__ void k_scan2a(const int* __restrict__ cnt2, int* __restrict__ bsum)
{
    __shared__ int wa[256];
    int b = blockIdx.x, t = threadIdx.x;
    int4 v = ((const int4*)cnt2)[b*256 + t];
    wa[t] = v.x + v.y + v.z + v.w;
    __syncthreads();
    for (int d = 128; d > 0; d >>= 1) {
        if (t < d) wa[t] += wa[t+d];
        __syncthreads();
    }
    if (t == 0) bsum[b] = wa[0];
}

__global__ void k_scan2b(const int* __restrict__ bsum, int* __restrict__ boff)
{
    __shared__ int wa[256];
    int t = threadIdx.x;
    wa[t] = bsum[t];
    __syncthreads();
    for (int d = 1; d < 256; d <<= 1) {
        int x = wa[t];
        int y = (t >= d) ? wa[t-d] : 0;
        __syncthreads();
        wa[t] = x + y;
        __syncthreads();
    }
    boff[t] = (t == 0) ? 0 : wa[t-1];
}

__global__ void k_scan2c(const int* __restrict__ cnt2, const int* __restrict__ boff,
                         int* __restrict__ off2, int* __restrict__ cursor2)
{
    __shared__ int wa[256];
    int b = blockIdx.x, t = threadIdx.x;
    int4 v = ((const int4*)cnt2)[b*256 + t];
    int s1 = v.x, s2 = s1 + v.y, s3 = s2 + v.z, s4 = s3 + v.w;
    wa[t] = s4;
    __syncthreads();
    for (int d = 1; d < 256; d <<= 1) {
        int x = wa[t];
        int y = (t >= d) ? wa[t-d] : 0;
        __syncthreads();
        wa[t] = x + y;
        __syncthreads();
    }
    int base = boff[b] + ((t == 0) ? 0 : wa[t-1]);
    int i = (b*256 + t)*4;
    off2[i]   = base;      cursor2[i]   = base;
    off2[i+1] = base + s1; cursor2[i+1] = base + s1;
    off2[i+2] = base + s2; cursor2[i+2] = base + s2;
    off2[i+3] = base + s3; cursor2[i+3] = base + s3;
    if (b == 255 && t == 255) off2[NEDGE_] = NANGLE_;
}

// ---------------------------------------------------------------------------
// Flat edge GEMM over CSR-ordered tiles + fused segmented h2g2.
// eself written compactly in CSR order (sequential); e_out NOT written here.
// ---------------------------------------------------------------------------
__global__ __launch_bounds__(256, 4) void k_edge_flat(
    const u16* __restrict__ NB, const u16* __restrict__ EB,
    const float* __restrict__ h2, const float* __restrict__ sw,
    const int* __restrict__ n2e, const int* __restrict__ n_ext2e,
    const int* __restrict__ csr,
    const u16* __restrict__ WTe, const float* __restrict__ nconst,
    const float* __restrict__ bne, const float* __restrict__ bes,
    float* __restrict__ msg,
    float* __restrict__ h2g2_e, float* __restrict__ h2g2_n,
    u16* __restrict__ eselfB)
{
    __shared__ __align__(16) u16 sA[64][200];
    __shared__ float sH[4][576];
    __shared__ int   s_eid[64];
    __shared__ int   s_node[64];
    __shared__ int   s_g[64];
    __shared__ float s_sw[64];
    __shared__ float s_h2[64][3];
    __shared__ int   s_segstart[65];
    __shared__ int   s_nseg;

    const int tid = threadIdx.x;
    const int w  = tid >> 6, l = tid & 63;
    const int lr = l & 15, hq = l >> 4, lk = hq * 8;
    const int base = blockIdx.x * 64;

    if (tid < 64) {
        int e = csr[base + tid];
        s_eid[tid]  = e;
        s_node[tid] = n2e[e];
        s_g[tid]    = n_ext2e[e];
        s_sw[tid]   = sw[e];
        s_h2[tid][0] = h2[e*3];
        s_h2[tid][1] = h2[e*3+1];
        s_h2[tid][2] = h2[e*3+2];
    }
    __syncthreads();

    if (tid < 64) {
        bool flag = (tid == 0) || (s_node[tid] != s_node[tid-1]);
        unsigned long long mask = __ballot(flag);
        if (flag) {
            int sid = __popcll(mask & ((1ull << tid) - 1ull));
            s_segstart[sid] = tid;
        }
        if (tid == 0) {
            int ns = __popcll(mask);
            s_nseg = ns;
            s_segstart[ns] = 64;
        }
    }

    #pragma unroll
    for (int f = tid; f < 1024; f += 256) {
        int r = f >> 4, c = f & 15;
        *(uint4*)&sA[r][8*c] = ((const uint4*)&NB[(size_t)s_g[r]*128])[c];
    }
    #pragma unroll
    for (int f = tid; f < 512; f += 256) {
        int r = f >> 3, c = f & 7;
        *(uint4*)&sA[r][128 + 8*c] = ((const uint4*)&EB[(size_t)s_eid[r]*64])[c];
    }
    __syncthreads();

    float bias[3];
    int   cful[3];
    #pragma unroll
    for (int nf = 0; nf < 3; ++nf) {
        int c = 48*w + 16*nf + lr;
        cful[nf] = c;
        bias[nf] = (c < 128) ? bne[c] : bes[c-128];
    }

    f32x4 acc[4][3] = {};
    #pragma unroll
    for (int kk = 0; kk < 6; ++kk) {
        bf16x8 a[4], b[3];
        #pragma unroll
        for (int m = 0; m < 4; ++m)
            a[m] = *(const bf16x8*)&sA[16*m + lr][kk*32 + lk];
        #pragma unroll
        for (int nf = 0; nf < 3; ++nf)
            b[nf] = *(const bf16x8*)&WTe[(size_t)cful[nf]*320 + 128 + kk*32 + lk];
        #pragma unroll
        for (int m = 0; m < 4; ++m)
            #pragma unroll
            for (int nf = 0; nf < 3; ++nf)
                acc[m][nf] = __builtin_amdgcn_mfma_f32_16x16x32_bf16(a[m], b[nf], acc[m][nf], 0, 0, 0);
    }

    #pragma unroll
    for (int nf = 0; nf < 3; ++nf) {
        int c = cful[nf];
        if (c < 128) {
            #pragma unroll
            for (int m = 0; m < 4; ++m)
                #pragma unroll
                for (int j = 0; j < 4; ++j) {
                    int r = 16*m + 4*hq + j;
                    float ncv = nconst[(size_t)s_node[r]*192 + c];
                    acc[m][nf][j] = silu_(acc[m][nf][j] + ncv + bias[nf]) * s_sw[r];
                }
        } else {
            int c2 = c - 128;
            #pragma unroll
            for (int m = 0; m < 4; ++m)
                #pragma unroll
                for (int j = 0; j < 4; ++j) {
                    int r = 16*m + 4*hq + j;
                    float ncv = nconst[(size_t)s_node[r]*192 + c];
                    eselfB[(size_t)(base + r)*64 + c2] =
                        f2bu(silu_(acc[m][nf][j] + ncv + bias[nf]));
                }
        }
    }

    // ---- segmented msg reduction ----
    const int nseg = s_nseg;
    for (int s = 0; s < nseg; ++s) {
        int rs = s_segstart[s], re = s_segstart[s+1];
        int nd = s_node[rs];
        #pragma unroll
        for (int nf = 0; nf < 3; ++nf) {
            if (cful[nf] >= 128) continue;
            float v = 0.f;
            #pragma unroll
            for (int m = 0; m < 4; ++m)
                #pragma unroll
                for (int j = 0; j < 4; ++j) {
                    int r = 16*m + 4*hq + j;
                    v += (r >= rs && r < re) ? acc[m][nf][j] : 0.f;
                }
            v += __shfl_xor(v, 16);
            v += __shfl_xor(v, 32);
            if (hq == 0) atomicAdd(&msg[(size_t)nd*128 + cful[nf]], v);
        }
    }

    // ---- segmented h2g2 accumulation ----
    for (int s = 0; s < nseg; ++s) {
        int rs = s_segstart[s], re = s_segstart[s+1];
        int nd = s_node[rs];
        int lo = max(16*w, rs), hi = min(16*w + 16, re);
        float hacc[9] = {0.f,0.f,0.f,0.f,0.f,0.f,0.f,0.f,0.f};
        for (int r = lo; r < hi; ++r) {
            float swv = s_sw[r];
            float s0 = s_h2[r][0] * swv;
            float s1 = s_h2[r][1] * swv;
            float s2 = s_h2[r][2] * swv;
            float eb = bu2f(sA[r][128 + l]);
            float n0 = bu2f(sA[r][l]);
            float n1 = bu2f(sA[r][64 + l]);
            hacc[0] = fmaf(s0, eb, hacc[0]);
            hacc[1] = fmaf(s1, eb, hacc[1]);
            hacc[2] = fmaf(s2, eb, hacc[2]);
            hacc[3] = fmaf(s0, n0, hacc[3]);
            hacc[4] = fmaf(s0, n1, hacc[4]);
            hacc[5] = fmaf(s1, n0, hacc[5]);
            hacc[6] = fmaf(s1, n1, hacc[6]);
            hacc[7] = fmaf(s2, n0, hacc[7]);
            hacc[8] = fmaf(s2, n1, hacc[8]);
        }
        #pragma unroll
        for (int q = 0; q < 3; ++q) sH[w][q*64 + l] = hacc[q];
        #pragma unroll
        for (int q = 0; q < 6; ++q) sH[w][192 + q*64 + l] = hacc[3+q];
        __syncthreads();
        for (int i = tid; i < 576; i += 256) {
            float v = sH[0][i] + sH[1][i] + sH[2][i] + sH[3][i];
            if (i < 192) atomicAdd(&h2g2_e[(size_t)nd*192 + i], v);
            else         atomicAdd(&h2g2_n[(size_t)nd*384 + (i - 192)], v);
        }
        __syncthreads();
    }
}

// ---------------------------------------------------------------------------
// Angle GEMM via MFMA, M-tile 32 (higher occupancy): rank-permuted ea rows
// written via LDS transpose (coalesced 16B/lane), a_out direct.
// ---------------------------------------------------------------------------
__global__ __launch_bounds__(256) void k_angle_mfma(
    const u16* __restrict__ NB, const u16* __restrict__ EB,
    const u16* __restrict__ AB, const float* __restrict__ a_sw,
    const int* __restrict__ n2a, const int* __restrict__ eij2a,
    const int* __restrict__ eik2a, const int* __restrict__ rank2,
    const u16* __restrict__ WTa,
    const float* __restrict__ b1, const float* __restrict__ bA,
    const float* __restrict__ a_res0,
    u16* __restrict__ ea, float* __restrict__ a_out)
{
    __shared__ __align__(16) u16 sA[32][296];
    __shared__ __align__(16) u16 sEA[32][64];
    __shared__ int s_na[32], s_ij[32], s_ik[32], s_rk[32];
    __shared__ float s_asw[32];
    const int tid = threadIdx.x;
    const int a0 = blockIdx.x * 32;

    if (tid < 32) {
        s_na[tid] = n2a[a0 + tid];
        s_ij[tid] = eij2a[a0 + tid];
        s_ik[tid] = eik2a[a0 + tid];
        s_rk[tid] = rank2[a0 + tid];
        s_asw[tid] = a_sw[a0 + tid];
    }
    __syncthreads();

    if (tid < 128) {                                 // angle_ebd from AB
        int r = tid >> 2, c = tid & 3;
        *(uint4*)&sA[r][8*c] = ((const uint4*)&AB[(size_t)(a0 + r)*32])[c];
    }
    #pragma unroll
    for (int f = tid; f < 512; f += 256) {           // node from NB
        int r = f >> 4, c = f & 15;
        *(uint4*)&sA[r][32 + 8*c] = ((const uint4*)&NB[(size_t)s_na[r]*128])[c];
    }
    if (tid < 256) {                                 // edge_ik from EB
        int r = tid >> 3, c = tid & 7;
        *(uint4*)&sA[r][160 + 8*c] = ((const uint4*)&EB[(size_t)s_ik[r]*64])[c];
    }
    {
        int f = tid;
        if (f < 256) {                               // edge_ij from EB
            int r = f >> 3, c = f & 7;
            *(uint4*)&sA[r][224 + 8*c] = ((const uint4*)&EB[(size_t)s_ij[r]*64])[c];
        }
    }
    __syncthreads();

    const int w = tid >> 6, l = tid & 63;
    const int lr = l & 15, hq = l >> 4, lk = hq * 8;
    const int mrow  = (w & 1) * 16;
    const int nbase = (w >> 1) * 48;

    f32x4 acc[3] = {};
    #pragma unroll
    for (int kk = 0; kk < 9; ++kk) {
        bf16x8 a = *(const bf16x8*)&sA[mrow + lr][kk*32 + lk];
        #pragma unroll
        for (int nf = 0; nf < 3; ++nf) {
            bf16x8 b = *(const bf16x8*)&WTa[(size_t)(nbase + 16*nf + lr)*288 + kk*32 + lk];
            acc[nf] = __builtin_amdgcn_mfma_f32_16x16x32_bf16(a, b, acc[nf], 0, 0, 0);
        }
    }

    #pragma unroll
    for (int nf = 0; nf < 3; ++nf) {
        int c = nbase + 16*nf + lr;
        if (c < 64) {                                // edge_angle -> sEA
            float bb = b1[c];
            #pragma unroll
            for (int j = 0; j < 4; ++j) {
                int r = mrow + 4*hq + j;
                sEA[r][c] = f2bu(silu_(acc[nf][j] + bb) * s_asw[r]);
            }
        } else {                                     // angle_self -> a_out
            int c2 = c - 64;
            float bb = bA[c2], rr = a_res0[c2];
            #pragma unroll
            for (int j = 0; j < 4; ++j) {
                int r = mrow + 4*hq + j;
                size_t idx = (size_t)(a0 + r)*32 + c2;
                a_out[idx] = bu2f(sA[r][c2]) + rr * silu_(acc[nf][j] + bb);
            }
        }
    }
    __syncthreads();

    if (tid < 256) {                                 // coalesced rank-scatter
        int r = tid >> 3, c = tid & 7;
        *(uint4*)&ea[(size_t)s_rk[r]*64 + 8*c] = *(const uint4*)&sEA[r][8*c];
    }
}

// ---------------------------------------------------------------------------
// e_out assembly (single writer): EB base + er0*eself(gathered via rank_e)
// + er1*silu(sum(ea segment) @ W2 + b2).
// ---------------------------------------------------------------------------
__global__ __launch_bounds__(256) void k_edgefin_mfma(
    const u16* __restrict__ EB, const u16* __restrict__ eselfB,
    const int* __restrict__ rank_e,
    const u16* __restrict__ ea, const int* __restrict__ off2,
    const u16* __restrict__ WT2,
    const float* __restrict__ b2_, const float* __restrict__ er0,
    const float* __restrict__ er1,
    float* __restrict__ e_out)
{
    __shared__ __align__(16) u16 sR[64][72];
    __shared__ __align__(16) u16 sE[64][72];
    __shared__ __align__(16) u16 sB[64][72];
    __shared__ int s_rk[64];
    const int tid = threadIdx.x;
    const int e0 = blockIdx.x * 64;
    const int w = tid >> 6, l = tid & 63;

    if (tid < 64) s_rk[tid] = rank_e[e0 + tid];
    __syncthreads();

    #pragma unroll
    for (int f = tid; f < 512; f += 256) {
        int r = f >> 3, c = f & 7;
        *(uint4*)&sB[r][8*c] = ((const uint4*)&EB[(size_t)(e0 + r)*64])[c];
        *(uint4*)&sE[r][8*c] = ((const uint4*)&eselfB[(size_t)s_rk[r]*64])[c];
    }

    #pragma unroll
    for (int r16 = 0; r16 < 16; ++r16) {
        int r = w*16 + r16;
        int e = e0 + r;
        float s = 0.f;
        int jb = off2[e], je = off2[e+1];
        for (int j = jb; j < je; ++j)
            s += bu2f(ea[(size_t)j*64 + l]);
        sR[r][l] = f2bu(s);
    }
    __syncthreads();

    const int lr = l & 15, hq = l >> 4, lk = hq * 8;

    f32x4 acc[4] = {};
    #pragma unroll
    for (int kk = 0; kk < 2; ++kk) {
        bf16x8 b = *(const bf16x8*)&WT2[(size_t)(16*w + lr)*64 + kk*32 + lk];
        #pragma unroll
        for (int m = 0; m < 4; ++m) {
            bf16x8 a = *(const bf16x8*)&sR[16*m + lr][kk*32 + lk];
            acc[m] = __builtin_amdgcn_mfma_f32_16x16x32_bf16(a, b, acc[m], 0, 0, 0);
        }
    }
    int c = 16*w + lr;
    float bb = b2_[c], r0 = er0[c], r1 = er1[c];
    #pragma unroll
    for (int m = 0; m < 4; ++m)
        #pragma unroll
        for (int j = 0; j < 4; ++j) {
            int r = 16*m + 4*hq + j;
            size_t idx = (size_t)(e0 + r)*64 + c;
            e_out[idx] = bu2f(sB[r][c]) + r0 * bu2f(sE[r][c])
                       + r1 * silu_(acc[m][j] + bb);
        }
}

// ---------------------------------------------------------------------------
// symc (bf16) from h2g2.
// ---------------------------------------------------------------------------
__global__ void k_symc(const float* __restrict__ h2g2_e,
                       const float* __restrict__ h2g2_n,
                       u16* __restrict__ symcB)
{
    __shared__ float he[192];
    __shared__ float hn[384];
    int n = blockIdx.x;
    int t = threadIdx.x;   // 128
    for (int i = t; i < 192; i += 128) he[i] = h2g2_e[(size_t)n*192 + i];
    for (int i = t; i < 384; i += 128) hn[i] = h2g2_n[(size_t)n*384 + i];
    __syncthreads();
    const float SCALE = 1.0f / (6.4f * 3.0f);
    for (int i = t; i < 768; i += 128) {
        float s;
        if (i < 256) {
            int a = i >> 6, j = i & 63;
            s = he[a]*he[j] + he[64+a]*he[64+j] + he[128+a]*he[128+j];
        } else {
            int i2 = i - 256;
            int a = i2 >> 7, j = i2 & 127;
            s = hn[a]*hn[j] + hn[128+a]*hn[128+j] + hn[256+a]*hn[256+j];
        }
        symcB[(size_t)n*768 + i] = f2bu(s * SCALE);
    }
}

// ---------------------------------------------------------------------------
// Node finalize via MFMA: sym GEMM (K=768) + self GEMM (K=128), 32-node tiles.
// ---------------------------------------------------------------------------
__global__ __launch_bounds__(256) void k_node_mfma(
    const u16* __restrict__ symcB, const u16* __restrict__ NB,
    const float* __restrict__ node_ext, const float* __restrict__ msg,
    const u16* __restrict__ WsymT, const u16* __restrict__ WnsT,
    const float* __restrict__ bns, const float* __restrict__ bsym,
    const float* __restrict__ nr0, const float* __restrict__ nr1,
    const float* __restrict__ nr2,
    float* __restrict__ n_out)
{
    __shared__ __align__(16) u16 sA[32][264];
    const int tid = threadIdx.x;
    const int n0 = blockIdx.x * 32;
    const int w = tid >> 6, l = tid & 63;
    const int lr = l & 15, hq = l >> 4, lk = hq * 8;

    f32x4 accY[2][2] = {};   // sym
    f32x4 accS[2][2] = {};   // self

    // sym GEMM: K=768 in 3 chunks of 256
    for (int chunk = 0; chunk < 3; ++chunk) {
        __syncthreads();
        #pragma unroll
        for (int f = tid; f < 1024; f += 256) {
            int r = f >> 5, c = f & 31;
            *(uint4*)&sA[r][8*c] =
                ((const uint4*)&symcB[(size_t)(n0 + r)*768 + chunk*256])[c];
        }
        __syncthreads();
        #pragma unroll
        for (int kk = 0; kk < 8; ++kk) {
            bf16x8 a[2], b[2];
            #pragma unroll
            for (int m = 0; m < 2; ++m)
                a[m] = *(const bf16x8*)&sA[16*m + lr][kk*32 + lk];
            #pragma unroll
            for (int nf = 0; nf < 2; ++nf)
                b[nf] = *(const bf16x8*)&WsymT[(size_t)(32*w + 16*nf + lr)*768
                                               + chunk*256 + kk*32 + lk];
            #pragma unroll
            for (int m = 0; m < 2; ++m)
                #pragma unroll
                for (int nf = 0; nf < 2; ++nf)
                    accY[m][nf] = __builtin_amdgcn_mfma_f32_16x16x32_bf16(a[m], b[nf], accY[m][nf], 0, 0, 0);
        }
    }

    // self GEMM: K=128
    __syncthreads();
    #pragma unroll
    for (int f = tid; f < 512; f += 256) {
        int r = f >> 4, c = f & 15;
        *(uint4*)&sA[r][8*c] = ((const uint4*)&NB[(size_t)(n0 + r)*128])[c];
    }
    __syncthreads();
    #pragma unroll
    for (int kk = 0; kk < 4; ++kk) {
        bf16x8 a[2], b[2];
        #pragma unroll
        for (int m = 0; m < 2; ++m)
            a[m] = *(const bf16x8*)&sA[16*m + lr][kk*32 + lk];
        #pragma unroll
        for (int nf = 0; nf < 2; ++nf)
            b[nf] = *(const bf16x8*)&WnsT[(size_t)(32*w + 16*nf + lr)*128 + kk*32 + lk];
        #pragma unroll
        for (int m = 0; m < 2; ++m)
            #pragma unroll
            for (int nf = 0; nf < 2; ++nf)
                accS[m][nf] = __builtin_amdgcn_mfma_f32_16x16x32_bf16(a[m], b[nf], accS[m][nf], 0, 0, 0);
    }

    #pragma unroll
    for (int nf = 0; nf < 2; ++nf) {
        int c = 32*w + 16*nf + lr;
        float bS = bns[c], bY = bsym[c];
        float r0 = nr0[c], r1 = nr1[c], r2 = nr2[c];
        #pragma unroll
        for (int m = 0; m < 2; ++m)
            #pragma unroll
            for (int j = 0; j < 4; ++j) {
                int r = 16*m + 4*hq + j;
                size_t idx = (size_t)(n0 + r)*128 + c;
                float self_ = silu_(accS[m][nf][j] + bS);
                float sym_  = silu_(accY[m][nf][j] + bY);
                n_out[idx] = node_ext[idx] + r0*self_ + r1*sym_
                           + r2 * msg[idx] * (1.0f / 6.4f);
            }
    }
}

// ---------------------------------------------------------------------------
extern "C" void kernel_launch(void* const* d_in, const int* in_sizes, int n_in,
                              void* d_out, int out_size, void* d_ws, size_t ws_size,
                              hipStream_t stream)
{
    const float* node_ext  = (const float*)d_in[0];
    const float* edge_ebd  = (const float*)d_in[1];
    const float* h2        = (const float*)d_in[2];
    const float* angle_ebd = (const float*)d_in[3];
    const float* sw        = (const float*)d_in[6];
    const float* a_sw      = (const float*)d_in[9];
    const int*  edge_index  = (const int*)d_in[10];
    const int*  angle_index = (const int*)d_in[11];
    const int* n2e     = edge_index;
    const int* n_ext2e = edge_index + NEDGE_;
    const int* n2a     = angle_index;
    const int* eij2a   = angle_index + NANGLE_;
    const int* eik2a   = angle_index + 2*NANGLE_;

    const float* Wns  = (const float*)d_in[12];
    const float* bns  = (const float*)d_in[13];
    const float* Wsym = (const float*)d_in[14];
    const float* bsym = (const float*)d_in[15];
    const float* Wne  = (const float*)d_in[16];
    const float* bne  = (const float*)d_in[17];
    const float* Wes  = (const float*)d_in[18];
    const float* bes  = (const float*)d_in[19];
    const float* W1   = (const float*)d_in[20];
    const float* b1   = (const float*)d_in[21];
    const float* W2   = (const float*)d_in[22];
    const float* b2_  = (const float*)d_in[23];
    const float* WA   = (const float*)d_in[24];
    const float* bA   = (const float*)d_in[25];
    const float* nr0  = (const float*)d_in[26];
    const float* nr1  = (const float*)d_in[27];
    const float* nr2  = (const float*)d_in[28];
    const float* er0  = (const float*)d_in[29];
    const float* er1  = (const float*)d_in[30];
    const float* ar0  = (const float*)d_in[31];

    // workspace layout (16B-aligned chunks)
    char* wsp = (char*)d_ws;
    u16*   ea      = (u16*)wsp;    wsp += (size_t)NANGLE_ * 64 * 2;
    u16*   EB      = (u16*)wsp;    wsp += (size_t)NEDGE_ * 64 * 2;
    u16*   NB      = (u16*)wsp;    wsp += (size_t)NALL_ * 128 * 2;
    u16*   AB      = (u16*)wsp;    wsp += (size_t)NANGLE_ * 32 * 2;
    u16*   eselfB  = (u16*)wsp;    wsp += (size_t)NEDGE_ * 64 * 2;
    u16*   symcB   = (u16*)wsp;    wsp += (size_t)NLOC_ * 768 * 2;
    // zeroed region: [cnt | cnt2 | msg | h2g2_e | h2g2_n]
    int*   cnt     = (int*)wsp;    wsp += 4096 * 4;
    int*   cnt2    = (int*)wsp;    wsp += (size_t)NEDGE_ * 4;
    float* msg     = (float*)wsp;  wsp += (size_t)NLOC_ * 128 * 4;
    float* h2g2_e  = (float*)wsp;  wsp += (size_t)NLOC_ * 192 * 4;
    float* h2g2_n  = (float*)wsp;  wsp += (size_t)NLOC_ * 384 * 4;
    size_t zero_bytes = 4096*4 + (size_t)NEDGE_*4 + (size_t)NLOC_*128*4
                      + (size_t)NLOC_*192*4 + (size_t)NLOC_*384*4;
    int*   off     = (int*)wsp;    wsp += 4104 * 4;
    int*   cursor  = (int*)wsp;    wsp += 4096 * 4;
    int*   csr     = (int*)wsp;    wsp += (size_t)NEDGE_ * 4;
    int*   rank_e  = (int*)wsp;    wsp += (size_t)NEDGE_ * 4;
    int*   off2    = (int*)wsp;    wsp += ((size_t)NEDGE_ + 16) * 4;
    int*   cursor2 = (int*)wsp;    wsp += (size_t)NEDGE_ * 4;
    int*   bsum    = (int*)wsp;    wsp += 256 * 4;
    int*   boff    = (int*)wsp;    wsp += 256 * 4;
    int*   rank2   = (int*)wsp;    wsp += (size_t)NANGLE_ * 4;
    float* nconst  = (float*)wsp;  wsp += (size_t)NLOC_ * 192 * 4;
    u16*   WTe     = (u16*)wsp;    wsp += 192 * 320 * 2;
    u16*   WTa     = (u16*)wsp;    wsp += 96 * 288 * 2;
    u16*   WT2     = (u16*)wsp;    wsp += 64 * 64 * 2;
    u16*   WsymT   = (u16*)wsp;    wsp += 128 * 768 * 2;
    u16*   WnsT    = (u16*)wsp;    wsp += 128 * 128 * 2;

    hipMemsetAsync(cnt, 0, zero_bytes, stream);

    float* n_out = (float*)d_out;
    float* e_out = n_out + (size_t)NLOC_ * 128;
    float* a_out = e_out + (size_t)NEDGE_ * 64;

    k_prep   <<<608, 768, 0, stream>>>(Wne, Wes, W1, WA, W2, Wsym, Wns,
                                       WTe, WTa, WT2, WsymT, WnsT);
    k_cvt    <<<768, 256, 0, stream>>>(node_ext, NB, NALL_*128/4);
    k_cvt    <<<4096, 256, 0, stream>>>(edge_ebd, EB, NEDGE_*64/4);
    k_cvt    <<<4096, 256, 0, stream>>>(angle_ebd, AB, NANGLE_*32/4);
    k_count  <<<NEDGE_/256, 256, 0, stream>>>(n2e, cnt);
    k_scan   <<<1, 1024, 0, stream>>>(cnt, off, cursor);
    k_fill_both <<<NEDGE_/256, 256, 0, stream>>>(n2e, cursor, csr, rank_e);
    k_count  <<<NANGLE_/256, 256, 0, stream>>>(eij2a, cnt2);
    k_scan2a <<<256, 256, 0, stream>>>(cnt2, bsum);
    k_scan2b <<<1, 256, 0, stream>>>(bsum, boff);
    k_scan2c <<<256, 256, 0, stream>>>(cnt2, boff, off2, cursor2);
    k_fill_rank <<<NANGLE_/256, 256, 0, stream>>>(eij2a, cursor2, rank2);

    k_nconst <<<NLOC_/64, 256, 0, stream>>>(NB, WTe, nconst);
    k_edge_flat <<<NEDGE_/64, 256, 0, stream>>>(NB, EB, h2, sw, n2e, n_ext2e, csr,
                                                WTe, nconst, bne, bes,
                                                msg, h2g2_e, h2g2_n, eselfB);
    k_angle_mfma <<<NANGLE_/32, 256, 0, stream>>>(NB, EB, AB, a_sw,
                                                  n2a, eij2a, eik2a, rank2,
                                                  WTa, b1, bA, ar0, ea, a_out);
    k_edgefin_mfma <<<NEDGE_/64, 256, 0, stream>>>(EB, eselfB, rank_e, ea, off2,
                                                   WT2, b2_, er0, er1, e_out);
    k_symc   <<<NLOC_, 128, 0, stream>>>(h2g2_e, h2g2_n, symcB);
    k_node_mfma <<<NLOC_/32, 256, 0, stream>>>(symcB, NB, node_ext, msg,
                                               WsymT, WnsT, bns, bsym,
                                               nr0, nr1, nr2, n_out);
}

// Round 10
// 423.799 us; speedup vs baseline: 10.0694x; 1.0720x over previous
//
#include <hip/hip_runtime.h>
#include <hip/hip_bf16.h>

#define NLOC_   4096
#define NALL_   6144
#define NEDGE_  262144
#define NANGLE_ 409600

typedef __bf16 bf16x8 __attribute__((ext_vector_type(8)));
typedef float  f32x4  __attribute__((ext_vector_type(4)));
typedef unsigned short u16;

__device__ __forceinline__ float silu_(float x){ return x / (1.0f + __expf(-x)); }

__device__ __forceinline__ u16 f2bu(float f){
    union { float f; unsigned u; } v; v.f = f;
    unsigned r = v.u + 0x7fffu + ((v.u >> 16) & 1u);
    return (u16)(r >> 16);
}
__device__ __forceinline__ float bu2f(u16 b){
    union { unsigned u; float f; } v; v.u = ((unsigned)b) << 16; return v.f;
}
__device__ __forceinline__ void st_bf16x4(u16* dst, float4 v){
    unsigned lo = (unsigned)f2bu(v.x) | ((unsigned)f2bu(v.y) << 16);
    unsigned hi = (unsigned)f2bu(v.z) | ((unsigned)f2bu(v.w) << 16);
    *reinterpret_cast<uint2*>(dst) = make_uint2(lo, hi);
}

// ---------------------------------------------------------------------------
// L1 mega-prep: weight transposes + bf16 tables + CSR counts, block-ranged.
//   [0,812)      weight prep (flat element index)
//   [812,1580)   NB cvt
//   [1580,3628)  EB cvt (grid-stride)
//   [3628,5676)  AB cvt (grid-stride)
//   [5676,6700)  count n2e
//   [6700,8300)  count eij2a
// ---------------------------------------------------------------------------
__global__ __launch_bounds__(256) void k_mega_prep(
    const float* __restrict__ Wne, const float* __restrict__ Wes,
    const float* __restrict__ W1,  const float* __restrict__ WA,
    const float* __restrict__ W2,  const float* __restrict__ Wsym,
    const float* __restrict__ Wns,
    const float* __restrict__ node_ext, const float* __restrict__ edge_ebd,
    const float* __restrict__ angle_ebd,
    const int* __restrict__ n2e, const int* __restrict__ eij2a,
    u16* __restrict__ WTe, u16* __restrict__ WTa, u16* __restrict__ WT2,
    u16* __restrict__ WsymT, u16* __restrict__ WnsT,
    u16* __restrict__ NB, u16* __restrict__ EB, u16* __restrict__ AB,
    int* __restrict__ cnt, int* __restrict__ cnt2)
{
    const int b = blockIdx.x, tid = threadIdx.x;
    if (b < 812) {
        int i = b*256 + tid;
        if (i < 61440) {                       // WTe[192][320]
            int r = i/320, c = i - r*320;
            WTe[i] = f2bu(r < 128 ? Wne[c*128 + r] : Wes[c*64 + (r-128)]);
        } else if (i < 89088) {                // WTa[96][288]
            int j = i - 61440; int r = j/288, c = j - r*288;
            WTa[j] = f2bu(r < 64 ? W1[c*64 + r] : WA[c*32 + (r-64)]);
        } else if (i < 93184) {                // WT2[64][64]
            int j = i - 89088; int r = j >> 6, c = j & 63;
            WT2[j] = f2bu(W2[c*64 + r]);
        } else if (i < 191488) {               // WsymT[128][768]
            int j = i - 93184; int r = j/768, c = j - r*768;
            WsymT[j] = f2bu(Wsym[c*128 + r]);
        } else {                               // WnsT[128][128]
            int j = i - 191488; int r = j >> 7, c = j & 127;
            WnsT[j] = f2bu(Wns[c*128 + r]);
        }
    } else if (b < 1580) {                     // NB: 196608 float4
        int i = (b - 812)*256 + tid;
        float4 v = ((const float4*)node_ext)[i];
        st_bf16x4(&NB[(size_t)i*4], v);
    } else if (b < 3628) {                     // EB: 4194304 float4
        for (int i = (b - 1580)*256 + tid; i < NEDGE_*64/4; i += 2048*256) {
            float4 v = ((const float4*)edge_ebd)[i];
            st_bf16x4(&EB[(size_t)i*4], v);
        }
    } else if (b < 5676) {                     // AB: 3276800 float4
        for (int i = (b - 3628)*256 + tid; i < NANGLE_*32/4; i += 2048*256) {
            float4 v = ((const float4*)angle_ebd)[i];
            st_bf16x4(&AB[(size_t)i*4], v);
        }
    } else if (b < 6700) {                     // count n2e
        int e = (b - 5676)*256 + tid;
        atomicAdd(&cnt[n2e[e]], 1);
    } else {                                   // count eij2a
        int a = (b - 6700)*256 + tid;
        atomicAdd(&cnt2[eij2a[a]], 1);
    }
}

// ---------------------------------------------------------------------------
// L2: block 0 = node scan (4096, 16/thread); blocks 1..256 = scan2a;
// blocks 257..320 = nconst (needs WTe/NB from L1).
// ---------------------------------------------------------------------------
__global__ __launch_bounds__(256) void k_scan_misc(
    const int* __restrict__ cnt, int* __restrict__ off, int* __restrict__ cursor,
    const int* __restrict__ cnt2, int* __restrict__ bsum,
    const u16* __restrict__ NB, const u16* __restrict__ WTe,
    float* __restrict__ nconst)
{
    __shared__ __align__(16) u16 sN[64][136];   // 17.4 KB, aliased by scans
    int* wa = (int*)&sN[0][0];
    const int b = blockIdx.x, t = threadIdx.x;

    if (b == 0) {
        int v[16]; int s = 0;
        #pragma unroll
        for (int k = 0; k < 16; ++k) { v[k] = s; s += cnt[16*t + k]; }
        wa[t] = s;
        __syncthreads();
        for (int d = 1; d < 256; d <<= 1) {
            int x = wa[t];
            int y = (t >= d) ? wa[t-d] : 0;
            __syncthreads();
            wa[t] = x + y;
            __syncthreads();
        }
        int excl = (t == 0) ? 0 : wa[t-1];
        #pragma unroll
        for (int k = 0; k < 16; ++k) {
            off[16*t + k]    = excl + v[k];
            cursor[16*t + k] = excl + v[k];
        }
        if (t == 255) off[4096] = excl + s;
    } else if (b <= 256) {
        int bb = b - 1;
        int4 v = ((const int4*)cnt2)[bb*256 + t];
        wa[t] = v.x + v.y + v.z + v.w;
        __syncthreads();
        for (int d = 128; d > 0; d >>= 1) {
            if (t < d) wa[t] += wa[t+d];
            __syncthreads();
        }
        if (t == 0) bsum[bb] = wa[0];
    } else {
        const int e0 = (b - 257) * 64;
        #pragma unroll
        for (int f = t; f < 1024; f += 256) {
            int r = f >> 4, c = f & 15;
            *(uint4*)&sN[r][8*c] = ((const uint4*)&NB[(size_t)(e0 + r)*128])[c];
        }
        __syncthreads();
        const int w = t >> 6, l = t & 63;
        const int lr = l & 15, hq = l >> 4, lk = hq * 8;
        f32x4 acc[4][3] = {};
        #pragma unroll
        for (int kk = 0; kk < 4; ++kk) {
            bf16x8 a[4], bb[3];
            #pragma unroll
            for (int m = 0; m < 4; ++m)
                a[m] = *(const bf16x8*)&sN[16*m + lr][kk*32 + lk];
            #pragma unroll
            for (int nf = 0; nf < 3; ++nf)
                bb[nf] = *(const bf16x8*)&WTe[(size_t)(48*w + 16*nf + lr)*320 + kk*32 + lk];
            #pragma unroll
            for (int m = 0; m < 4; ++m)
                #pragma unroll
                for (int nf = 0; nf < 3; ++nf)
                    acc[m][nf] = __builtin_amdgcn_mfma_f32_16x16x32_bf16(a[m], bb[nf], acc[m][nf], 0, 0, 0);
        }
        #pragma unroll
        for (int nf = 0; nf < 3; ++nf) {
            int c = 48*w + 16*nf + lr;
            #pragma unroll
            for (int m = 0; m < 4; ++m)
                #pragma unroll
                for (int j = 0; j < 4; ++j) {
                    int r = 16*m + 4*hq + j;
                    nconst[(size_t)(e0 + r)*192 + c] = acc[m][nf][j];
                }
        }
    }
}

__global__ void k_scan2b(const int* __restrict__ bsum, int* __restrict__ boff)
{
    __shared__ int wa[256];
    int t = threadIdx.x;
    wa[t] = bsum[t];
    __syncthreads();
    for (int d = 1; d < 256; d <<= 1) {
        int x = wa[t];
        int y = (t >= d) ? wa[t-d] : 0;
        __syncthreads();
        wa[t] = x + y;
        __syncthreads();
    }
    boff[t] = (t == 0) ? 0 : wa[t-1];
}

__global__ void k_scan2c(const int* __restrict__ cnt2, const int* __restrict__ boff,
                         int* __restrict__ off2, int* __restrict__ cursor2)
{
    __shared__ int wa[256];
    int b = blockIdx.x, t = threadIdx.x;
    int4 v = ((const int4*)cnt2)[b*256 + t];
    int s1 = v.x, s2 = s1 + v.y, s3 = s2 + v.z, s4 = s3 + v.w;
    wa[t] = s4;
    __syncthreads();
    for (int d = 1; d < 256; d <<= 1) {
        int x = wa[t];
        int y = (t >= d) ? wa[t-d] : 0;
        __syncthreads();
        wa[t] = x + y;
        __syncthreads();
    }
    int base = boff[b] + ((t == 0) ? 0 : wa[t-1]);
    int i = (b*256 + t)*4;
    off2[i]   = base;      cursor2[i]   = base;
    off2[i+1] = base + s1; cursor2[i+1] = base + s1;
    off2[i+2] = base + s2; cursor2[i+2] = base + s2;
    off2[i+3] = base + s3; cursor2[i+3] = base + s3;
    if (b == 255 && t == 255) off2[NEDGE_] = NANGLE_;
}

// L5: fused fills. [0,1024) edge csr; [1024,2624) angle rank.
__global__ void k_fill2(const int* __restrict__ n2e, int* __restrict__ cursor,
                        int* __restrict__ csr,
                        const int* __restrict__ eij2a, int* __restrict__ cursor2,
                        int* __restrict__ rank2)
{
    int b = blockIdx.x;
    if (b < 1024) {
        int e = b*256 + threadIdx.x;
        int pos = atomicAdd(&cursor[n2e[e]], 1);
        csr[pos] = e;
    } else {
        int a = (b - 1024)*256 + threadIdx.x;
        int pos = atomicAdd(&cursor2[eij2a[a]], 1);
        rank2[a] = pos;
    }
}

// ---------------------------------------------------------------------------
// Flat edge GEMM over CSR-ordered tiles + fused segmented h2g2.
// eself written in ORIGINAL edge order (scatter by s_eid) -> edgefin reads seq.
// ---------------------------------------------------------------------------
__global__ __launch_bounds__(256, 4) void k_edge_flat(
    const u16* __restrict__ NB, const u16* __restrict__ EB,
    const float* __restrict__ h2, const float* __restrict__ sw,
    const int* __restrict__ n2e, const int* __restrict__ n_ext2e,
    const int* __restrict__ csr,
    const u16* __restrict__ WTe, const float* __restrict__ nconst,
    const float* __restrict__ bne, const float* __restrict__ bes,
    float* __restrict__ msg,
    float* __restrict__ h2g2_e, float* __restrict__ h2g2_n,
    u16* __restrict__ eselfO)
{
    __shared__ __align__(16) u16 sA[64][200];
    __shared__ float sH[4][576];
    __shared__ int   s_eid[64];
    __shared__ int   s_node[64];
    __shared__ int   s_g[64];
    __shared__ float s_sw[64];
    __shared__ float s_h2[64][3];
    __shared__ int   s_segstart[65];
    __shared__ int   s_nseg;

    const int tid = threadIdx.x;
    const int w  = tid >> 6, l = tid & 63;
    const int lr = l & 15, hq = l >> 4, lk = hq * 8;
    const int base = blockIdx.x * 64;

    if (tid < 64) {
        int e = csr[base + tid];
        s_eid[tid]  = e;
        s_node[tid] = n2e[e];
        s_g[tid]    = n_ext2e[e];
        s_sw[tid]   = sw[e];
        s_h2[tid][0] = h2[e*3];
        s_h2[tid][1] = h2[e*3+1];
        s_h2[tid][2] = h2[e*3+2];
    }
    __syncthreads();

    if (tid < 64) {
        bool flag = (tid == 0) || (s_node[tid] != s_node[tid-1]);
        unsigned long long mask = __ballot(flag);
        if (flag) {
            int sid = __popcll(mask & ((1ull << tid) - 1ull));
            s_segstart[sid] = tid;
        }
        if (tid == 0) {
            int ns = __popcll(mask);
            s_nseg = ns;
            s_segstart[ns] = 64;
        }
    }

    #pragma unroll
    for (int f = tid; f < 1024; f += 256) {
        int r = f >> 4, c = f & 15;
        *(uint4*)&sA[r][8*c] = ((const uint4*)&NB[(size_t)s_g[r]*128])[c];
    }
    #pragma unroll
    for (int f = tid; f < 512; f += 256) {
        int r = f >> 3, c = f & 7;
        *(uint4*)&sA[r][128 + 8*c] = ((const uint4*)&EB[(size_t)s_eid[r]*64])[c];
    }
    __syncthreads();

    float bias[3];
    int   cful[3];
    #pragma unroll
    for (int nf = 0; nf < 3; ++nf) {
        int c = 48*w + 16*nf + lr;
        cful[nf] = c;
        bias[nf] = (c < 128) ? bne[c] : bes[c-128];
    }

    f32x4 acc[4][3] = {};
    #pragma unroll
    for (int kk = 0; kk < 6; ++kk) {
        bf16x8 a[4], b[3];
        #pragma unroll
        for (int m = 0; m < 4; ++m)
            a[m] = *(const bf16x8*)&sA[16*m + lr][kk*32 + lk];
        #pragma unroll
        for (int nf = 0; nf < 3; ++nf)
            b[nf] = *(const bf16x8*)&WTe[(size_t)cful[nf]*320 + 128 + kk*32 + lk];
        #pragma unroll
        for (int m = 0; m < 4; ++m)
            #pragma unroll
            for (int nf = 0; nf < 3; ++nf)
                acc[m][nf] = __builtin_amdgcn_mfma_f32_16x16x32_bf16(a[m], b[nf], acc[m][nf], 0, 0, 0);
    }

    #pragma unroll
    for (int nf = 0; nf < 3; ++nf) {
        int c = cful[nf];
        if (c < 128) {
            #pragma unroll
            for (int m = 0; m < 4; ++m)
                #pragma unroll
                for (int j = 0; j < 4; ++j) {
                    int r = 16*m + 4*hq + j;
                    float ncv = nconst[(size_t)s_node[r]*192 + c];
                    acc[m][nf][j] = silu_(acc[m][nf][j] + ncv + bias[nf]) * s_sw[r];
                }
        } else {
            int c2 = c - 128;
            #pragma unroll
            for (int m = 0; m < 4; ++m)
                #pragma unroll
                for (int j = 0; j < 4; ++j) {
                    int r = 16*m + 4*hq + j;
                    float ncv = nconst[(size_t)s_node[r]*192 + c];
                    eselfO[(size_t)s_eid[r]*64 + c2] =
                        f2bu(silu_(acc[m][nf][j] + ncv + bias[nf]));
                }
        }
    }

    // ---- segmented msg reduction ----
    const int nseg = s_nseg;
    for (int s = 0; s < nseg; ++s) {
        int rs = s_segstart[s], re = s_segstart[s+1];
        int nd = s_node[rs];
        #pragma unroll
        for (int nf = 0; nf < 3; ++nf) {
            if (cful[nf] >= 128) continue;
            float v = 0.f;
            #pragma unroll
            for (int m = 0; m < 4; ++m)
                #pragma unroll
                for (int j = 0; j < 4; ++j) {
                    int r = 16*m + 4*hq + j;
                    v += (r >= rs && r < re) ? acc[m][nf][j] : 0.f;
                }
            v += __shfl_xor(v, 16);
            v += __shfl_xor(v, 32);
            if (hq == 0) atomicAdd(&msg[(size_t)nd*128 + cful[nf]], v);
        }
    }

    // ---- segmented h2g2 accumulation ----
    for (int s = 0; s < nseg; ++s) {
        int rs = s_segstart[s], re = s_segstart[s+1];
        int nd = s_node[rs];
        int lo = max(16*w, rs), hi = min(16*w + 16, re);
        float hacc[9] = {0.f,0.f,0.f,0.f,0.f,0.f,0.f,0.f,0.f};
        for (int r = lo; r < hi; ++r) {
            float swv = s_sw[r];
            float s0 = s_h2[r][0] * swv;
            float s1 = s_h2[r][1] * swv;
            float s2 = s_h2[r][2] * swv;
            float eb = bu2f(sA[r][128 + l]);
            float n0 = bu2f(sA[r][l]);
            float n1 = bu2f(sA[r][64 + l]);
            hacc[0] = fmaf(s0, eb, hacc[0]);
            hacc[1] = fmaf(s1, eb, hacc[1]);
            hacc[2] = fmaf(s2, eb, hacc[2]);
            hacc[3] = fmaf(s0, n0, hacc[3]);
            hacc[4] = fmaf(s0, n1, hacc[4]);
            hacc[5] = fmaf(s1, n0, hacc[5]);
            hacc[6] = fmaf(s1, n1, hacc[6]);
            hacc[7] = fmaf(s2, n0, hacc[7]);
            hacc[8] = fmaf(s2, n1, hacc[8]);
        }
        #pragma unroll
        for (int q = 0; q < 3; ++q) sH[w][q*64 + l] = hacc[q];
        #pragma unroll
        for (int q = 0; q < 6; ++q) sH[w][192 + q*64 + l] = hacc[3+q];
        __syncthreads();
        for (int i = tid; i < 576; i += 256) {
            float v = sH[0][i] + sH[1][i] + sH[2][i] + sH[3][i];
            if (i < 192) atomicAdd(&h2g2_e[(size_t)nd*192 + i], v);
            else         atomicAdd(&h2g2_n[(size_t)nd*384 + (i - 192)], v);
        }
        __syncthreads();
    }
}

// ---------------------------------------------------------------------------
// Angle GEMM via MFMA, M-tile 32, rank-permuted coalesced ea scatter.
// ---------------------------------------------------------------------------
__global__ __launch_bounds__(256) void k_angle_mfma(
    const u16* __restrict__ NB, const u16* __restrict__ EB,
    const u16* __restrict__ AB, const float* __restrict__ a_sw,
    const int* __restrict__ n2a, const int* __restrict__ eij2a,
    const int* __restrict__ eik2a, const int* __restrict__ rank2,
    const u16* __restrict__ WTa,
    const float* __restrict__ b1, const float* __restrict__ bA,
    const float* __restrict__ a_res0,
    u16* __restrict__ ea, float* __restrict__ a_out)
{
    __shared__ __align__(16) u16 sA[32][296];
    __shared__ __align__(16) u16 sEA[32][64];
    __shared__ int s_na[32], s_ij[32], s_ik[32], s_rk[32];
    __shared__ float s_asw[32];
    const int tid = threadIdx.x;
    const int a0 = blockIdx.x * 32;

    if (tid < 32) {
        s_na[tid] = n2a[a0 + tid];
        s_ij[tid] = eij2a[a0 + tid];
        s_ik[tid] = eik2a[a0 + tid];
        s_rk[tid] = rank2[a0 + tid];
        s_asw[tid] = a_sw[a0 + tid];
    }
    __syncthreads();

    if (tid < 128) {
        int r = tid >> 2, c = tid & 3;
        *(uint4*)&sA[r][8*c] = ((const uint4*)&AB[(size_t)(a0 + r)*32])[c];
    }
    #pragma unroll
    for (int f = tid; f < 512; f += 256) {
        int r = f >> 4, c = f & 15;
        *(uint4*)&sA[r][32 + 8*c] = ((const uint4*)&NB[(size_t)s_na[r]*128])[c];
    }
    {
        int r = tid >> 3, c = tid & 7;
        *(uint4*)&sA[r][160 + 8*c] = ((const uint4*)&EB[(size_t)s_ik[r]*64])[c];
        *(uint4*)&sA[r][224 + 8*c] = ((const uint4*)&EB[(size_t)s_ij[r]*64])[c];
    }
    __syncthreads();

    const int w = tid >> 6, l = tid & 63;
    const int lr = l & 15, hq = l >> 4, lk = hq * 8;
    const int mrow  = (w & 1) * 16;
    const int nbase = (w >> 1) * 48;

    f32x4 acc[3] = {};
    #pragma unroll
    for (int kk = 0; kk < 9; ++kk) {
        bf16x8 a = *(const bf16x8*)&sA[mrow + lr][kk*32 + lk];
        #pragma unroll
        for (int nf = 0; nf < 3; ++nf) {
            bf16x8 b = *(const bf16x8*)&WTa[(size_t)(nbase + 16*nf + lr)*288 + kk*32 + lk];
            acc[nf] = __builtin_amdgcn_mfma_f32_16x16x32_bf16(a, b, acc[nf], 0, 0, 0);
        }
    }

    #pragma unroll
    for (int nf = 0; nf < 3; ++nf) {
        int c = nbase + 16*nf + lr;
        if (c < 64) {
            float bb = b1[c];
            #pragma unroll
            for (int j = 0; j < 4; ++j) {
                int r = mrow + 4*hq + j;
                sEA[r][c] = f2bu(silu_(acc[nf][j] + bb) * s_asw[r]);
            }
        } else {
            int c2 = c - 64;
            float bb = bA[c2], rr = a_res0[c2];
            #pragma unroll
            for (int j = 0; j < 4; ++j) {
                int r = mrow + 4*hq + j;
                size_t idx = (size_t)(a0 + r)*32 + c2;
                a_out[idx] = bu2f(sA[r][c2]) + rr * silu_(acc[nf][j] + bb);
            }
        }
    }
    __syncthreads();

    {
        int r = tid >> 3, c = tid & 7;
        *(uint4*)&ea[(size_t)s_rk[r]*64 + 8*c] = *(const uint4*)&sEA[r][8*c];
    }
}

// ---------------------------------------------------------------------------
// L8 fused: [0,4096) edgefin (all reads sequential now); [4096,8192) symc.
// ---------------------------------------------------------------------------
__global__ __launch_bounds__(256) void k_fin(
    const u16* __restrict__ EB, const u16* __restrict__ eselfO,
    const u16* __restrict__ ea, const int* __restrict__ off2,
    const u16* __restrict__ WT2,
    const float* __restrict__ b2_, const float* __restrict__ er0,
    const float* __restrict__ er1,
    float* __restrict__ e_out,
    const float* __restrict__ h2g2_e, const float* __restrict__ h2g2_n,
    u16* __restrict__ symcB)
{
    __shared__ __align__(16) u16 sR[64][72];
    __shared__ __align__(16) u16 sE[64][72];
    __shared__ __align__(16) u16 sB[64][72];
    const int tid = threadIdx.x;
    const int blk = blockIdx.x;

    if (blk < 4096) {
        const int e0 = blk * 64;
        const int w = tid >> 6, l = tid & 63;

        #pragma unroll
        for (int f = tid; f < 512; f += 256) {
            int r = f >> 3, c = f & 7;
            *(uint4*)&sB[r][8*c] = ((const uint4*)&EB[(size_t)(e0 + r)*64])[c];
            *(uint4*)&sE[r][8*c] = ((const uint4*)&eselfO[(size_t)(e0 + r)*64])[c];
        }

        #pragma unroll
        for (int r16 = 0; r16 < 16; ++r16) {
            int r = w*16 + r16;
            int e = e0 + r;
            float s = 0.f;
            int jb = off2[e], je = off2[e+1];
            for (int j = jb; j < je; ++j)
                s += bu2f(ea[(size_t)j*64 + l]);
            sR[r][l] = f2bu(s);
        }
        __syncthreads();

        const int lr = l & 15, hq = l >> 4, lk = hq * 8;
        f32x4 acc[4] = {};
        #pragma unroll
        for (int kk = 0; kk < 2; ++kk) {
            bf16x8 b = *(const bf16x8*)&WT2[(size_t)(16*w + lr)*64 + kk*32 + lk];
            #pragma unroll
            for (int m = 0; m < 4; ++m) {
                bf16x8 a = *(const bf16x8*)&sR[16*m + lr][kk*32 + lk];
                acc[m] = __builtin_amdgcn_mfma_f32_16x16x32_bf16(a, b, acc[m], 0, 0, 0);
            }
        }
        int c = 16*w + lr;
        float bb = b2_[c], r0 = er0[c], r1 = er1[c];
        #pragma unroll
        for (int m = 0; m < 4; ++m)
            #pragma unroll
            for (int j = 0; j < 4; ++j) {
                int r = 16*m + 4*hq + j;
                size_t idx = (size_t)(e0 + r)*64 + c;
                e_out[idx] = bu2f(sB[r][c]) + r0 * bu2f(sE[r][c])
                           + r1 * silu_(acc[m][j] + bb);
            }
    } else {
        const int n = blk - 4096;
        float* he = (float*)&sR[0][0];     // 192 f32
        float* hn = he + 192;              // 384 f32 (fits in sR+sE)
        for (int i = tid; i < 192; i += 256) he[i] = h2g2_e[(size_t)n*192 + i];
        for (int i = tid; i < 384; i += 256) hn[i] = h2g2_n[(size_t)n*384 + i];
        __syncthreads();
        const float SCALE = 1.0f / (6.4f * 3.0f);
        for (int i = tid; i < 768; i += 256) {
            float s;
            if (i < 256) {
                int a = i >> 6, j = i & 63;
                s = he[a]*he[j] + he[64+a]*he[64+j] + he[128+a]*he[128+j];
            } else {
                int i2 = i - 256;
                int a = i2 >> 7, j = i2 & 127;
                s = hn[a]*hn[j] + hn[128+a]*hn[128+j] + hn[256+a]*hn[256+j];
            }
            symcB[(size_t)n*768 + i] = f2bu(s * SCALE);
        }
    }
}

// ---------------------------------------------------------------------------
// Node finalize via MFMA (unchanged).
// ---------------------------------------------------------------------------
__global__ __launch_bounds__(256) void k_node_mfma(
    const u16* __restrict__ symcB, const u16* __restrict__ NB,
    const float* __restrict__ node_ext, const float* __restrict__ msg,
    const u16* __restrict__ WsymT, const u16* __restrict__ WnsT,
    const float* __restrict__ bns, const float* __restrict__ bsym,
    const float* __restrict__ nr0, const float* __restrict__ nr1,
    const float* __restrict__ nr2,
    float* __restrict__ n_out)
{
    __shared__ __align__(16) u16 sA[32][264];
    const int tid = threadIdx.x;
    const int n0 = blockIdx.x * 32;
    const int w = tid >> 6, l = tid & 63;
    const int lr = l & 15, hq = l >> 4, lk = hq * 8;

    f32x4 accY[2][2] = {};
    f32x4 accS[2][2] = {};

    for (int chunk = 0; chunk < 3; ++chunk) {
        __syncthreads();
        #pragma unroll
        for (int f = tid; f < 1024; f += 256) {
            int r = f >> 5, c = f & 31;
            *(uint4*)&sA[r][8*c] =
                ((const uint4*)&symcB[(size_t)(n0 + r)*768 + chunk*256])[c];
        }
        __syncthreads();
        #pragma unroll
        for (int kk = 0; kk < 8; ++kk) {
            bf16x8 a[2], b[2];
            #pragma unroll
            for (int m = 0; m < 2; ++m)
                a[m] = *(const bf16x8*)&sA[16*m + lr][kk*32 + lk];
            #pragma unroll
            for (int nf = 0; nf < 2; ++nf)
                b[nf] = *(const bf16x8*)&WsymT[(size_t)(32*w + 16*nf + lr)*768
                                               + chunk*256 + kk*32 + lk];
            #pragma unroll
            for (int m = 0; m < 2; ++m)
                #pragma unroll
                for (int nf = 0; nf < 2; ++nf)
                    accY[m][nf] = __builtin_amdgcn_mfma_f32_16x16x32_bf16(a[m], b[nf], accY[m][nf], 0, 0, 0);
        }
    }

    __syncthreads();
    #pragma unroll
    for (int f = tid; f < 512; f += 256) {
        int r = f >> 4, c = f & 15;
        *(uint4*)&sA[r][8*c] = ((const uint4*)&NB[(size_t)(n0 + r)*128])[c];
    }
    __syncthreads();
    #pragma unroll
    for (int kk = 0; kk < 4; ++kk) {
        bf16x8 a[2], b[2];
        #pragma unroll
        for (int m = 0; m < 2; ++m)
            a[m] = *(const bf16x8*)&sA[16*m + lr][kk*32 + lk];
        #pragma unroll
        for (int nf = 0; nf < 2; ++nf)
            b[nf] = *(const bf16x8*)&WnsT[(size_t)(32*w + 16*nf + lr)*128 + kk*32 + lk];
        #pragma unroll
        for (int m = 0; m < 2; ++m)
            #pragma unroll
            for (int nf = 0; nf < 2; ++nf)
                accS[m][nf] = __builtin_amdgcn_mfma_f32_16x16x32_bf16(a[m], b[nf], accS[m][nf], 0, 0, 0);
    }

    #pragma unroll
    for (int nf = 0; nf < 2; ++nf) {
        int c = 32*w + 16*nf + lr;
        float bS = bns[c], bY = bsym[c];
        float r0 = nr0[c], r1 = nr1[c], r2 = nr2[c];
        #pragma unroll
        for (int m = 0; m < 2; ++m)
            #pragma unroll
            for (int j = 0; j < 4; ++j) {
                int r = 16*m + 4*hq + j;
                size_t idx = (size_t)(n0 + r)*128 + c;
                float self_ = silu_(accS[m][nf][j] + bS);
                float sym_  = silu_(accY[m][nf][j] + bY);
                n_out[idx] = node_ext[idx] + r0*self_ + r1*sym_
                           + r2 * msg[idx] * (1.0f / 6.4f);
            }
    }
}

// ---------------------------------------------------------------------------
extern "C" void kernel_launch(void* const* d_in, const int* in_sizes, int n_in,
                              void* d_out, int out_size, void* d_ws, size_t ws_size,
                              hipStream_t stream)
{
    const float* node_ext  = (const float*)d_in[0];
    const float* edge_ebd  = (const float*)d_in[1];
    const float* h2        = (const float*)d_in[2];
    const float* angle_ebd = (const float*)d_in[3];
    const float* sw        = (const float*)d_in[6];
    const float* a_sw      = (const float*)d_in[9];
    const int*  edge_index  = (const int*)d_in[10];
    const int*  angle_index = (const int*)d_in[11];
    const int* n2e     = edge_index;
    const int* n_ext2e = edge_index + NEDGE_;
    const int* n2a     = angle_index;
    const int* eij2a   = angle_index + NANGLE_;
    const int* eik2a   = angle_index + 2*NANGLE_;

    const float* Wns  = (const float*)d_in[12];
    const float* bns  = (const float*)d_in[13];
    const float* Wsym = (const float*)d_in[14];
    const float* bsym = (const float*)d_in[15];
    const float* Wne  = (const float*)d_in[16];
    const float* bne  = (const float*)d_in[17];
    const float* Wes  = (const float*)d_in[18];
    const float* bes  = (const float*)d_in[19];
    const float* W1   = (const float*)d_in[20];
    const float* b1   = (const float*)d_in[21];
    const float* W2   = (const float*)d_in[22];
    const float* b2_  = (const float*)d_in[23];
    const float* WA   = (const float*)d_in[24];
    const float* bA   = (const float*)d_in[25];
    const float* nr0  = (const float*)d_in[26];
    const float* nr1  = (const float*)d_in[27];
    const float* nr2  = (const float*)d_in[28];
    const float* er0  = (const float*)d_in[29];
    const float* er1  = (const float*)d_in[30];
    const float* ar0  = (const float*)d_in[31];

    // workspace layout
    char* wsp = (char*)d_ws;
    u16*   ea      = (u16*)wsp;    wsp += (size_t)NANGLE_ * 64 * 2;
    u16*   EB      = (u16*)wsp;    wsp += (size_t)NEDGE_ * 64 * 2;
    u16*   NB      = (u16*)wsp;    wsp += (size_t)NALL_ * 128 * 2;
    u16*   AB      = (u16*)wsp;    wsp += (size_t)NANGLE_ * 32 * 2;
    u16*   eselfO  = (u16*)wsp;    wsp += (size_t)NEDGE_ * 64 * 2;
    u16*   symcB   = (u16*)wsp;    wsp += (size_t)NLOC_ * 768 * 2;
    // zeroed region: [cnt | cnt2 | msg | h2g2_e | h2g2_n]
    int*   cnt     = (int*)wsp;    wsp += 4096 * 4;
    int*   cnt2    = (int*)wsp;    wsp += (size_t)NEDGE_ * 4;
    float* msg     = (float*)wsp;  wsp += (size_t)NLOC_ * 128 * 4;
    float* h2g2_e  = (float*)wsp;  wsp += (size_t)NLOC_ * 192 * 4;
    float* h2g2_n  = (float*)wsp;  wsp += (size_t)NLOC_ * 384 * 4;
    size_t zero_bytes = 4096*4 + (size_t)NEDGE_*4 + (size_t)NLOC_*128*4
                      + (size_t)NLOC_*192*4 + (size_t)NLOC_*384*4;
    int*   off     = (int*)wsp;    wsp += 4104 * 4;
    int*   cursor  = (int*)wsp;    wsp += 4096 * 4;
    int*   csr     = (int*)wsp;    wsp += (size_t)NEDGE_ * 4;
    int*   off2    = (int*)wsp;    wsp += ((size_t)NEDGE_ + 16) * 4;
    int*   cursor2 = (int*)wsp;    wsp += (size_t)NEDGE_ * 4;
    int*   bsum    = (int*)wsp;    wsp += 256 * 4;
    int*   boff    = (int*)wsp;    wsp += 256 * 4;
    int*   rank2   = (int*)wsp;    wsp += (size_t)NANGLE_ * 4;
    float* nconst  = (float*)wsp;  wsp += (size_t)NLOC_ * 192 * 4;
    u16*   WTe     = (u16*)wsp;    wsp += 192 * 320 * 2;
    u16*   WTa     = (u16*)wsp;    wsp += 96 * 288 * 2;
    u16*   WT2     = (u16*)wsp;    wsp += 64 * 64 * 2;
    u16*   WsymT   = (u16*)wsp;    wsp += 128 * 768 * 2;
    u16*   WnsT    = (u16*)wsp;    wsp += 128 * 128 * 2;

    hipMemsetAsync(cnt, 0, zero_bytes, stream);

    float* n_out = (float*)d_out;
    float* e_out = n_out + (size_t)NLOC_ * 128;
    float* a_out = e_out + (size_t)NEDGE_ * 64;

    k_mega_prep <<<8300, 256, 0, stream>>>(Wne, Wes, W1, WA, W2, Wsym, Wns,
                                           node_ext, edge_ebd, angle_ebd,
                                           n2e, eij2a,
                                           WTe, WTa, WT2, WsymT, WnsT,
                                           NB, EB, AB, cnt, cnt2);
    k_scan_misc <<<321, 256, 0, stream>>>(cnt, off, cursor, cnt2, bsum,
                                          NB, WTe, nconst);
    k_scan2b <<<1, 256, 0, stream>>>(bsum, boff);
    k_scan2c <<<256, 256, 0, stream>>>(cnt2, boff, off2, cursor2);
    k_fill2  <<<2624, 256, 0, stream>>>(n2e, cursor, csr, eij2a, cursor2, rank2);

    k_edge_flat <<<NEDGE_/64, 256, 0, stream>>>(NB, EB, h2, sw, n2e, n_ext2e, csr,
                                                WTe, nconst, bne, bes,
                                                msg, h2g2_e, h2g2_n, eselfO);
    k_angle_mfma <<<NANGLE_/32, 256, 0, stream>>>(NB, EB, AB, a_sw,
                                                  n2a, eij2a, eik2a, rank2,
                                                  WTa, b1, bA, ar0, ea, a_out);
    k_fin <<<8192, 256, 0, stream>>>(EB, eselfO, ea, off2, WT2, b2_, er0, er1,
                                     e_out, h2g2_e, h2g2_n, symcB);
    k_node_mfma <<<NLOC_/32, 256, 0, stream>>>(symcB, NB, node_ext, msg,
                                               WsymT, WnsT, bns, bsym,
                                               nr0, nr1, nr2, n_out);
}

// Round 11
// 422.582 us; speedup vs baseline: 10.0983x; 1.0029x over previous
//
#include <hip/hip_runtime.h>
#include <hip/hip_bf16.h>

#define NLOC_   4096
#define NALL_   6144
#define NEDGE_  262144
#define NANGLE_ 409600

typedef __bf16 bf16x8 __attribute__((ext_vector_type(8)));
typedef float  f32x4  __attribute__((ext_vector_type(4)));
typedef unsigned short u16;

__device__ __forceinline__ float silu_(float x){ return x / (1.0f + __expf(-x)); }

__device__ __forceinline__ u16 f2bu(float f){
    union { float f; unsigned u; } v; v.f = f;
    unsigned r = v.u + 0x7fffu + ((v.u >> 16) & 1u);
    return (u16)(r >> 16);
}
__device__ __forceinline__ float bu2f(u16 b){
    union { unsigned u; float f; } v; v.u = ((unsigned)b) << 16; return v.f;
}
__device__ __forceinline__ void st_bf16x4(u16* dst, float4 v){
    unsigned lo = (unsigned)f2bu(v.x) | ((unsigned)f2bu(v.y) << 16);
    unsigned hi = (unsigned)f2bu(v.z) | ((unsigned)f2bu(v.w) << 16);
    *reinterpret_cast<uint2*>(dst) = make_uint2(lo, hi);
}

// ---------------------------------------------------------------------------
// L1 mega-prep: weight transposes + bf16 tables + CSR counts, block-ranged.
// Weight element ranges (flat i over 207872 elements):
//   [0,61440)        WTe[192][320]
//   [61440,76800)    WTa2[96][160]  (K repacked: angle | eik | eij)
//   [76800,89088)    WTaN[96][128]  (node K-slice, rows 32..160)
//   [89088,93184)    WT2[64][64]
//   [93184,191488)   WsymT[128][768]
//   [191488,207872)  WnsT[128][128]
// ---------------------------------------------------------------------------
__global__ __launch_bounds__(256) void k_mega_prep(
    const float* __restrict__ Wne, const float* __restrict__ Wes,
    const float* __restrict__ W1,  const float* __restrict__ WA,
    const float* __restrict__ W2,  const float* __restrict__ Wsym,
    const float* __restrict__ Wns,
    const float* __restrict__ node_ext, const float* __restrict__ edge_ebd,
    const float* __restrict__ angle_ebd,
    const int* __restrict__ n2e, const int* __restrict__ eij2a,
    u16* __restrict__ WTe, u16* __restrict__ WTa2, u16* __restrict__ WTaN,
    u16* __restrict__ WT2, u16* __restrict__ WsymT, u16* __restrict__ WnsT,
    u16* __restrict__ NB, u16* __restrict__ EB, u16* __restrict__ AB,
    int* __restrict__ cnt, int* __restrict__ cnt2)
{
    const int b = blockIdx.x, tid = threadIdx.x;
    if (b < 812) {
        int i = b*256 + tid;
        if (i < 61440) {                       // WTe[192][320]
            int r = i/320, c = i - r*320;
            WTe[i] = f2bu(r < 128 ? Wne[c*128 + r] : Wes[c*64 + (r-128)]);
        } else if (i < 76800) {                // WTa2[96][160]
            int j = i - 61440; int r = j/160, c2 = j - r*160;
            int k = (c2 < 32) ? c2 : c2 + 128;
            WTa2[j] = f2bu(r < 64 ? W1[k*64 + r] : WA[k*32 + (r-64)]);
        } else if (i < 89088) {                // WTaN[96][128]
            int j = i - 76800; int r = j >> 7, c2 = j & 127;
            int k = c2 + 32;
            WTaN[j] = f2bu(r < 64 ? W1[k*64 + r] : WA[k*32 + (r-64)]);
        } else if (i < 93184) {                // WT2[64][64]
            int j = i - 89088; int r = j >> 6, c = j & 63;
            WT2[j] = f2bu(W2[c*64 + r]);
        } else if (i < 191488) {               // WsymT[128][768]
            int j = i - 93184; int r = j/768, c = j - r*768;
            WsymT[j] = f2bu(Wsym[c*128 + r]);
        } else {                               // WnsT[128][128]
            int j = i - 191488; int r = j >> 7, c = j & 127;
            WnsT[j] = f2bu(Wns[c*128 + r]);
        }
    } else if (b < 1580) {                     // NB: 196608 float4
        int i = (b - 812)*256 + tid;
        float4 v = ((const float4*)node_ext)[i];
        st_bf16x4(&NB[(size_t)i*4], v);
    } else if (b < 3628) {                     // EB: 4194304 float4
        for (int i = (b - 1580)*256 + tid; i < NEDGE_*64/4; i += 2048*256) {
            float4 v = ((const float4*)edge_ebd)[i];
            st_bf16x4(&EB[(size_t)i*4], v);
        }
    } else if (b < 5676) {                     // AB: 3276800 float4
        for (int i = (b - 3628)*256 + tid; i < NANGLE_*32/4; i += 2048*256) {
            float4 v = ((const float4*)angle_ebd)[i];
            st_bf16x4(&AB[(size_t)i*4], v);
        }
    } else if (b < 6700) {                     // count n2e
        int e = (b - 5676)*256 + tid;
        atomicAdd(&cnt[n2e[e]], 1);
    } else {                                   // count eij2a
        int a = (b - 6700)*256 + tid;
        atomicAdd(&cnt2[eij2a[a]], 1);
    }
}

// ---------------------------------------------------------------------------
// L2: block 0 = node scan; 1..256 = scan2a; 257..320 = nconst (edge path);
// 321..384 = nconstA (angle node-slice).
// ---------------------------------------------------------------------------
__global__ __launch_bounds__(256) void k_scan_misc(
    const int* __restrict__ cnt, int* __restrict__ off, int* __restrict__ cursor,
    const int* __restrict__ cnt2, int* __restrict__ bsum,
    const u16* __restrict__ NB, const u16* __restrict__ WTe,
    const u16* __restrict__ WTaN,
    float* __restrict__ nconst, float* __restrict__ nconstA)
{
    __shared__ __align__(16) u16 sN[64][136];
    int* wa = (int*)&sN[0][0];
    const int b = blockIdx.x, t = threadIdx.x;

    if (b == 0) {
        int v[16]; int s = 0;
        #pragma unroll
        for (int k = 0; k < 16; ++k) { v[k] = s; s += cnt[16*t + k]; }
        wa[t] = s;
        __syncthreads();
        for (int d = 1; d < 256; d <<= 1) {
            int x = wa[t];
            int y = (t >= d) ? wa[t-d] : 0;
            __syncthreads();
            wa[t] = x + y;
            __syncthreads();
        }
        int excl = (t == 0) ? 0 : wa[t-1];
        #pragma unroll
        for (int k = 0; k < 16; ++k) {
            off[16*t + k]    = excl + v[k];
            cursor[16*t + k] = excl + v[k];
        }
        if (t == 255) off[4096] = excl + s;
    } else if (b <= 256) {
        int bb = b - 1;
        int4 v = ((const int4*)cnt2)[bb*256 + t];
        wa[t] = v.x + v.y + v.z + v.w;
        __syncthreads();
        for (int d = 128; d > 0; d >>= 1) {
            if (t < d) wa[t] += wa[t+d];
            __syncthreads();
        }
        if (t == 0) bsum[bb] = wa[0];
    } else if (b <= 320) {
        const int e0 = (b - 257) * 64;
        #pragma unroll
        for (int f = t; f < 1024; f += 256) {
            int r = f >> 4, c = f & 15;
            *(uint4*)&sN[r][8*c] = ((const uint4*)&NB[(size_t)(e0 + r)*128])[c];
        }
        __syncthreads();
        const int w = t >> 6, l = t & 63;
        const int lr = l & 15, hq = l >> 4, lk = hq * 8;
        f32x4 acc[4][3] = {};
        #pragma unroll
        for (int kk = 0; kk < 4; ++kk) {
            bf16x8 a[4], bb[3];
            #pragma unroll
            for (int m = 0; m < 4; ++m)
                a[m] = *(const bf16x8*)&sN[16*m + lr][kk*32 + lk];
            #pragma unroll
            for (int nf = 0; nf < 3; ++nf)
                bb[nf] = *(const bf16x8*)&WTe[(size_t)(48*w + 16*nf + lr)*320 + kk*32 + lk];
            #pragma unroll
            for (int m = 0; m < 4; ++m)
                #pragma unroll
                for (int nf = 0; nf < 3; ++nf)
                    acc[m][nf] = __builtin_amdgcn_mfma_f32_16x16x32_bf16(a[m], bb[nf], acc[m][nf], 0, 0, 0);
        }
        #pragma unroll
        for (int nf = 0; nf < 3; ++nf) {
            int c = 48*w + 16*nf + lr;
            #pragma unroll
            for (int m = 0; m < 4; ++m)
                #pragma unroll
                for (int j = 0; j < 4; ++j) {
                    int r = 16*m + 4*hq + j;
                    nconst[(size_t)(e0 + r)*192 + c] = acc[m][nf][j];
                }
        }
    } else {
        // nconstA: 64 nodes per block, K=128, N=96
        const int n0 = (b - 321) * 64;
        #pragma unroll
        for (int f = t; f < 1024; f += 256) {
            int r = f >> 4, c = f & 15;
            *(uint4*)&sN[r][8*c] = ((const uint4*)&NB[(size_t)(n0 + r)*128])[c];
        }
        __syncthreads();
        const int w = t >> 6, l = t & 63;
        const int lr = l & 15, hq = l >> 4, lk = hq * 8;
        f32x4 acc[6] = {};
        #pragma unroll
        for (int kk = 0; kk < 4; ++kk) {
            bf16x8 a = *(const bf16x8*)&sN[16*w + lr][kk*32 + lk];
            #pragma unroll
            for (int nf = 0; nf < 6; ++nf) {
                bf16x8 bb = *(const bf16x8*)&WTaN[(size_t)(16*nf + lr)*128 + kk*32 + lk];
                acc[nf] = __builtin_amdgcn_mfma_f32_16x16x32_bf16(a, bb, acc[nf], 0, 0, 0);
            }
        }
        #pragma unroll
        for (int nf = 0; nf < 6; ++nf) {
            int c = 16*nf + lr;
            #pragma unroll
            for (int j = 0; j < 4; ++j) {
                int r = 16*w + 4*hq + j;
                nconstA[(size_t)(n0 + r)*96 + c] = acc[nf][j];
            }
        }
    }
}

__global__ void k_scan2b(const int* __restrict__ bsum, int* __restrict__ boff)
{
    __shared__ int wa[256];
    int t = threadIdx.x;
    wa[t] = bsum[t];
    __syncthreads();
    for (int d = 1; d < 256; d <<= 1) {
        int x = wa[t];
        int y = (t >= d) ? wa[t-d] : 0;
        __syncthreads();
        wa[t] = x + y;
        __syncthreads();
    }
    boff[t] = (t == 0) ? 0 : wa[t-1];
}

__global__ void k_scan2c(const int* __restrict__ cnt2, const int* __restrict__ boff,
                         int* __restrict__ off2, int* __restrict__ cursor2)
{
    __shared__ int wa[256];
    int b = blockIdx.x, t = threadIdx.x;
    int4 v = ((const int4*)cnt2)[b*256 + t];
    int s1 = v.x, s2 = s1 + v.y, s3 = s2 + v.z, s4 = s3 + v.w;
    wa[t] = s4;
    __syncthreads();
    for (int d = 1; d < 256; d <<= 1) {
        int x = wa[t];
        int y = (t >= d) ? wa[t-d] : 0;
        __syncthreads();
        wa[t] = x + y;
        __syncthreads();
    }
    int base = boff[b] + ((t == 0) ? 0 : wa[t-1]);
    int i = (b*256 + t)*4;
    off2[i]   = base;      cursor2[i]   = base;
    off2[i+1] = base + s1; cursor2[i+1] = base + s1;
    off2[i+2] = base + s2; cursor2[i+2] = base + s2;
    off2[i+3] = base + s3; cursor2[i+3] = base + s3;
    if (b == 255 && t == 255) off2[NEDGE_] = NANGLE_;
}

// L5: fused fills. [0,1024) edge csr; [1024,2624) angle csr2 (sorted list).
__global__ void k_fill2(const int* __restrict__ n2e, int* __restrict__ cursor,
                        int* __restrict__ csr,
                        const int* __restrict__ eij2a, int* __restrict__ cursor2,
                        int* __restrict__ csr2)
{
    int b = blockIdx.x;
    if (b < 1024) {
        int e = b*256 + threadIdx.x;
        int pos = atomicAdd(&cursor[n2e[e]], 1);
        csr[pos] = e;
    } else {
        int a = (b - 1024)*256 + threadIdx.x;
        int pos = atomicAdd(&cursor2[eij2a[a]], 1);
        csr2[pos] = a;
    }
}

// ---------------------------------------------------------------------------
// Flat edge GEMM over CSR-ordered tiles + fused segmented h2g2.
// ---------------------------------------------------------------------------
__global__ __launch_bounds__(256, 4) void k_edge_flat(
    const u16* __restrict__ NB, const u16* __restrict__ EB,
    const float* __restrict__ h2, const float* __restrict__ sw,
    const int* __restrict__ n2e, const int* __restrict__ n_ext2e,
    const int* __restrict__ csr,
    const u16* __restrict__ WTe, const float* __restrict__ nconst,
    const float* __restrict__ bne, const float* __restrict__ bes,
    float* __restrict__ msg,
    float* __restrict__ h2g2_e, float* __restrict__ h2g2_n,
    u16* __restrict__ eselfO)
{
    __shared__ __align__(16) u16 sA[64][200];
    __shared__ float sH[4][576];
    __shared__ int   s_eid[64];
    __shared__ int   s_node[64];
    __shared__ int   s_g[64];
    __shared__ float s_sw[64];
    __shared__ float s_h2[64][3];
    __shared__ int   s_segstart[65];
    __shared__ int   s_nseg;

    const int tid = threadIdx.x;
    const int w  = tid >> 6, l = tid & 63;
    const int lr = l & 15, hq = l >> 4, lk = hq * 8;
    const int base = blockIdx.x * 64;

    if (tid < 64) {
        int e = csr[base + tid];
        s_eid[tid]  = e;
        s_node[tid] = n2e[e];
        s_g[tid]    = n_ext2e[e];
        s_sw[tid]   = sw[e];
        s_h2[tid][0] = h2[e*3];
        s_h2[tid][1] = h2[e*3+1];
        s_h2[tid][2] = h2[e*3+2];
    }
    __syncthreads();

    if (tid < 64) {
        bool flag = (tid == 0) || (s_node[tid] != s_node[tid-1]);
        unsigned long long mask = __ballot(flag);
        if (flag) {
            int sid = __popcll(mask & ((1ull << tid) - 1ull));
            s_segstart[sid] = tid;
        }
        if (tid == 0) {
            int ns = __popcll(mask);
            s_nseg = ns;
            s_segstart[ns] = 64;
        }
    }

    #pragma unroll
    for (int f = tid; f < 1024; f += 256) {
        int r = f >> 4, c = f & 15;
        *(uint4*)&sA[r][8*c] = ((const uint4*)&NB[(size_t)s_g[r]*128])[c];
    }
    #pragma unroll
    for (int f = tid; f < 512; f += 256) {
        int r = f >> 3, c = f & 7;
        *(uint4*)&sA[r][128 + 8*c] = ((const uint4*)&EB[(size_t)s_eid[r]*64])[c];
    }
    __syncthreads();

    float bias[3];
    int   cful[3];
    #pragma unroll
    for (int nf = 0; nf < 3; ++nf) {
        int c = 48*w + 16*nf + lr;
        cful[nf] = c;
        bias[nf] = (c < 128) ? bne[c] : bes[c-128];
    }

    f32x4 acc[4][3] = {};
    #pragma unroll
    for (int kk = 0; kk < 6; ++kk) {
        bf16x8 a[4], b[3];
        #pragma unroll
        for (int m = 0; m < 4; ++m)
            a[m] = *(const bf16x8*)&sA[16*m + lr][kk*32 + lk];
        #pragma unroll
        for (int nf = 0; nf < 3; ++nf)
            b[nf] = *(const bf16x8*)&WTe[(size_t)cful[nf]*320 + 128 + kk*32 + lk];
        #pragma unroll
        for (int m = 0; m < 4; ++m)
            #pragma unroll
            for (int nf = 0; nf < 3; ++nf)
                acc[m][nf] = __builtin_amdgcn_mfma_f32_16x16x32_bf16(a[m], b[nf], acc[m][nf], 0, 0, 0);
    }

    #pragma unroll
    for (int nf = 0; nf < 3; ++nf) {
        int c = cful[nf];
        if (c < 128) {
            #pragma unroll
            for (int m = 0; m < 4; ++m)
                #pragma unroll
                for (int j = 0; j < 4; ++j) {
                    int r = 16*m + 4*hq + j;
                    float ncv = nconst[(size_t)s_node[r]*192 + c];
                    acc[m][nf][j] = silu_(acc[m][nf][j] + ncv + bias[nf]) * s_sw[r];
                }
        } else {
            int c2 = c - 128;
            #pragma unroll
            for (int m = 0; m < 4; ++m)
                #pragma unroll
                for (int j = 0; j < 4; ++j) {
                    int r = 16*m + 4*hq + j;
                    float ncv = nconst[(size_t)s_node[r]*192 + c];
                    eselfO[(size_t)s_eid[r]*64 + c2] =
                        f2bu(silu_(acc[m][nf][j] + ncv + bias[nf]));
                }
        }
    }

    // ---- segmented msg reduction ----
    const int nseg = s_nseg;
    for (int s = 0; s < nseg; ++s) {
        int rs = s_segstart[s], re = s_segstart[s+1];
        int nd = s_node[rs];
        #pragma unroll
        for (int nf = 0; nf < 3; ++nf) {
            if (cful[nf] >= 128) continue;
            float v = 0.f;
            #pragma unroll
            for (int m = 0; m < 4; ++m)
                #pragma unroll
                for (int j = 0; j < 4; ++j) {
                    int r = 16*m + 4*hq + j;
                    v += (r >= rs && r < re) ? acc[m][nf][j] : 0.f;
                }
            v += __shfl_xor(v, 16);
            v += __shfl_xor(v, 32);
            if (hq == 0) atomicAdd(&msg[(size_t)nd*128 + cful[nf]], v);
        }
    }

    // ---- segmented h2g2 accumulation ----
    for (int s = 0; s < nseg; ++s) {
        int rs = s_segstart[s], re = s_segstart[s+1];
        int nd = s_node[rs];
        int lo = max(16*w, rs), hi = min(16*w + 16, re);
        float hacc[9] = {0.f,0.f,0.f,0.f,0.f,0.f,0.f,0.f,0.f};
        for (int r = lo; r < hi; ++r) {
            float swv = s_sw[r];
            float s0 = s_h2[r][0] * swv;
            float s1 = s_h2[r][1] * swv;
            float s2 = s_h2[r][2] * swv;
            float eb = bu2f(sA[r][128 + l]);
            float n0 = bu2f(sA[r][l]);
            float n1 = bu2f(sA[r][64 + l]);
            hacc[0] = fmaf(s0, eb, hacc[0]);
            hacc[1] = fmaf(s1, eb, hacc[1]);
            hacc[2] = fmaf(s2, eb, hacc[2]);
            hacc[3] = fmaf(s0, n0, hacc[3]);
            hacc[4] = fmaf(s0, n1, hacc[4]);
            hacc[5] = fmaf(s1, n0, hacc[5]);
            hacc[6] = fmaf(s1, n1, hacc[6]);
            hacc[7] = fmaf(s2, n0, hacc[7]);
            hacc[8] = fmaf(s2, n1, hacc[8]);
        }
        #pragma unroll
        for (int q = 0; q < 3; ++q) sH[w][q*64 + l] = hacc[q];
        #pragma unroll
        for (int q = 0; q < 6; ++q) sH[w][192 + q*64 + l] = hacc[3+q];
        __syncthreads();
        for (int i = tid; i < 576; i += 256) {
            float v = sH[0][i] + sH[1][i] + sH[2][i] + sH[3][i];
            if (i < 192) atomicAdd(&h2g2_e[(size_t)nd*192 + i], v);
            else         atomicAdd(&h2g2_n[(size_t)nd*384 + (i - 192)], v);
        }
        __syncthreads();
    }
}

// ---------------------------------------------------------------------------
// Angle GEMM via MFMA, eij-SORTED order: block handles 32 consecutive sorted
// positions. K=160 (node slice hoisted to nconstA). ea writes sequential.
// ---------------------------------------------------------------------------
__global__ __launch_bounds__(256) void k_angle_mfma(
    const u16* __restrict__ EB, const u16* __restrict__ AB,
    const float* __restrict__ a_sw,
    const int* __restrict__ n2a, const int* __restrict__ eij2a,
    const int* __restrict__ eik2a, const int* __restrict__ csr2,
    const u16* __restrict__ WTa2, const float* __restrict__ nconstA,
    const float* __restrict__ b1, const float* __restrict__ bA,
    const float* __restrict__ a_res0,
    u16* __restrict__ ea, float* __restrict__ a_out)
{
    __shared__ __align__(16) u16 sA[32][168];
    __shared__ __align__(16) u16 sEA[32][64];
    __shared__ int s_a[32], s_nd[32], s_ij[32], s_ik[32];
    __shared__ float s_asw[32];
    const int tid = threadIdx.x;
    const int p0 = blockIdx.x * 32;

    if (tid < 32) {
        int a = csr2[p0 + tid];
        s_a[tid]  = a;
        s_nd[tid] = n2a[a];
        s_ij[tid] = eij2a[a];
        s_ik[tid] = eik2a[a];
        s_asw[tid] = a_sw[a];
    }
    __syncthreads();

    if (tid < 128) {                                 // angle_ebd from AB (gather)
        int r = tid >> 2, c = tid & 3;
        *(uint4*)&sA[r][8*c] = ((const uint4*)&AB[(size_t)s_a[r]*32])[c];
    }
    {
        int r = tid >> 3, c = tid & 7;
        *(uint4*)&sA[r][32 + 8*c] = ((const uint4*)&EB[(size_t)s_ik[r]*64])[c];
        *(uint4*)&sA[r][96 + 8*c] = ((const uint4*)&EB[(size_t)s_ij[r]*64])[c];
    }
    __syncthreads();

    const int w = tid >> 6, l = tid & 63;
    const int lr = l & 15, hq = l >> 4, lk = hq * 8;
    const int mrow  = (w & 1) * 16;
    const int nbase = (w >> 1) * 48;

    f32x4 acc[3] = {};
    #pragma unroll
    for (int kk = 0; kk < 5; ++kk) {
        bf16x8 a = *(const bf16x8*)&sA[mrow + lr][kk*32 + lk];
        #pragma unroll
        for (int nf = 0; nf < 3; ++nf) {
            bf16x8 b = *(const bf16x8*)&WTa2[(size_t)(nbase + 16*nf + lr)*160 + kk*32 + lk];
            acc[nf] = __builtin_amdgcn_mfma_f32_16x16x32_bf16(a, b, acc[nf], 0, 0, 0);
        }
    }

    #pragma unroll
    for (int nf = 0; nf < 3; ++nf) {
        int c = nbase + 16*nf + lr;
        if (c < 64) {                                // edge_angle -> sEA
            float bb = b1[c];
            #pragma unroll
            for (int j = 0; j < 4; ++j) {
                int r = mrow + 4*hq + j;
                float nca = nconstA[(size_t)s_nd[r]*96 + c];
                sEA[r][c] = f2bu(silu_(acc[nf][j] + nca + bb) * s_asw[r]);
            }
        } else {                                     // angle_self -> a_out
            int c2 = c - 64;
            float bb = bA[c2], rr = a_res0[c2];
            #pragma unroll
            for (int j = 0; j < 4; ++j) {
                int r = mrow + 4*hq + j;
                float nca = nconstA[(size_t)s_nd[r]*96 + c];
                a_out[(size_t)s_a[r]*32 + c2] =
                    bu2f(sA[r][c2]) + rr * silu_(acc[nf][j] + nca + bb);
            }
        }
    }
    __syncthreads();

    {                                                // sequential ea store
        int r = tid >> 3, c = tid & 7;
        *(uint4*)&ea[((size_t)(p0 + r))*64 + 8*c] = *(const uint4*)&sEA[r][8*c];
    }
}

// ---------------------------------------------------------------------------
// L8 fused: [0,4096) edgefin (all reads sequential); [4096,8192) symc.
// ---------------------------------------------------------------------------
__global__ __launch_bounds__(256) void k_fin(
    const u16* __restrict__ EB, const u16* __restrict__ eselfO,
    const u16* __restrict__ ea, const int* __restrict__ off2,
    const u16* __restrict__ WT2,
    const float* __restrict__ b2_, const float* __restrict__ er0,
    const float* __restrict__ er1,
    float* __restrict__ e_out,
    const float* __restrict__ h2g2_e, const float* __restrict__ h2g2_n,
    u16* __restrict__ symcB)
{
    __shared__ __align__(16) u16 sR[64][72];
    __shared__ __align__(16) u16 sE[64][72];
    __shared__ __align__(16) u16 sB[64][72];
    const int tid = threadIdx.x;
    const int blk = blockIdx.x;

    if (blk < 4096) {
        const int e0 = blk * 64;
        const int w = tid >> 6, l = tid & 63;

        #pragma unroll
        for (int f = tid; f < 512; f += 256) {
            int r = f >> 3, c = f & 7;
            *(uint4*)&sB[r][8*c] = ((const uint4*)&EB[(size_t)(e0 + r)*64])[c];
            *(uint4*)&sE[r][8*c] = ((const uint4*)&eselfO[(size_t)(e0 + r)*64])[c];
        }

        #pragma unroll
        for (int r16 = 0; r16 < 16; ++r16) {
            int r = w*16 + r16;
            int e = e0 + r;
            float s = 0.f;
            int jb = off2[e], je = off2[e+1];
            for (int j = jb; j < je; ++j)
                s += bu2f(ea[(size_t)j*64 + l]);
            sR[r][l] = f2bu(s);
        }
        __syncthreads();

        const int lr = l & 15, hq = l >> 4, lk = hq * 8;
        f32x4 acc[4] = {};
        #pragma unroll
        for (int kk = 0; kk < 2; ++kk) {
            bf16x8 b = *(const bf16x8*)&WT2[(size_t)(16*w + lr)*64 + kk*32 + lk];
            #pragma unroll
            for (int m = 0; m < 4; ++m) {
                bf16x8 a = *(const bf16x8*)&sR[16*m + lr][kk*32 + lk];
                acc[m] = __builtin_amdgcn_mfma_f32_16x16x32_bf16(a, b, acc[m], 0, 0, 0);
            }
        }
        int c = 16*w + lr;
        float bb = b2_[c], r0 = er0[c], r1 = er1[c];
        #pragma unroll
        for (int m = 0; m < 4; ++m)
            #pragma unroll
            for (int j = 0; j < 4; ++j) {
                int r = 16*m + 4*hq + j;
                size_t idx = (size_t)(e0 + r)*64 + c;
                e_out[idx] = bu2f(sB[r][c]) + r0 * bu2f(sE[r][c])
                           + r1 * silu_(acc[m][j] + bb);
            }
    } else {
        const int n = blk - 4096;
        float* he = (float*)&sR[0][0];
        float* hn = he + 192;
        for (int i = tid; i < 192; i += 256) he[i] = h2g2_e[(size_t)n*192 + i];
        for (int i = tid; i < 384; i += 256) hn[i] = h2g2_n[(size_t)n*384 + i];
        __syncthreads();
        const float SCALE = 1.0f / (6.4f * 3.0f);
        for (int i = tid; i < 768; i += 256) {
            float s;
            if (i < 256) {
                int a = i >> 6, j = i & 63;
                s = he[a]*he[j] + he[64+a]*he[64+j] + he[128+a]*he[128+j];
            } else {
                int i2 = i - 256;
                int a = i2 >> 7, j = i2 & 127;
                s = hn[a]*hn[j] + hn[128+a]*hn[128+j] + hn[256+a]*hn[256+j];
            }
            symcB[(size_t)n*768 + i] = f2bu(s * SCALE);
        }
    }
}

// ---------------------------------------------------------------------------
// Node finalize via MFMA.
// ---------------------------------------------------------------------------
__global__ __launch_bounds__(256) void k_node_mfma(
    const u16* __restrict__ symcB, const u16* __restrict__ NB,
    const float* __restrict__ node_ext, const float* __restrict__ msg,
    const u16* __restrict__ WsymT, const u16* __restrict__ WnsT,
    const float* __restrict__ bns, const float* __restrict__ bsym,
    const float* __restrict__ nr0, const float* __restrict__ nr1,
    const float* __restrict__ nr2,
    float* __restrict__ n_out)
{
    __shared__ __align__(16) u16 sA[32][264];
    const int tid = threadIdx.x;
    const int n0 = blockIdx.x * 32;
    const int w = tid >> 6, l = tid & 63;
    const int lr = l & 15, hq = l >> 4, lk = hq * 8;

    f32x4 accY[2][2] = {};
    f32x4 accS[2][2] = {};

    for (int chunk = 0; chunk < 3; ++chunk) {
        __syncthreads();
        #pragma unroll
        for (int f = tid; f < 1024; f += 256) {
            int r = f >> 5, c = f & 31;
            *(uint4*)&sA[r][8*c] =
                ((const uint4*)&symcB[(size_t)(n0 + r)*768 + chunk*256])[c];
        }
        __syncthreads();
        #pragma unroll
        for (int kk = 0; kk < 8; ++kk) {
            bf16x8 a[2], b[2];
            #pragma unroll
            for (int m = 0; m < 2; ++m)
                a[m] = *(const bf16x8*)&sA[16*m + lr][kk*32 + lk];
            #pragma unroll
            for (int nf = 0; nf < 2; ++nf)
                b[nf] = *(const bf16x8*)&WsymT[(size_t)(32*w + 16*nf + lr)*768
                                               + chunk*256 + kk*32 + lk];
            #pragma unroll
            for (int m = 0; m < 2; ++m)
                #pragma unroll
                for (int nf = 0; nf < 2; ++nf)
                    accY[m][nf] = __builtin_amdgcn_mfma_f32_16x16x32_bf16(a[m], b[nf], accY[m][nf], 0, 0, 0);
        }
    }

    __syncthreads();
    #pragma unroll
    for (int f = tid; f < 512; f += 256) {
        int r = f >> 4, c = f & 15;
        *(uint4*)&sA[r][8*c] = ((const uint4*)&NB[(size_t)(n0 + r)*128])[c];
    }
    __syncthreads();
    #pragma unroll
    for (int kk = 0; kk < 4; ++kk) {
        bf16x8 a[2], b[2];
        #pragma unroll
        for (int m = 0; m < 2; ++m)
            a[m] = *(const bf16x8*)&sA[16*m + lr][kk*32 + lk];
        #pragma unroll
        for (int nf = 0; nf < 2; ++nf)
            b[nf] = *(const bf16x8*)&WnsT[(size_t)(32*w + 16*nf + lr)*128 + kk*32 + lk];
        #pragma unroll
        for (int m = 0; m < 2; ++m)
            #pragma unroll
            for (int nf = 0; nf < 2; ++nf)
                accS[m][nf] = __builtin_amdgcn_mfma_f32_16x16x32_bf16(a[m], b[nf], accS[m][nf], 0, 0, 0);
    }

    #pragma unroll
    for (int nf = 0; nf < 2; ++nf) {
        int c = 32*w + 16*nf + lr;
        float bS = bns[c], bY = bsym[c];
        float r0 = nr0[c], r1 = nr1[c], r2 = nr2[c];
        #pragma unroll
        for (int m = 0; m < 2; ++m)
            #pragma unroll
            for (int j = 0; j < 4; ++j) {
                int r = 16*m + 4*hq + j;
                size_t idx = (size_t)(n0 + r)*128 + c;
                float self_ = silu_(accS[m][nf][j] + bS);
                float sym_  = silu_(accY[m][nf][j] + bY);
                n_out[idx] = node_ext[idx] + r0*self_ + r1*sym_
                           + r2 * msg[idx] * (1.0f / 6.4f);
            }
    }
}

// ---------------------------------------------------------------------------
extern "C" void kernel_launch(void* const* d_in, const int* in_sizes, int n_in,
                              void* d_out, int out_size, void* d_ws, size_t ws_size,
                              hipStream_t stream)
{
    const float* node_ext  = (const float*)d_in[0];
    const float* edge_ebd  = (const float*)d_in[1];
    const float* h2        = (const float*)d_in[2];
    const float* angle_ebd = (const float*)d_in[3];
    const float* sw        = (const float*)d_in[6];
    const float* a_sw      = (const float*)d_in[9];
    const int*  edge_index  = (const int*)d_in[10];
    const int*  angle_index = (const int*)d_in[11];
    const int* n2e     = edge_index;
    const int* n_ext2e = edge_index + NEDGE_;
    const int* n2a     = angle_index;
    const int* eij2a   = angle_index + NANGLE_;
    const int* eik2a   = angle_index + 2*NANGLE_;

    const float* Wns  = (const float*)d_in[12];
    const float* bns  = (const float*)d_in[13];
    const float* Wsym = (const float*)d_in[14];
    const float* bsym = (const float*)d_in[15];
    const float* Wne  = (const float*)d_in[16];
    const float* bne  = (const float*)d_in[17];
    const float* Wes  = (const float*)d_in[18];
    const float* bes  = (const float*)d_in[19];
    const float* W1   = (const float*)d_in[20];
    const float* b1   = (const float*)d_in[21];
    const float* W2   = (const float*)d_in[22];
    const float* b2_  = (const float*)d_in[23];
    const float* WA   = (const float*)d_in[24];
    const float* bA   = (const float*)d_in[25];
    const float* nr0  = (const float*)d_in[26];
    const float* nr1  = (const float*)d_in[27];
    const float* nr2  = (const float*)d_in[28];
    const float* er0  = (const float*)d_in[29];
    const float* er1  = (const float*)d_in[30];
    const float* ar0  = (const float*)d_in[31];

    // workspace layout
    char* wsp = (char*)d_ws;
    u16*   ea      = (u16*)wsp;    wsp += (size_t)NANGLE_ * 64 * 2;
    u16*   EB      = (u16*)wsp;    wsp += (size_t)NEDGE_ * 64 * 2;
    u16*   NB      = (u16*)wsp;    wsp += (size_t)NALL_ * 128 * 2;
    u16*   AB      = (u16*)wsp;    wsp += (size_t)NANGLE_ * 32 * 2;
    u16*   eselfO  = (u16*)wsp;    wsp += (size_t)NEDGE_ * 64 * 2;
    u16*   symcB   = (u16*)wsp;    wsp += (size_t)NLOC_ * 768 * 2;
    // zeroed region: [cnt | cnt2 | msg | h2g2_e | h2g2_n]
    int*   cnt     = (int*)wsp;    wsp += 4096 * 4;
    int*   cnt2    = (int*)wsp;    wsp += (size_t)NEDGE_ * 4;
    float* msg     = (float*)wsp;  wsp += (size_t)NLOC_ * 128 * 4;
    float* h2g2_e  = (float*)wsp;  wsp += (size_t)NLOC_ * 192 * 4;
    float* h2g2_n  = (float*)wsp;  wsp += (size_t)NLOC_ * 384 * 4;
    size_t zero_bytes = 4096*4 + (size_t)NEDGE_*4 + (size_t)NLOC_*128*4
                      + (size_t)NLOC_*192*4 + (size_t)NLOC_*384*4;
    int*   off     = (int*)wsp;    wsp += 4104 * 4;
    int*   cursor  = (int*)wsp;    wsp += 4096 * 4;
    int*   csr     = (int*)wsp;    wsp += (size_t)NEDGE_ * 4;
    int*   off2    = (int*)wsp;    wsp += ((size_t)NEDGE_ + 16) * 4;
    int*   cursor2 = (int*)wsp;    wsp += (size_t)NEDGE_ * 4;
    int*   bsum    = (int*)wsp;    wsp += 256 * 4;
    int*   boff    = (int*)wsp;    wsp += 256 * 4;
    int*   csr2    = (int*)wsp;    wsp += (size_t)NANGLE_ * 4;
    float* nconst  = (float*)wsp;  wsp += (size_t)NLOC_ * 192 * 4;
    float* nconstA = (float*)wsp;  wsp += (size_t)NLOC_ * 96 * 4;
    u16*   WTe     = (u16*)wsp;    wsp += 192 * 320 * 2;
    u16*   WTa2    = (u16*)wsp;    wsp += 96 * 160 * 2;
    u16*   WTaN    = (u16*)wsp;    wsp += 96 * 128 * 2;
    u16*   WT2     = (u16*)wsp;    wsp += 64 * 64 * 2;
    u16*   WsymT   = (u16*)wsp;    wsp += 128 * 768 * 2;
    u16*   WnsT    = (u16*)wsp;    wsp += 128 * 128 * 2;

    hipMemsetAsync(cnt, 0, zero_bytes, stream);

    float* n_out = (float*)d_out;
    float* e_out = n_out + (size_t)NLOC_ * 128;
    float* a_out = e_out + (size_t)NEDGE_ * 64;

    k_mega_prep <<<8300, 256, 0, stream>>>(Wne, Wes, W1, WA, W2, Wsym, Wns,
                                           node_ext, edge_ebd, angle_ebd,
                                           n2e, eij2a,
                                           WTe, WTa2, WTaN, WT2, WsymT, WnsT,
                                           NB, EB, AB, cnt, cnt2);
    k_scan_misc <<<385, 256, 0, stream>>>(cnt, off, cursor, cnt2, bsum,
                                          NB, WTe, WTaN, nconst, nconstA);
    k_scan2b <<<1, 256, 0, stream>>>(bsum, boff);
    k_scan2c <<<256, 256, 0, stream>>>(cnt2, boff, off2, cursor2);
    k_fill2  <<<2624, 256, 0, stream>>>(n2e, cursor, csr, eij2a, cursor2, csr2);

    k_edge_flat <<<NEDGE_/64, 256, 0, stream>>>(NB, EB, h2, sw, n2e, n_ext2e, csr,
                                                WTe, nconst, bne, bes,
                                                msg, h2g2_e, h2g2_n, eselfO);
    k_angle_mfma <<<NANGLE_/32, 256, 0, stream>>>(EB, AB, a_sw,
                                                  n2a, eij2a, eik2a, csr2,
                                                  WTa2, nconstA, b1, bA, ar0,
                                                  ea, a_out);
    k_fin <<<8192, 256, 0, stream>>>(EB, eselfO, ea, off2, WT2, b2_, er0, er1,
                                     e_out, h2g2_e, h2g2_n, symcB);
    k_node_mfma <<<NLOC_/32, 256, 0, stream>>>(symcB, NB, node_ext, msg,
                                               WsymT, WnsT, bns, bsym,
                                               nr0, nr1, nr2, n_out);
}